// Round 2
// baseline (7280.105 us; speedup 1.0000x reference)
//
#include <hip/hip_runtime.h>

// Problem constants
#define BB 4
#define NN 8192
#define CC 64
#define SS 2048
#define KK 32
#define MROWS (BB*SS*KK)   // 262144

__device__ __forceinline__ float bf2f(unsigned short u){
  union { unsigned int i; float f; } v; v.i = ((unsigned int)u) << 16; return v.f;
}
__device__ __forceinline__ unsigned short f2bf(float f){
  union { float f; unsigned int i; } v; v.f = f;
  unsigned int u = v.i;
  unsigned int r = (u + 0x7FFFu + ((u >> 16) & 1u)) >> 16;
  return (unsigned short)r;
}

// ---------------- dtype detection ----------------
__global__ void detect_kernel(const void* pts, int* flag){
  __shared__ int cnt;
  if (threadIdx.x == 0) cnt = 0;
  __syncthreads();
  unsigned short u = ((const unsigned short*)pts)[threadIdx.x];
  int e = (u >> 7) & 0xFF;
  if (e != 0 && (e < 112 || e > 143)) atomicAdd(&cnt, 1);
  __syncthreads();
  if (threadIdx.x == 0) *flag = (cnt > 32) ? 1 : 0;
}

__global__ void convert_kernel(const void* src, float* dst, int n, const int* flag){
  int i = blockIdx.x*256 + threadIdx.x;
  if (i >= n) return;
  dst[i] = (*flag != 0) ? ((const float*)src)[i] : bf2f(((const unsigned short*)src)[i]);
}

// (B,C,N) -> (B,N,C) f32, tiled transpose
__global__ __launch_bounds__(256) void transpose_points(const void* pts, float* out, const int* flag){
  __shared__ float tile[64][65];
  int bx = blockIdx.x; int b = bx >> 7; int n0 = (bx & 127) * 64; int tid = threadIdx.x;
  bool isf = (*flag != 0);
  #pragma unroll
  for (int k = 0; k < 16; k++){
    int idx = k*256 + tid; int c = idx >> 6; int ni = idx & 63;
    size_t src = ((size_t)b*CC + c)*NN + n0 + ni;
    tile[c][ni] = isf ? ((const float*)pts)[src] : bf2f(((const unsigned short*)pts)[src]);
  }
  __syncthreads();
  #pragma unroll
  for (int k = 0; k < 16; k++){
    int idx = k*256 + tid; int ni = idx >> 6; int c = idx & 63;
    out[((size_t)b*NN + n0 + ni)*CC + c] = tile[c][ni];
  }
}

// ---------------- FPS ----------------
__global__ __launch_bounds__(512) void fps_kernel(const float* xyzf, int* fps_idx, void* d_out, const int* flag){
  int b = blockIdx.x, tid = threadIdx.x;
  const float* xb = xyzf + (size_t)b*NN*3;
  float px[16], py[16], pz[16], dmin[16];
  #pragma unroll
  for (int j = 0; j < 16; j++){
    int p = tid + j*512;
    px[j] = xb[p*3]; py[j] = xb[p*3+1]; pz[j] = xb[p*3+2];
    dmin[j] = 1e10f;
  }
  __shared__ float sc[3]; __shared__ int swin;
  __shared__ float rv[8]; __shared__ int ri[8];
  int far = 0;
  bool isf32 = (*flag != 0);
  float* outf = (float*)d_out; unsigned short* outh = (unsigned short*)d_out;
  for (int s = 0; s < SS; s++){
    int ot = far & 511, oj = far >> 9;
    if (tid == ot){
      #pragma unroll
      for (int j = 0; j < 16; j++) if (j == oj){ sc[0]=px[j]; sc[1]=py[j]; sc[2]=pz[j]; }
    }
    __syncthreads();
    float cx = sc[0], cy = sc[1], cz = sc[2];
    if (tid == 0){
      fps_idx[b*SS + s] = far;
      size_t o = ((size_t)b*SS + s)*3;
      if (isf32){ outf[o]=cx; outf[o+1]=cy; outf[o+2]=cz; }
      else { outh[o]=f2bf(cx); outh[o+1]=f2bf(cy); outh[o+2]=f2bf(cz); }
    }
    float bv = -1.0f; int bi = 0x7FFFFFFF;
    {
      #pragma clang fp contract(off)
      #pragma unroll
      for (int j = 0; j < 16; j++){
        float dx = px[j]-cx, dy = py[j]-cy, dz = pz[j]-cz;
        float d = dx*dx + dy*dy + dz*dz;
        float nd = fminf(dmin[j], d); dmin[j] = nd;
        if (nd > bv){ bv = nd; bi = tid + (j << 9); }
      }
    }
    #pragma unroll
    for (int off = 32; off; off >>= 1){
      float ov = __shfl_down(bv, off); int oi = __shfl_down(bi, off);
      if (ov > bv || (ov == bv && oi < bi)){ bv = ov; bi = oi; }
    }
    if ((tid & 63) == 0){ rv[tid >> 6] = bv; ri[tid >> 6] = bi; }
    __syncthreads();
    if (tid < 64){
      float v = (tid < 8) ? rv[tid] : -1.0f;
      int i2 = (tid < 8) ? ri[tid] : 0x7FFFFFFF;
      #pragma unroll
      for (int off = 4; off; off >>= 1){
        float ov = __shfl_down(v, off); int oi = __shfl_down(i2, off);
        if (ov > v || (ov == v && oi < i2)){ v = ov; i2 = oi; }
      }
      if (tid == 0) swin = i2;
    }
    __syncthreads();
    far = swin;
  }
}

// ---------------- kNN ----------------
__global__ __launch_bounds__(256) void knn_kernel(const float* xyzf, const int* fps_idx, int* knn){
  int blk = blockIdx.x; int b = blk >> 7; int s0 = (blk & 127) * 16; int tid = threadIdx.x;
  const float* xb = xyzf + (size_t)b*NN*3;
  __shared__ float scc[3]; __shared__ float rv[4]; __shared__ int ri[4];
  __shared__ float swv; __shared__ int swi;
  for (int ci = 0; ci < 16; ci++){
    int s = s0 + ci;
    if (tid == 0){
      int f = fps_idx[b*SS + s];
      scc[0] = xb[f*3]; scc[1] = xb[f*3+1]; scc[2] = xb[f*3+2];
    }
    __syncthreads();
    float cx = scc[0], cy = scc[1], cz = scc[2];
    float dv[32];
    float lmv = 3e38f; int lmi = 0x7FFFFFFF;
    {
      #pragma clang fp contract(off)
      #pragma unroll
      for (int q = 0; q < 8; q++){
        const float4* p4 = (const float4*)(xb + (size_t)tid*96 + q*12);
        float4 A = p4[0], B = p4[1], C = p4[2];
        float xs_[4] = {A.x, A.w, B.z, C.y};
        float ys_[4] = {A.y, B.x, B.w, C.z};
        float zs_[4] = {A.z, B.y, C.x, C.w};
        #pragma unroll
        for (int r = 0; r < 4; r++){
          float dx = cx - xs_[r], dy = cy - ys_[r], dz = cz - zs_[r];
          float d = dx*dx + dy*dy + dz*dz;
          int t = q*4 + r; dv[t] = d;
          int p = tid*32 + t;
          if (d < lmv || (d == lmv && p < lmi)){ lmv = d; lmi = p; }
        }
      }
    }
    int out_base = ((b*SS + s) << 5);
    for (int r = 0; r < 32; r++){
      float v = lmv; int i2 = lmi;
      #pragma unroll
      for (int off = 32; off; off >>= 1){
        float ov = __shfl_down(v, off); int oi = __shfl_down(i2, off);
        if (ov < v || (ov == v && oi < i2)){ v = ov; i2 = oi; }
      }
      if ((tid & 63) == 0){ rv[tid >> 6] = v; ri[tid >> 6] = i2; }
      __syncthreads();
      if (tid == 0){
        float wv = rv[0]; int wi = ri[0];
        #pragma unroll
        for (int q = 1; q < 4; q++){
          if (rv[q] < wv || (rv[q] == wv && ri[q] < wi)){ wv = rv[q]; wi = ri[q]; }
        }
        swv = wv; swi = wi; knn[out_base + r] = wi;
      }
      __syncthreads();
      float wv = swv; int wi = swi;
      if (lmi == wi){
        lmv = 3e38f; lmi = 0x7FFFFFFF;
        #pragma unroll
        for (int t = 0; t < 32; t++){
          int p = tid*32 + t; float d = dv[t];
          bool alive = (d > wv) || (d == wv && p > wi);
          if (alive && (d < lmv || (d == lmv && p < lmi))){ lmv = d; lmi = p; }
        }
      }
    }
  }
}

// ---------------- fused recompute chain ----------------
// 64-row (2-centroid) LDS tile; all intermediates stay in LDS.
// MODE 0: stats of y0; 1: stats of y1; 2: stats of y2; 3: final maxpool+write.

__device__ __forceinline__ void mm64(const float (*xs)[68], float (*wbb)[64],
    const float* __restrict__ w, int IN, int KP, int obase, int tid, float acc[4][4]){
  int tx = tid & 15, ty = tid >> 4;
  #pragma unroll
  for (int i = 0; i < 4; i++)
    #pragma unroll
    for (int j = 0; j < 4; j++) acc[i][j] = 0.f;
  for (int k0 = 0; k0 < KP; k0 += 16){
    __syncthreads();   // protect wbb reuse
    {
      int o = tid & 63, kb = (tid >> 6) << 2;
      const float* wrow = w + (size_t)(obase + o) * IN + k0 + kb;
      #pragma unroll
      for (int i2 = 0; i2 < 4; i2++){
        int k = k0 + kb + i2;
        wbb[kb + i2][o] = (k < IN) ? wrow[i2] : 0.f;
      }
    }
    __syncthreads();
    #pragma unroll
    for (int kk = 0; kk < 16; kk++){
      const float4 xv = *(const float4*)&xs[k0 + kk][tx << 2];
      const float4 wv = *(const float4*)&wbb[kk][ty << 2];
      float xr[4] = {xv.x, xv.y, xv.z, xv.w};
      float wr[4] = {wv.x, wv.y, wv.z, wv.w};
      #pragma unroll
      for (int i = 0; i < 4; i++)
        #pragma unroll
        for (int j = 0; j < 4; j++)
          acc[i][j] += xr[i] * wr[j];
    }
  }
}

template<int MODE>
__global__ __launch_bounds__(256) void chain_kernel(
    const float* __restrict__ xyzf, const float* __restrict__ ptst,
    const int* __restrict__ fpsi, const int* __restrict__ knn,
    const float* __restrict__ w0, const float* __restrict__ w1, const float* __restrict__ w2,
    const float* __restrict__ bnac,
    float* osum, float* osq,
    void* d_out, const int* __restrict__ flag)
{
  __shared__ float xb0[80][68];
  __shared__ float wb[16][64];
  __shared__ float xb1[(MODE >= 1) ? 64 : 1][68];
  __shared__ float xb2[(MODE >= 2) ? 128 : 1][68];

  int tid = threadIdx.x, tx = tid & 15, ty = tid >> 4;
  constexpr int TILES = (MODE == 3) ? 1 : 8;
  constexpr int NCH = (MODE == 0) ? 1 : (MODE == 1) ? 2 : 4;
  float ssum[NCH][4], ssq[NCH][4];
  if (MODE < 3){
    #pragma unroll
    for (int c = 0; c < NCH; c++)
      #pragma unroll
      for (int j = 0; j < 4; j++){ ssum[c][j] = 0.f; ssq[c][j] = 0.f; }
  }
  bool isf32 = (MODE == 3) ? (*flag != 0) : false;

  for (int t = 0; t < TILES; t++){
    int row0 = (blockIdx.x * TILES + t) * 64;
    // ---- gather into xb0[k][r] ----
    {
      int r = tid >> 2, p = tid & 3;
      int g = row0 + r;
      int b = g >> 16, s = (g >> 5) & 2047;
      int n = knn[g];
      const float* xb = xyzf + (size_t)b*NN*3;
      if (p == 0){
        int f = fpsi[(b << 11) + s];
        xb0[0][r] = xb[n*3]   - xb[f*3];
        xb0[1][r] = xb[n*3+1] - xb[f*3+1];
        xb0[2][r] = xb[n*3+2] - xb[f*3+2];
      }
      const float4* pr = (const float4*)(ptst + ((size_t)b*NN + n)*CC);
      #pragma unroll
      for (int q = 0; q < 4; q++){
        float4 v = pr[p*4 + q];
        int k = 3 + p*16 + q*4;
        xb0[k][r] = v.x; xb0[k+1][r] = v.y; xb0[k+2][r] = v.z; xb0[k+3][r] = v.w;
      }
      if (p == 3){
        #pragma unroll
        for (int k = 67; k < 80; k++) xb0[k][r] = 0.f;
      }
    }

    float acc[4][4];
    // ---- L0: y0 = x @ W0^T (OUT=64, one chunk) ----
    mm64(xb0, wb, w0, 67, 80, 0, tid, acc);
    if (MODE == 0){
      #pragma unroll
      for (int j = 0; j < 4; j++){
        float s0 = acc[0][j] + acc[1][j] + acc[2][j] + acc[3][j];
        float q0 = acc[0][j]*acc[0][j] + acc[1][j]*acc[1][j] + acc[2][j]*acc[2][j] + acc[3][j]*acc[3][j];
        ssum[0][j] += s0; ssq[0][j] += q0;
      }
    } else {
      #pragma unroll
      for (int j = 0; j < 4; j++){
        int o = ty*4 + j;
        float a = bnac[o], c = bnac[64 + o];
        #pragma unroll
        for (int i = 0; i < 4; i++)
          xb1[o][tx*4 + i] = fmaxf(acc[i][j]*a + c, 0.f);
      }
    }

    if (MODE >= 1){
      // ---- L1: y1 = x1 @ W1^T (OUT=128, 2 chunks) ----
      #pragma unroll
      for (int ch = 0; ch < 2; ch++){
        mm64(xb1, wb, w1, 64, 64, ch*64, tid, acc);
        if (MODE == 1){
          #pragma unroll
          for (int j = 0; j < 4; j++){
            float s0 = acc[0][j] + acc[1][j] + acc[2][j] + acc[3][j];
            float q0 = acc[0][j]*acc[0][j] + acc[1][j]*acc[1][j] + acc[2][j]*acc[2][j] + acc[3][j]*acc[3][j];
            ssum[ch][j] += s0; ssq[ch][j] += q0;
          }
        } else {
          #pragma unroll
          for (int j = 0; j < 4; j++){
            int o = ch*64 + ty*4 + j;
            float a = bnac[128 + o], c = bnac[256 + o];
            #pragma unroll
            for (int i = 0; i < 4; i++)
              xb2[o][tx*4 + i] = fmaxf(acc[i][j]*a + c, 0.f);
          }
        }
      }
    }

    if (MODE >= 2){
      // ---- L2: y2 = x2 @ W2^T (OUT=256, 4 chunks) ----
      #pragma unroll
      for (int ch = 0; ch < 4; ch++){
        mm64(xb2, wb, w2, 128, 128, ch*64, tid, acc);
        if (MODE == 2){
          #pragma unroll
          for (int j = 0; j < 4; j++){
            float s0 = acc[0][j] + acc[1][j] + acc[2][j] + acc[3][j];
            float q0 = acc[0][j]*acc[0][j] + acc[1][j]*acc[1][j] + acc[2][j]*acc[2][j] + acc[3][j]*acc[3][j];
            ssum[ch][j] += s0; ssq[ch][j] += q0;
          }
        } else {
          float m[4];
          #pragma unroll
          for (int j = 0; j < 4; j++){
            int o = ch*64 + ty*4 + j;
            float a = bnac[384 + o], c = bnac[640 + o];
            float v = fmaxf(fmaxf(acc[0][j]*a + c, acc[1][j]*a + c),
                            fmaxf(acc[2][j]*a + c, acc[3][j]*a + c));
            m[j] = fmaxf(v, 0.f);
          }
          #pragma unroll
          for (int mo = 1; mo < 8; mo <<= 1){
            #pragma unroll
            for (int j = 0; j < 4; j++) m[j] = fmaxf(m[j], __shfl_xor(m[j], mo));
          }
          if ((tx & 7) == 0){
            int cglob = (row0 >> 5) + (tx >> 3);
            int b = cglob >> 11, s = cglob & 2047;
            #pragma unroll
            for (int j = 0; j < 4; j++){
              int o = ch*64 + ty*4 + j;
              size_t oo = (size_t)BB*SS*3 + (((size_t)(b*256 + o)) << 11) + s;
              if (isf32) ((float*)d_out)[oo] = m[j];
              else ((unsigned short*)d_out)[oo] = f2bf(m[j]);
            }
          }
        }
      }
    }
    __syncthreads();   // protect xb0/xb1/xb2 overwrite by next tile
  }

  if (MODE < 3){
    #pragma unroll
    for (int c = 0; c < NCH; c++)
      #pragma unroll
      for (int j = 0; j < 4; j++){
        #pragma unroll
        for (int mo = 1; mo < 16; mo <<= 1){
          ssum[c][j] += __shfl_xor(ssum[c][j], mo);
          ssq [c][j] += __shfl_xor(ssq [c][j], mo);
        }
        if (tx == 0){
          atomicAdd(&osum[c*64 + ty*4 + j], ssum[c][j]);
          atomicAdd(&osq [c*64 + ty*4 + j], ssq [c][j]);
        }
      }
  }
}

__global__ void bn_finalize(const float* sum, const float* sq, const float* g, const float* bb,
                            float* a, float* c, int n){
  int o = blockIdx.x*64 + threadIdx.x;
  if (o >= n) return;
  const float invM = 1.0f/262144.0f;
  float mu = sum[o]*invM;
  float var = sq[o]*invM - mu*mu; var = fmaxf(var, 0.f);
  float inv = 1.0f/sqrtf(var + 1e-5f);
  float av = g[o]*inv;
  a[o] = av; c[o] = bb[o] - mu*av;
}

// ---------------- workspace layout (bytes, 256-aligned) — total ~10.1 MB ----------------
#define OFF_FLAG   0u
#define OFF_FPS    256u
#define OFF_KNN    33024u
#define OFF_STATS  1081600u    // 896 f32: sum0,sq0,sum1,sq1,sum2,sq2 (zeroed)
#define OFF_BNAC   1085184u    // 896 f32: a0,c0,a1,c1,a2,c2
#define OFF_XYZF   1088768u    // B*N*3 f32
#define OFF_W0     1481984u
#define OFF_W1     1499136u
#define OFF_W2     1531904u
#define OFF_GB     1662976u    // 896 f32: g0,b0,g1,b1,g2,b2
#define OFF_PTST   1666816u    // B*N*64 f32 -> ends at 10055424

extern "C" void kernel_launch(void* const* d_in, const int* in_sizes, int n_in,
                              void* d_out, int out_size, void* d_ws, size_t ws_size,
                              hipStream_t stream){
  char* ws = (char*)d_ws;
  int*   flag  = (int*)(ws + OFF_FLAG);
  int*   fpsi  = (int*)(ws + OFF_FPS);
  int*   knn   = (int*)(ws + OFF_KNN);
  float* stats = (float*)(ws + OFF_STATS);
  float* bnac  = (float*)(ws + OFF_BNAC);
  float* xyzf  = (float*)(ws + OFF_XYZF);
  float* w0f   = (float*)(ws + OFF_W0);
  float* w1f   = (float*)(ws + OFF_W1);
  float* w2f   = (float*)(ws + OFF_W2);
  float* gbf   = (float*)(ws + OFF_GB);
  float* ptst  = (float*)(ws + OFF_PTST);

  hipMemsetAsync(ws + OFF_STATS, 0, 896*4, stream);
  detect_kernel<<<1, 256, 0, stream>>>(d_in[1], flag);

  convert_kernel<<<384, 256, 0, stream>>>(d_in[0], xyzf, BB*NN*3, flag);
  convert_kernel<<<17,  256, 0, stream>>>(d_in[2], w0f, 64*67,   flag);
  convert_kernel<<<32,  256, 0, stream>>>(d_in[5], w1f, 128*64,  flag);
  convert_kernel<<<128, 256, 0, stream>>>(d_in[8], w2f, 256*128, flag);
  convert_kernel<<<1, 256, 0, stream>>>(d_in[3],  gbf + 0,   64,  flag);
  convert_kernel<<<1, 256, 0, stream>>>(d_in[4],  gbf + 64,  64,  flag);
  convert_kernel<<<1, 256, 0, stream>>>(d_in[6],  gbf + 128, 128, flag);
  convert_kernel<<<1, 256, 0, stream>>>(d_in[7],  gbf + 256, 128, flag);
  convert_kernel<<<1, 256, 0, stream>>>(d_in[9],  gbf + 384, 256, flag);
  convert_kernel<<<1, 256, 0, stream>>>(d_in[10], gbf + 640, 256, flag);
  transpose_points<<<512, 256, 0, stream>>>(d_in[1], ptst, flag);

  fps_kernel<<<BB, 512, 0, stream>>>(xyzf, fpsi, d_out, flag);
  knn_kernel<<<512, 256, 0, stream>>>(xyzf, fpsi, knn);

  chain_kernel<0><<<512, 256, 0, stream>>>(xyzf, ptst, fpsi, knn, w0f, w1f, w2f, bnac,
                                           stats + 0, stats + 64, d_out, flag);
  bn_finalize<<<1, 64, 0, stream>>>(stats + 0, stats + 64, gbf + 0, gbf + 64, bnac + 0, bnac + 64, 64);

  chain_kernel<1><<<512, 256, 0, stream>>>(xyzf, ptst, fpsi, knn, w0f, w1f, w2f, bnac,
                                           stats + 128, stats + 256, d_out, flag);
  bn_finalize<<<2, 64, 0, stream>>>(stats + 128, stats + 256, gbf + 128, gbf + 256, bnac + 128, bnac + 256, 128);

  chain_kernel<2><<<512, 256, 0, stream>>>(xyzf, ptst, fpsi, knn, w0f, w1f, w2f, bnac,
                                           stats + 384, stats + 640, d_out, flag);
  bn_finalize<<<4, 64, 0, stream>>>(stats + 384, stats + 640, gbf + 384, gbf + 640, bnac + 384, bnac + 640, 256);

  chain_kernel<3><<<4096, 256, 0, stream>>>(xyzf, ptst, fpsi, knn, w0f, w1f, w2f, bnac,
                                            nullptr, nullptr, d_out, flag);
  (void)in_sizes; (void)n_in; (void)out_size; (void)ws_size;
}

// Round 3
// 6302.503 us; speedup vs baseline: 1.1551x; 1.1551x over previous
//
#include <hip/hip_runtime.h>

// Problem constants
#define BB 4
#define NN 8192
#define CC 64
#define SS 2048
#define KK 32
#define MROWS (BB*SS*KK)   // 262144

__device__ __forceinline__ float bf2f(unsigned short u){
  union { unsigned int i; float f; } v; v.i = ((unsigned int)u) << 16; return v.f;
}
__device__ __forceinline__ unsigned short f2bf(float f){
  union { float f; unsigned int i; } v; v.f = f;
  unsigned int u = v.i;
  unsigned int r = (u + 0x7FFFu + ((u >> 16) & 1u)) >> 16;
  return (unsigned short)r;
}

// ---------------- dtype detection ----------------
__global__ void detect_kernel(const void* pts, int* flag){
  __shared__ int cnt;
  if (threadIdx.x == 0) cnt = 0;
  __syncthreads();
  unsigned short u = ((const unsigned short*)pts)[threadIdx.x];
  int e = (u >> 7) & 0xFF;
  if (e != 0 && (e < 112 || e > 143)) atomicAdd(&cnt, 1);
  __syncthreads();
  if (threadIdx.x == 0) *flag = (cnt > 32) ? 1 : 0;
}

__global__ void convert_kernel(const void* src, float* dst, int n, const int* flag){
  int i = blockIdx.x*256 + threadIdx.x;
  if (i >= n) return;
  dst[i] = (*flag != 0) ? ((const float*)src)[i] : bf2f(((const unsigned short*)src)[i]);
}

// (B,C,N) -> (B,N,C) f32, tiled transpose
__global__ __launch_bounds__(256) void transpose_points(const void* pts, float* out, const int* flag){
  __shared__ float tile[64][65];
  int bx = blockIdx.x; int b = bx >> 7; int n0 = (bx & 127) * 64; int tid = threadIdx.x;
  bool isf = (*flag != 0);
  #pragma unroll
  for (int k = 0; k < 16; k++){
    int idx = k*256 + tid; int c = idx >> 6; int ni = idx & 63;
    size_t src = ((size_t)b*CC + c)*NN + n0 + ni;
    tile[c][ni] = isf ? ((const float*)pts)[src] : bf2f(((const unsigned short*)pts)[src]);
  }
  __syncthreads();
  #pragma unroll
  for (int k = 0; k < 16; k++){
    int idx = k*256 + tid; int ni = idx >> 6; int c = idx & 63;
    out[((size_t)b*NN + n0 + ni)*CC + c] = tile[c][ni];
  }
}

// ---------------- FPS v2 ----------------
// 1024 threads, 8 pts/lane in regs. xyz mirrored in LDS for broadcast centroid
// reads (no owner phase). Packed u64 (bits(dmin)<<32 | ~idx) argmax: max value,
// lowest index on ties -> matches np.argmax first-occurrence. One barrier/step
// with double-buffered per-wave results.
__global__ __launch_bounds__(1024, 1) void fps_kernel(const float* xyzf, int* fps_idx,
                                                      void* d_out, const int* flag){
  int b = blockIdx.x, tid = threadIdx.x;
  const float* xb = xyzf + (size_t)b*NN*3;
  __shared__ float sxyz[NN*3];
  __shared__ unsigned long long rv[2][16];
  for (int i = tid; i < NN*3/4; i += 1024)
    ((float4*)sxyz)[i] = ((const float4*)xb)[i];
  float px[8], py[8], pz[8], dmin[8];
  unsigned int ipk[8];
  #pragma unroll
  for (int j = 0; j < 8; j++){
    int p = tid + j*1024;
    px[j] = xb[p*3]; py[j] = xb[p*3+1]; pz[j] = xb[p*3+2];
    dmin[j] = 1e10f; ipk[j] = ~(unsigned)p;
  }
  __syncthreads();
  int far = 0;
  bool isf32 = (*flag != 0);
  float* outf = (float*)d_out; unsigned short* outh = (unsigned short*)d_out;
  int wv = tid >> 6, ln = tid & 63;
  for (int s = 0; s < SS; s++){
    float cx = sxyz[far*3], cy = sxyz[far*3+1], cz = sxyz[far*3+2];
    if (tid == 0){
      fps_idx[b*SS + s] = far;
      size_t o = ((size_t)b*SS + s)*3;
      if (isf32){ outf[o]=cx; outf[o+1]=cy; outf[o+2]=cz; }
      else { outh[o]=f2bf(cx); outh[o+1]=f2bf(cy); outh[o+2]=f2bf(cz); }
    }
    // per-lane best over 8 points: track (float, packed-idx) then pack once
    float bv = -1.0f; unsigned bip = 0u;
    {
      #pragma clang fp contract(off)
      #pragma unroll
      for (int j = 0; j < 8; j++){
        float dx = px[j]-cx, dy = py[j]-cy, dz = pz[j]-cz;
        float d = dx*dx + dy*dy + dz*dz;
        float nd = fminf(dmin[j], d); dmin[j] = nd;
        if (nd > bv){ bv = nd; bip = ipk[j]; }   // strict > keeps lowest j (=lowest idx)
      }
    }
    union { float f; unsigned u; } cvt; cvt.f = bv;
    unsigned long long best = ((unsigned long long)cvt.u << 32) | bip;
    #pragma unroll
    for (int off = 1; off < 64; off <<= 1){
      unsigned long long o2 = __shfl_xor(best, off);
      if (o2 > best) best = o2;
    }
    if (ln == 0) rv[s & 1][wv] = best;
    __syncthreads();
    unsigned long long v = rv[s & 1][ln & 15];
    #pragma unroll
    for (int off = 1; off < 16; off <<= 1){
      unsigned long long o2 = __shfl_xor(v, off);
      if (o2 > v) v = o2;
    }
    far = (int)(~(unsigned)v);
  }
}

// ---------------- kNN ----------------
__global__ __launch_bounds__(256) void knn_kernel(const float* xyzf, const int* fps_idx, int* knn){
  int blk = blockIdx.x; int b = blk >> 7; int s0 = (blk & 127) * 16; int tid = threadIdx.x;
  const float* xb = xyzf + (size_t)b*NN*3;
  __shared__ float scc[3]; __shared__ float rv[4]; __shared__ int ri[4];
  __shared__ float swv; __shared__ int swi;
  for (int ci = 0; ci < 16; ci++){
    int s = s0 + ci;
    if (tid == 0){
      int f = fps_idx[b*SS + s];
      scc[0] = xb[f*3]; scc[1] = xb[f*3+1]; scc[2] = xb[f*3+2];
    }
    __syncthreads();
    float cx = scc[0], cy = scc[1], cz = scc[2];
    float dv[32];
    float lmv = 3e38f; int lmi = 0x7FFFFFFF;
    {
      #pragma clang fp contract(off)
      #pragma unroll
      for (int q = 0; q < 8; q++){
        const float4* p4 = (const float4*)(xb + (size_t)tid*96 + q*12);
        float4 A = p4[0], B = p4[1], C = p4[2];
        float xs_[4] = {A.x, A.w, B.z, C.y};
        float ys_[4] = {A.y, B.x, B.w, C.z};
        float zs_[4] = {A.z, B.y, C.x, C.w};
        #pragma unroll
        for (int r = 0; r < 4; r++){
          float dx = cx - xs_[r], dy = cy - ys_[r], dz = cz - zs_[r];
          float d = dx*dx + dy*dy + dz*dz;
          int t = q*4 + r; dv[t] = d;
          int p = tid*32 + t;
          if (d < lmv || (d == lmv && p < lmi)){ lmv = d; lmi = p; }
        }
      }
    }
    int out_base = ((b*SS + s) << 5);
    for (int r = 0; r < 32; r++){
      float v = lmv; int i2 = lmi;
      #pragma unroll
      for (int off = 32; off; off >>= 1){
        float ov = __shfl_down(v, off); int oi = __shfl_down(i2, off);
        if (ov < v || (ov == v && oi < i2)){ v = ov; i2 = oi; }
      }
      if ((tid & 63) == 0){ rv[tid >> 6] = v; ri[tid >> 6] = i2; }
      __syncthreads();
      if (tid == 0){
        float wv = rv[0]; int wi = ri[0];
        #pragma unroll
        for (int q = 1; q < 4; q++){
          if (rv[q] < wv || (rv[q] == wv && ri[q] < wi)){ wv = rv[q]; wi = ri[q]; }
        }
        swv = wv; swi = wi; knn[out_base + r] = wi;
      }
      __syncthreads();
      float wv = swv; int wi = swi;
      if (lmi == wi){
        lmv = 3e38f; lmi = 0x7FFFFFFF;
        #pragma unroll
        for (int t = 0; t < 32; t++){
          int p = tid*32 + t; float d = dv[t];
          bool alive = (d > wv) || (d == wv && p > wi);
          if (alive && (d < lmv || (d == lmv && p < lmi))){ lmv = d; lmi = p; }
        }
      }
    }
  }
}

// ---------------- fused recompute chain ----------------
__device__ __forceinline__ void mm64(const float (*xs)[68], float (*wbb)[64],
    const float* __restrict__ w, int IN, int KP, int obase, int tid, float acc[4][4]){
  int tx = tid & 15, ty = tid >> 4;
  #pragma unroll
  for (int i = 0; i < 4; i++)
    #pragma unroll
    for (int j = 0; j < 4; j++) acc[i][j] = 0.f;
  for (int k0 = 0; k0 < KP; k0 += 16){
    __syncthreads();
    {
      int o = tid & 63, kb = (tid >> 6) << 2;
      const float* wrow = w + (size_t)(obase + o) * IN + k0 + kb;
      #pragma unroll
      for (int i2 = 0; i2 < 4; i2++){
        int k = k0 + kb + i2;
        wbb[kb + i2][o] = (k < IN) ? wrow[i2] : 0.f;
      }
    }
    __syncthreads();
    #pragma unroll
    for (int kk = 0; kk < 16; kk++){
      const float4 xv = *(const float4*)&xs[k0 + kk][tx << 2];
      const float4 wv = *(const float4*)&wbb[kk][ty << 2];
      float xr[4] = {xv.x, xv.y, xv.z, xv.w};
      float wr[4] = {wv.x, wv.y, wv.z, wv.w};
      #pragma unroll
      for (int i = 0; i < 4; i++)
        #pragma unroll
        for (int j = 0; j < 4; j++)
          acc[i][j] += xr[i] * wr[j];
    }
  }
}

template<int MODE>
__global__ __launch_bounds__(256) void chain_kernel(
    const float* __restrict__ xyzf, const float* __restrict__ ptst,
    const int* __restrict__ fpsi, const int* __restrict__ knn,
    const float* __restrict__ w0, const float* __restrict__ w1, const float* __restrict__ w2,
    const float* __restrict__ bnac,
    float* osum, float* osq,
    void* d_out, const int* __restrict__ flag)
{
  __shared__ float xb0[80][68];
  __shared__ float wb[16][64];
  __shared__ float xb1[(MODE >= 1) ? 64 : 1][68];
  __shared__ float xb2[(MODE >= 2) ? 128 : 1][68];

  int tid = threadIdx.x, tx = tid & 15, ty = tid >> 4;
  constexpr int TILES = (MODE == 3) ? 1 : 8;
  constexpr int NCH = (MODE == 0) ? 1 : (MODE == 1) ? 2 : 4;
  float ssum[NCH][4], ssq[NCH][4];
  if (MODE < 3){
    #pragma unroll
    for (int c = 0; c < NCH; c++)
      #pragma unroll
      for (int j = 0; j < 4; j++){ ssum[c][j] = 0.f; ssq[c][j] = 0.f; }
  }
  bool isf32 = (MODE == 3) ? (*flag != 0) : false;

  for (int t = 0; t < TILES; t++){
    int row0 = (blockIdx.x * TILES + t) * 64;
    {
      int r = tid >> 2, p = tid & 3;
      int g = row0 + r;
      int b = g >> 16, s = (g >> 5) & 2047;
      int n = knn[g];
      const float* xb = xyzf + (size_t)b*NN*3;
      if (p == 0){
        int f = fpsi[(b << 11) + s];
        xb0[0][r] = xb[n*3]   - xb[f*3];
        xb0[1][r] = xb[n*3+1] - xb[f*3+1];
        xb0[2][r] = xb[n*3+2] - xb[f*3+2];
      }
      const float4* pr = (const float4*)(ptst + ((size_t)b*NN + n)*CC);
      #pragma unroll
      for (int q = 0; q < 4; q++){
        float4 v = pr[p*4 + q];
        int k = 3 + p*16 + q*4;
        xb0[k][r] = v.x; xb0[k+1][r] = v.y; xb0[k+2][r] = v.z; xb0[k+3][r] = v.w;
      }
      if (p == 3){
        #pragma unroll
        for (int k = 67; k < 80; k++) xb0[k][r] = 0.f;
      }
    }

    float acc[4][4];
    mm64(xb0, wb, w0, 67, 80, 0, tid, acc);
    if (MODE == 0){
      #pragma unroll
      for (int j = 0; j < 4; j++){
        float s0 = acc[0][j] + acc[1][j] + acc[2][j] + acc[3][j];
        float q0 = acc[0][j]*acc[0][j] + acc[1][j]*acc[1][j] + acc[2][j]*acc[2][j] + acc[3][j]*acc[3][j];
        ssum[0][j] += s0; ssq[0][j] += q0;
      }
    } else {
      #pragma unroll
      for (int j = 0; j < 4; j++){
        int o = ty*4 + j;
        float a = bnac[o], c = bnac[64 + o];
        #pragma unroll
        for (int i = 0; i < 4; i++)
          xb1[o][tx*4 + i] = fmaxf(acc[i][j]*a + c, 0.f);
      }
    }

    if (MODE >= 1){
      #pragma unroll
      for (int ch = 0; ch < 2; ch++){
        mm64(xb1, wb, w1, 64, 64, ch*64, tid, acc);
        if (MODE == 1){
          #pragma unroll
          for (int j = 0; j < 4; j++){
            float s0 = acc[0][j] + acc[1][j] + acc[2][j] + acc[3][j];
            float q0 = acc[0][j]*acc[0][j] + acc[1][j]*acc[1][j] + acc[2][j]*acc[2][j] + acc[3][j]*acc[3][j];
            ssum[ch][j] += s0; ssq[ch][j] += q0;
          }
        } else {
          #pragma unroll
          for (int j = 0; j < 4; j++){
            int o = ch*64 + ty*4 + j;
            float a = bnac[128 + o], c = bnac[256 + o];
            #pragma unroll
            for (int i = 0; i < 4; i++)
              xb2[o][tx*4 + i] = fmaxf(acc[i][j]*a + c, 0.f);
          }
        }
      }
    }

    if (MODE >= 2){
      #pragma unroll
      for (int ch = 0; ch < 4; ch++){
        mm64(xb2, wb, w2, 128, 128, ch*64, tid, acc);
        if (MODE == 2){
          #pragma unroll
          for (int j = 0; j < 4; j++){
            float s0 = acc[0][j] + acc[1][j] + acc[2][j] + acc[3][j];
            float q0 = acc[0][j]*acc[0][j] + acc[1][j]*acc[1][j] + acc[2][j]*acc[2][j] + acc[3][j]*acc[3][j];
            ssum[ch][j] += s0; ssq[ch][j] += q0;
          }
        } else {
          float m[4];
          #pragma unroll
          for (int j = 0; j < 4; j++){
            int o = ch*64 + ty*4 + j;
            float a = bnac[384 + o], c = bnac[640 + o];
            float v = fmaxf(fmaxf(acc[0][j]*a + c, acc[1][j]*a + c),
                            fmaxf(acc[2][j]*a + c, acc[3][j]*a + c));
            m[j] = fmaxf(v, 0.f);
          }
          #pragma unroll
          for (int mo = 1; mo < 8; mo <<= 1){
            #pragma unroll
            for (int j = 0; j < 4; j++) m[j] = fmaxf(m[j], __shfl_xor(m[j], mo));
          }
          if ((tx & 7) == 0){
            int cglob = (row0 >> 5) + (tx >> 3);
            int b = cglob >> 11, s = cglob & 2047;
            #pragma unroll
            for (int j = 0; j < 4; j++){
              int o = ch*64 + ty*4 + j;
              size_t oo = (size_t)BB*SS*3 + (((size_t)(b*256 + o)) << 11) + s;
              if (isf32) ((float*)d_out)[oo] = m[j];
              else ((unsigned short*)d_out)[oo] = f2bf(m[j]);
            }
          }
        }
      }
    }
    __syncthreads();
  }

  if (MODE < 3){
    #pragma unroll
    for (int c = 0; c < NCH; c++)
      #pragma unroll
      for (int j = 0; j < 4; j++){
        #pragma unroll
        for (int mo = 1; mo < 16; mo <<= 1){
          ssum[c][j] += __shfl_xor(ssum[c][j], mo);
          ssq [c][j] += __shfl_xor(ssq [c][j], mo);
        }
        if (tx == 0){
          atomicAdd(&osum[c*64 + ty*4 + j], ssum[c][j]);
          atomicAdd(&osq [c*64 + ty*4 + j], ssq [c][j]);
        }
      }
  }
}

__global__ void bn_finalize(const float* sum, const float* sq, const float* g, const float* bb,
                            float* a, float* c, int n){
  int o = blockIdx.x*64 + threadIdx.x;
  if (o >= n) return;
  const float invM = 1.0f/262144.0f;
  float mu = sum[o]*invM;
  float var = sq[o]*invM - mu*mu; var = fmaxf(var, 0.f);
  float inv = 1.0f/sqrtf(var + 1e-5f);
  float av = g[o]*inv;
  a[o] = av; c[o] = bb[o] - mu*av;
}

// ---------------- workspace layout (bytes, 256-aligned) — total ~10.1 MB ----------------
#define OFF_FLAG   0u
#define OFF_FPS    256u
#define OFF_KNN    33024u
#define OFF_STATS  1081600u
#define OFF_BNAC   1085184u
#define OFF_XYZF   1088768u
#define OFF_W0     1481984u
#define OFF_W1     1499136u
#define OFF_W2     1531904u
#define OFF_GB     1662976u
#define OFF_PTST   1666816u

extern "C" void kernel_launch(void* const* d_in, const int* in_sizes, int n_in,
                              void* d_out, int out_size, void* d_ws, size_t ws_size,
                              hipStream_t stream){
  char* ws = (char*)d_ws;
  int*   flag  = (int*)(ws + OFF_FLAG);
  int*   fpsi  = (int*)(ws + OFF_FPS);
  int*   knn   = (int*)(ws + OFF_KNN);
  float* stats = (float*)(ws + OFF_STATS);
  float* bnac  = (float*)(ws + OFF_BNAC);
  float* xyzf  = (float*)(ws + OFF_XYZF);
  float* w0f   = (float*)(ws + OFF_W0);
  float* w1f   = (float*)(ws + OFF_W1);
  float* w2f   = (float*)(ws + OFF_W2);
  float* gbf   = (float*)(ws + OFF_GB);
  float* ptst  = (float*)(ws + OFF_PTST);

  hipMemsetAsync(ws + OFF_STATS, 0, 896*4, stream);
  detect_kernel<<<1, 256, 0, stream>>>(d_in[1], flag);

  convert_kernel<<<384, 256, 0, stream>>>(d_in[0], xyzf, BB*NN*3, flag);
  convert_kernel<<<17,  256, 0, stream>>>(d_in[2], w0f, 64*67,   flag);
  convert_kernel<<<32,  256, 0, stream>>>(d_in[5], w1f, 128*64,  flag);
  convert_kernel<<<128, 256, 0, stream>>>(d_in[8], w2f, 256*128, flag);
  convert_kernel<<<1, 256, 0, stream>>>(d_in[3],  gbf + 0,   64,  flag);
  convert_kernel<<<1, 256, 0, stream>>>(d_in[4],  gbf + 64,  64,  flag);
  convert_kernel<<<1, 256, 0, stream>>>(d_in[6],  gbf + 128, 128, flag);
  convert_kernel<<<1, 256, 0, stream>>>(d_in[7],  gbf + 256, 128, flag);
  convert_kernel<<<1, 256, 0, stream>>>(d_in[9],  gbf + 384, 256, flag);
  convert_kernel<<<1, 256, 0, stream>>>(d_in[10], gbf + 640, 256, flag);
  transpose_points<<<512, 256, 0, stream>>>(d_in[1], ptst, flag);

  fps_kernel<<<BB, 1024, 0, stream>>>(xyzf, fpsi, d_out, flag);
  knn_kernel<<<512, 256, 0, stream>>>(xyzf, fpsi, knn);

  chain_kernel<0><<<512, 256, 0, stream>>>(xyzf, ptst, fpsi, knn, w0f, w1f, w2f, bnac,
                                           stats + 0, stats + 64, d_out, flag);
  bn_finalize<<<1, 64, 0, stream>>>(stats + 0, stats + 64, gbf + 0, gbf + 64, bnac + 0, bnac + 64, 64);

  chain_kernel<1><<<512, 256, 0, stream>>>(xyzf, ptst, fpsi, knn, w0f, w1f, w2f, bnac,
                                           stats + 128, stats + 256, d_out, flag);
  bn_finalize<<<2, 64, 0, stream>>>(stats + 128, stats + 256, gbf + 128, gbf + 256, bnac + 128, bnac + 256, 128);

  chain_kernel<2><<<512, 256, 0, stream>>>(xyzf, ptst, fpsi, knn, w0f, w1f, w2f, bnac,
                                           stats + 384, stats + 640, d_out, flag);
  bn_finalize<<<4, 64, 0, stream>>>(stats + 384, stats + 640, gbf + 384, gbf + 640, bnac + 384, bnac + 640, 256);

  chain_kernel<3><<<4096, 256, 0, stream>>>(xyzf, ptst, fpsi, knn, w0f, w1f, w2f, bnac,
                                            nullptr, nullptr, d_out, flag);
  (void)in_sizes; (void)n_in; (void)out_size; (void)ws_size;
}

// Round 4
// 5282.014 us; speedup vs baseline: 1.3783x; 1.1932x over previous
//
#include <hip/hip_runtime.h>

#define BB 4
#define NN 8192
#define CC 64
#define SS 2048
#define KK 32
#define MROWS (BB*SS*KK)   // 262144

typedef __attribute__((ext_vector_type(8))) short bf16x8_t;
typedef __attribute__((ext_vector_type(4))) float f32x4_t;

__device__ __forceinline__ float bf2f(unsigned short u){
  union { unsigned int i; float f; } v; v.i = ((unsigned int)u) << 16; return v.f;
}
__device__ __forceinline__ unsigned short f2bf(float f){
  union { float f; unsigned int i; } v; v.f = f;
  unsigned int u = v.i;
  unsigned int r = (u + 0x7FFFu + ((u >> 16) & 1u)) >> 16;
  return (unsigned short)r;
}

// ---------------- dtype detection ----------------
__global__ void detect_kernel(const void* pts, int* flag){
  __shared__ int cnt;
  if (threadIdx.x == 0) cnt = 0;
  __syncthreads();
  unsigned short u = ((const unsigned short*)pts)[threadIdx.x];
  int e = (u >> 7) & 0xFF;
  if (e != 0 && (e < 112 || e > 143)) atomicAdd(&cnt, 1);
  __syncthreads();
  if (threadIdx.x == 0) *flag = (cnt > 32) ? 1 : 0;
}

__global__ void convert_kernel(const void* src, float* dst, int n, const int* flag){
  int i = blockIdx.x*256 + threadIdx.x;
  if (i >= n) return;
  dst[i] = (*flag != 0) ? ((const float*)src)[i] : bf2f(((const unsigned short*)src)[i]);
}

// (B,C,N) -> (B,N,C) bf16
__global__ __launch_bounds__(256) void transpose_pts_bf16(const void* pts, unsigned short* out, const int* flag){
  __shared__ float tile[64][65];
  int bx = blockIdx.x; int b = bx >> 7; int n0 = (bx & 127) * 64; int tid = threadIdx.x;
  bool isf = (*flag != 0);
  #pragma unroll
  for (int k = 0; k < 16; k++){
    int idx = k*256 + tid; int c = idx >> 6; int ni = idx & 63;
    size_t src = ((size_t)b*CC + c)*NN + n0 + ni;
    tile[c][ni] = isf ? ((const float*)pts)[src] : bf2f(((const unsigned short*)pts)[src]);
  }
  __syncthreads();
  #pragma unroll
  for (int k = 0; k < 16; k++){
    int idx = k*256 + tid; int ni = idx >> 6; int c = idx & 63;
    out[((size_t)b*NN + n0 + ni)*CC + c] = f2bf(tile[c][ni]);
  }
}

// pack weights into MFMA B-fragment order (bf16):
// dst[f*512 + lane*8 + j] = W[ct*16 + (lane&15)][ks*32 + (lane>>4)*8 + j], f = ct*KSTEPS+ks
// remap (layer0): feature order is [points(64), xyz(3), pad...]; source col = k<64 ? k+3 : (k<67 ? k-64 : none)
__global__ void pack_w(const void* src, unsigned short* dst, int CTS, int KSTEPS, int IN, int remap, const int* flag){
  int idx = blockIdx.x*256 + threadIdx.x;
  int total = CTS*KSTEPS*512;
  if (idx >= total) return;
  int f = idx >> 9, lane = (idx >> 3) & 63, j = idx & 7;
  int ct = f / KSTEPS, ks = f % KSTEPS;
  int n = ct*16 + (lane & 15);
  int k = ks*32 + (lane >> 4)*8 + j;
  int ksrc;
  if (remap){ ksrc = (k < 64) ? (k + 3) : (k < 67 ? k - 64 : -1); }
  else      { ksrc = (k < IN) ? k : -1; }
  float v = 0.f;
  if (ksrc >= 0){
    size_t si = (size_t)n*IN + ksrc;
    v = (*flag != 0) ? ((const float*)src)[si] : bf2f(((const unsigned short*)src)[si]);
  }
  dst[idx] = f2bf(v);
}

// ---------------- DPP helpers (VALU-pipe cross-lane max on packed u64) ----------------
template<int CTRL>
__device__ __forceinline__ void dppmax64(unsigned &lo, unsigned &hi){
  unsigned olo = (unsigned)__builtin_amdgcn_update_dpp(0, (int)lo, CTRL, 0xF, 0xF, true);
  unsigned ohi = (unsigned)__builtin_amdgcn_update_dpp(0, (int)hi, CTRL, 0xF, 0xF, true);
  if (ohi > hi || (ohi == hi && olo > lo)){ lo = olo; hi = ohi; }
}

// ---------------- FPS v3: DPP reductions (DS-pipe relief) ----------------
__global__ __launch_bounds__(1024, 1) void fps_kernel(const float* xyzf, int* fps_idx,
                                                      void* d_out, const int* flag){
  int b = blockIdx.x, tid = threadIdx.x;
  const float* xb = xyzf + (size_t)b*NN*3;
  __shared__ float sxyz[NN*3];
  __shared__ unsigned long long rv[2][16];
  for (int i = tid; i < NN*3/4; i += 1024)
    ((float4*)sxyz)[i] = ((const float4*)xb)[i];
  float px[8], py[8], pz[8], dmin[8];
  unsigned int ipk[8];
  #pragma unroll
  for (int j = 0; j < 8; j++){
    int p = tid + j*1024;
    px[j] = xb[p*3]; py[j] = xb[p*3+1]; pz[j] = xb[p*3+2];
    dmin[j] = 1e10f; ipk[j] = ~(unsigned)p;
  }
  __syncthreads();
  int far = 0;
  bool isf32 = (*flag != 0);
  float* outf = (float*)d_out; unsigned short* outh = (unsigned short*)d_out;
  int wv = tid >> 6, ln = tid & 63;
  for (int s = 0; s < SS; s++){
    float cx = sxyz[far*3], cy = sxyz[far*3+1], cz = sxyz[far*3+2];
    if (tid == 0){
      fps_idx[b*SS + s] = far;
      size_t o = ((size_t)b*SS + s)*3;
      if (isf32){ outf[o]=cx; outf[o+1]=cy; outf[o+2]=cz; }
      else { outh[o]=f2bf(cx); outh[o+1]=f2bf(cy); outh[o+2]=f2bf(cz); }
    }
    float bv = -1.0f; unsigned bip = 0u;
    {
      #pragma clang fp contract(off)
      #pragma unroll
      for (int j = 0; j < 8; j++){
        float dx = px[j]-cx, dy = py[j]-cy, dz = pz[j]-cz;
        float d = dx*dx + dy*dy + dz*dz;
        float nd = fminf(dmin[j], d); dmin[j] = nd;
        if (nd > bv){ bv = nd; bip = ipk[j]; }
      }
    }
    union { float f; unsigned u; } cvt; cvt.f = bv;
    unsigned lo = bip, hi = cvt.u;
    // wave64 max -> lane 63 (rocPRIM pattern), all on VALU pipe
    dppmax64<0x111>(lo, hi);  // row_shr:1
    dppmax64<0x112>(lo, hi);  // row_shr:2
    dppmax64<0x114>(lo, hi);  // row_shr:4
    dppmax64<0x118>(lo, hi);  // row_shr:8
    dppmax64<0x142>(lo, hi);  // row_bcast:15
    dppmax64<0x143>(lo, hi);  // row_bcast:31
    if (ln == 63) rv[s & 1][wv] = ((unsigned long long)hi << 32) | lo;
    __syncthreads();
    unsigned long long t = rv[s & 1][ln & 15];
    unsigned tlo = (unsigned)t, thi = (unsigned)(t >> 32);
    dppmax64<0x111>(tlo, thi);
    dppmax64<0x112>(tlo, thi);
    dppmax64<0x114>(tlo, thi);
    dppmax64<0x118>(tlo, thi);
    far = (int)(~(unsigned)__builtin_amdgcn_readlane((int)tlo, 63));
  }
}

// ---------------- kNN (unchanged) ----------------
__global__ __launch_bounds__(256) void knn_kernel(const float* xyzf, const int* fps_idx, int* knn){
  int blk = blockIdx.x; int b = blk >> 7; int s0 = (blk & 127) * 16; int tid = threadIdx.x;
  const float* xb = xyzf + (size_t)b*NN*3;
  __shared__ float scc[3]; __shared__ float rv[4]; __shared__ int ri[4];
  __shared__ float swv; __shared__ int swi;
  for (int ci = 0; ci < 16; ci++){
    int s = s0 + ci;
    if (tid == 0){
      int f = fps_idx[b*SS + s];
      scc[0] = xb[f*3]; scc[1] = xb[f*3+1]; scc[2] = xb[f*3+2];
    }
    __syncthreads();
    float cx = scc[0], cy = scc[1], cz = scc[2];
    float dv[32];
    float lmv = 3e38f; int lmi = 0x7FFFFFFF;
    {
      #pragma clang fp contract(off)
      #pragma unroll
      for (int q = 0; q < 8; q++){
        const float4* p4 = (const float4*)(xb + (size_t)tid*96 + q*12);
        float4 A = p4[0], B = p4[1], C = p4[2];
        float xs_[4] = {A.x, A.w, B.z, C.y};
        float ys_[4] = {A.y, B.x, B.w, C.z};
        float zs_[4] = {A.z, B.y, C.x, C.w};
        #pragma unroll
        for (int r = 0; r < 4; r++){
          float dx = cx - xs_[r], dy = cy - ys_[r], dz = cz - zs_[r];
          float d = dx*dx + dy*dy + dz*dz;
          int t = q*4 + r; dv[t] = d;
          int p = tid*32 + t;
          if (d < lmv || (d == lmv && p < lmi)){ lmv = d; lmi = p; }
        }
      }
    }
    int out_base = ((b*SS + s) << 5);
    for (int r = 0; r < 32; r++){
      float v = lmv; int i2 = lmi;
      #pragma unroll
      for (int off = 32; off; off >>= 1){
        float ov = __shfl_down(v, off); int oi = __shfl_down(i2, off);
        if (ov < v || (ov == v && oi < i2)){ v = ov; i2 = oi; }
      }
      if ((tid & 63) == 0){ rv[tid >> 6] = v; ri[tid >> 6] = i2; }
      __syncthreads();
      if (tid == 0){
        float wv = rv[0]; int wi = ri[0];
        #pragma unroll
        for (int q = 1; q < 4; q++){
          if (rv[q] < wv || (rv[q] == wv && ri[q] < wi)){ wv = rv[q]; wi = ri[q]; }
        }
        swv = wv; swi = wi; knn[out_base + r] = wi;
      }
      __syncthreads();
      float wv = swv; int wi = swi;
      if (lmi == wi){
        lmv = 3e38f; lmi = 0x7FFFFFFF;
        #pragma unroll
        for (int t = 0; t < 32; t++){
          int p = tid*32 + t; float d = dv[t];
          bool alive = (d > wv) || (d == wv && p > wi);
          if (alive && (d < lmv || (d == lmv && p < lmi))){ lmv = d; lmi = p; }
        }
      }
    }
  }
}

// ---------------- MFMA recompute chain ----------------
// 64-row tile, 4 waves; wave w owns rows [w*16, w*16+16) end-to-end (barrier-free).
// Feature order layer0: [points(64), xyz(3), pad->96]. Weights pre-packed as B-frags.
// MODE 0/1/2: per-channel sum/sumsq of y0/y1/y2 (8 tiles/block). MODE 3: full chain + maxpool.

__device__ __forceinline__ bf16x8_t bfrag(const unsigned short* wp, int f, int lane){
  return *(const bf16x8_t*)(wp + ((size_t)f << 9) + (lane << 3));
}

template<int MODE>
__global__ __launch_bounds__(256) void chain_mfma(
    const float* __restrict__ xyzf, const unsigned short* __restrict__ ptsb,
    const int* __restrict__ fpsi, const int* __restrict__ knn,
    const unsigned short* __restrict__ w0p, const unsigned short* __restrict__ w1p,
    const unsigned short* __restrict__ w2p,
    const float* __restrict__ bnac, float* osum, float* osq,
    void* d_out, const int* __restrict__ flag)
{
  __shared__ unsigned short xb0[64*104];
  __shared__ unsigned short xb1[(MODE >= 1) ? 64*72 : 8];
  __shared__ unsigned short xb2[(MODE >= 2) ? 64*136 : 8];
  __shared__ float sacc[(MODE < 3) ? 512 : 1];
  __shared__ float smax[(MODE == 3) ? 1024 : 1];

  int tid = threadIdx.x, lane = tid & 63, w = tid >> 6;
  int l15 = lane & 15, quad = lane >> 4;
  constexpr int TILES = (MODE == 3) ? 1 : 8;
  constexpr int NCT = (MODE == 0) ? 4 : (MODE == 1) ? 8 : 16;  // coltiles tracked for stats

  float ssum[(MODE < 3) ? NCT : 1], ssq[(MODE < 3) ? NCT : 1];
  if (MODE < 3){
    #pragma unroll
    for (int c = 0; c < NCT; c++){ ssum[c] = 0.f; ssq[c] = 0.f; }
    sacc[tid] = 0.f; sacc[tid + 256] = 0.f;
    __syncthreads();
  }

  for (int t = 0; t < TILES; t++){
    int row0 = (blockIdx.x * TILES + t) * 64;
    // ---- gather into xb0 (A-frag layout, stride 104) ----
    {
      int r = tid >> 2, p = tid & 3;
      int g = row0 + r;
      int bq = g >> 16, s = (g >> 5) & 2047;
      int n = knn[g];
      const bf16x8_t* pr = (const bf16x8_t*)(ptsb + (((size_t)bq*NN + n) << 6));
      *(bf16x8_t*)&xb0[r*104 + p*16]     = pr[p*2];
      *(bf16x8_t*)&xb0[r*104 + p*16 + 8] = pr[p*2 + 1];
      if (p == 3){
        const float* xbp = xyzf + (size_t)bq*NN*3;
        int f = fpsi[(bq << 11) + s];
        float dx = xbp[n*3]   - xbp[f*3];
        float dy = xbp[n*3+1] - xbp[f*3+1];
        float dz = xbp[n*3+2] - xbp[f*3+2];
        bf16x8_t v = {(short)f2bf(dx), (short)f2bf(dy), (short)f2bf(dz), 0,0,0,0,0};
        bf16x8_t z = {0,0,0,0,0,0,0,0};
        *(bf16x8_t*)&xb0[r*104 + 64] = v;
        *(bf16x8_t*)&xb0[r*104 + 72] = z;
        *(bf16x8_t*)&xb0[r*104 + 80] = z;
        *(bf16x8_t*)&xb0[r*104 + 88] = z;
      }
    }
    // (no barrier: wave w wrote exactly the rows it reads)

    // ---- L0: K=96 (3 ksteps), OUT=64 (4 coltiles) ----
    bf16x8_t a0[3];
    #pragma unroll
    for (int ks = 0; ks < 3; ks++)
      a0[ks] = *(const bf16x8_t*)&xb0[(w*16 + l15)*104 + ks*32 + quad*8];
    f32x4_t acc0[4];
    #pragma unroll
    for (int ct = 0; ct < 4; ct++){
      f32x4_t a = {0.f,0.f,0.f,0.f};
      #pragma unroll
      for (int ks = 0; ks < 3; ks++)
        a = __builtin_amdgcn_mfma_f32_16x16x32_bf16(a0[ks], bfrag(w0p, ct*3+ks, lane), a, 0, 0, 0);
      acc0[ct] = a;
    }
    if (MODE == 0){
      #pragma unroll
      for (int ct = 0; ct < 4; ct++)
        #pragma unroll
        for (int r = 0; r < 4; r++){ float v = acc0[ct][r]; ssum[ct] += v; ssq[ct] += v*v; }
    } else {
      #pragma unroll
      for (int ct = 0; ct < 4; ct++){
        int o = ct*16 + l15;
        float ga = bnac[o], gc = bnac[64 + o];
        #pragma unroll
        for (int r = 0; r < 4; r++)
          xb1[(w*16 + quad*4 + r)*72 + o] = f2bf(fmaxf(acc0[ct][r]*ga + gc, 0.f));
      }
    }

    if (MODE >= 1){
      // ---- L1: K=64 (2 ksteps), OUT=128 (8 coltiles) ----
      bf16x8_t a1[2];
      #pragma unroll
      for (int ks = 0; ks < 2; ks++)
        a1[ks] = *(const bf16x8_t*)&xb1[(w*16 + l15)*72 + ks*32 + quad*8];
      f32x4_t acc1[8];
      #pragma unroll
      for (int ct = 0; ct < 8; ct++){
        f32x4_t a = {0.f,0.f,0.f,0.f};
        #pragma unroll
        for (int ks = 0; ks < 2; ks++)
          a = __builtin_amdgcn_mfma_f32_16x16x32_bf16(a1[ks], bfrag(w1p, ct*2+ks, lane), a, 0, 0, 0);
        acc1[ct] = a;
      }
      if (MODE == 1){
        #pragma unroll
        for (int ct = 0; ct < 8; ct++)
          #pragma unroll
          for (int r = 0; r < 4; r++){ float v = acc1[ct][r]; ssum[ct] += v; ssq[ct] += v*v; }
      } else {
        #pragma unroll
        for (int ct = 0; ct < 8; ct++){
          int o = ct*16 + l15;
          float ga = bnac[128 + o], gc = bnac[256 + o];
          #pragma unroll
          for (int r = 0; r < 4; r++)
            xb2[(w*16 + quad*4 + r)*136 + o] = f2bf(fmaxf(acc1[ct][r]*ga + gc, 0.f));
        }
      }
    }

    if (MODE >= 2){
      // ---- L2: K=128 (4 ksteps), OUT=256 (16 coltiles) ----
      bf16x8_t a2[4];
      #pragma unroll
      for (int ks = 0; ks < 4; ks++)
        a2[ks] = *(const bf16x8_t*)&xb2[(w*16 + l15)*136 + ks*32 + quad*8];
      #pragma unroll
      for (int ct = 0; ct < 16; ct++){
        f32x4_t a = {0.f,0.f,0.f,0.f};
        #pragma unroll
        for (int ks = 0; ks < 4; ks++)
          a = __builtin_amdgcn_mfma_f32_16x16x32_bf16(a2[ks], bfrag(w2p, ct*4+ks, lane), a, 0, 0, 0);
        if (MODE == 2){
          #pragma unroll
          for (int r = 0; r < 4; r++){ float v = a[r]; ssum[ct] += v; ssq[ct] += v*v; }
        } else {
          int o = ct*16 + l15;
          float ga = bnac[384 + o], gc = bnac[640 + o];
          float m = fmaxf(fmaxf(a[0]*ga + gc, a[1]*ga + gc), fmaxf(a[2]*ga + gc, a[3]*ga + gc));
          m = fmaxf(m, __shfl_xor(m, 16));
          m = fmaxf(m, __shfl_xor(m, 32));
          if (quad == 0) smax[w*256 + o] = m;
        }
      }
    }
  }

  if (MODE < 3){
    #pragma unroll
    for (int c = 0; c < NCT; c++){
      ssum[c] += __shfl_xor(ssum[c], 16); ssum[c] += __shfl_xor(ssum[c], 32);
      ssq [c] += __shfl_xor(ssq [c], 16); ssq [c] += __shfl_xor(ssq [c], 32);
    }
    if (quad == 0){
      #pragma unroll
      for (int c = 0; c < NCT; c++){
        atomicAdd(&sacc[c*16 + l15], ssum[c]);
        atomicAdd(&sacc[256 + c*16 + l15], ssq[c]);
      }
    }
    __syncthreads();
    if (tid < NCT*16){
      atomicAdd(&osum[tid], sacc[tid]);
      atomicAdd(&osq [tid], sacc[256 + tid]);
    }
  } else {
    __syncthreads();
    // two centroids per block: waves 0,1 -> cg, waves 2,3 -> cg+1
    float v0 = fmaxf(fmaxf(smax[tid], smax[256 + tid]), 0.f);
    float v1 = fmaxf(fmaxf(smax[512 + tid], smax[768 + tid]), 0.f);
    int cg = blockIdx.x * 2;
    bool isf32 = (*flag != 0);
    int b0 = cg >> 11, s0 = cg & 2047;
    int b1 = (cg+1) >> 11, s1 = (cg+1) & 2047;
    size_t o0 = (size_t)BB*SS*3 + (((size_t)(b0*256 + tid)) << 11) + s0;
    size_t o1 = (size_t)BB*SS*3 + (((size_t)(b1*256 + tid)) << 11) + s1;
    if (isf32){ ((float*)d_out)[o0] = v0; ((float*)d_out)[o1] = v1; }
    else { ((unsigned short*)d_out)[o0] = f2bf(v0); ((unsigned short*)d_out)[o1] = f2bf(v1); }
  }
}

__global__ void bn_finalize(const float* sum, const float* sq, const float* g, const float* bb,
                            float* a, float* c, int n){
  int o = blockIdx.x*64 + threadIdx.x;
  if (o >= n) return;
  const float invM = 1.0f/262144.0f;
  float mu = sum[o]*invM;
  float var = sq[o]*invM - mu*mu; var = fmaxf(var, 0.f);
  float inv = 1.0f/sqrtf(var + 1e-5f);
  float av = g[o]*inv;
  a[o] = av; c[o] = bb[o] - mu*av;
}

// ---------------- workspace layout (bytes) — total ~5.8 MB ----------------
#define OFF_FLAG   0u
#define OFF_FPS    256u
#define OFF_KNN    33024u
#define OFF_STATS  1081600u    // 896 f32 (zeroed)
#define OFF_BNAC   1085184u    // 896 f32
#define OFF_XYZF   1088768u    // B*N*3 f32
#define OFF_GB     1481984u    // 896 f32
#define OFF_W0P    1485568u    // 6144 bf16
#define OFF_W1P    1497856u    // 8192 bf16
#define OFF_W2P    1514240u    // 32768 bf16
#define OFF_PTSB   1579776u    // B*N*64 bf16

extern "C" void kernel_launch(void* const* d_in, const int* in_sizes, int n_in,
                              void* d_out, int out_size, void* d_ws, size_t ws_size,
                              hipStream_t stream){
  char* ws = (char*)d_ws;
  int*   flag  = (int*)(ws + OFF_FLAG);
  int*   fpsi  = (int*)(ws + OFF_FPS);
  int*   knn   = (int*)(ws + OFF_KNN);
  float* stats = (float*)(ws + OFF_STATS);
  float* bnac  = (float*)(ws + OFF_BNAC);
  float* xyzf  = (float*)(ws + OFF_XYZF);
  float* gbf   = (float*)(ws + OFF_GB);
  unsigned short* w0p = (unsigned short*)(ws + OFF_W0P);
  unsigned short* w1p = (unsigned short*)(ws + OFF_W1P);
  unsigned short* w2p = (unsigned short*)(ws + OFF_W2P);
  unsigned short* ptsb = (unsigned short*)(ws + OFF_PTSB);

  hipMemsetAsync(ws + OFF_STATS, 0, 896*4, stream);
  detect_kernel<<<1, 256, 0, stream>>>(d_in[1], flag);

  convert_kernel<<<384, 256, 0, stream>>>(d_in[0], xyzf, BB*NN*3, flag);
  convert_kernel<<<1, 256, 0, stream>>>(d_in[3],  gbf + 0,   64,  flag);
  convert_kernel<<<1, 256, 0, stream>>>(d_in[4],  gbf + 64,  64,  flag);
  convert_kernel<<<1, 256, 0, stream>>>(d_in[6],  gbf + 128, 128, flag);
  convert_kernel<<<1, 256, 0, stream>>>(d_in[7],  gbf + 256, 128, flag);
  convert_kernel<<<1, 256, 0, stream>>>(d_in[9],  gbf + 384, 256, flag);
  convert_kernel<<<1, 256, 0, stream>>>(d_in[10], gbf + 640, 256, flag);
  transpose_pts_bf16<<<512, 256, 0, stream>>>(d_in[1], ptsb, flag);

  pack_w<<<24,  256, 0, stream>>>(d_in[2], w0p, 4, 3, 67, 1, flag);
  pack_w<<<32,  256, 0, stream>>>(d_in[5], w1p, 8, 2, 64, 0, flag);
  pack_w<<<128, 256, 0, stream>>>(d_in[8], w2p, 16, 4, 128, 0, flag);

  fps_kernel<<<BB, 1024, 0, stream>>>(xyzf, fpsi, d_out, flag);
  knn_kernel<<<512, 256, 0, stream>>>(xyzf, fpsi, knn);

  chain_mfma<0><<<512, 256, 0, stream>>>(xyzf, ptsb, fpsi, knn, w0p, w1p, w2p, bnac,
                                         stats + 0, stats + 64, d_out, flag);
  bn_finalize<<<1, 64, 0, stream>>>(stats + 0, stats + 64, gbf + 0, gbf + 64, bnac + 0, bnac + 64, 64);

  chain_mfma<1><<<512, 256, 0, stream>>>(xyzf, ptsb, fpsi, knn, w0p, w1p, w2p, bnac,
                                         stats + 128, stats + 256, d_out, flag);
  bn_finalize<<<2, 64, 0, stream>>>(stats + 128, stats + 256, gbf + 128, gbf + 256, bnac + 128, bnac + 256, 128);

  chain_mfma<2><<<512, 256, 0, stream>>>(xyzf, ptsb, fpsi, knn, w0p, w1p, w2p, bnac,
                                         stats + 384, stats + 640, d_out, flag);
  bn_finalize<<<4, 64, 0, stream>>>(stats + 384, stats + 640, gbf + 384, gbf + 640, bnac + 384, bnac + 640, 256);

  chain_mfma<3><<<4096, 256, 0, stream>>>(xyzf, ptsb, fpsi, knn, w0p, w1p, w2p, bnac,
                                          nullptr, nullptr, d_out, flag);
  (void)in_sizes; (void)n_in; (void)out_size; (void)ws_size;
}

// Round 5
// 4657.984 us; speedup vs baseline: 1.5629x; 1.1340x over previous
//
#include <hip/hip_runtime.h>

#define BB 4
#define NN 8192
#define CC 64
#define SS 2048
#define KK 32
#define MROWS (BB*SS*KK)   // 262144

typedef __attribute__((ext_vector_type(8))) short bf16x8_t;
typedef __attribute__((ext_vector_type(4))) float f32x4_t;
typedef __attribute__((ext_vector_type(2))) float f32x2_t;

__device__ __forceinline__ float bf2f(unsigned short u){
  union { unsigned int i; float f; } v; v.i = ((unsigned int)u) << 16; return v.f;
}
__device__ __forceinline__ unsigned short f2bf(float f){
  union { float f; unsigned int i; } v; v.f = f;
  unsigned int u = v.i;
  unsigned int r = (u + 0x7FFFu + ((u >> 16) & 1u)) >> 16;
  return (unsigned short)r;
}
__device__ __forceinline__ float i2f(int i){ union { int i; float f; } v; v.i = i; return v.f; }
__device__ __forceinline__ int f2i(float f){ union { float f; int i; } v; v.f = f; return v.i; }

// ---------------- dtype detection ----------------
__global__ void detect_kernel(const void* pts, int* flag){
  __shared__ int cnt;
  if (threadIdx.x == 0) cnt = 0;
  __syncthreads();
  unsigned short u = ((const unsigned short*)pts)[threadIdx.x];
  int e = (u >> 7) & 0xFF;
  if (e != 0 && (e < 112 || e > 143)) atomicAdd(&cnt, 1);
  __syncthreads();
  if (threadIdx.x == 0) *flag = (cnt > 32) ? 1 : 0;
}

__global__ void convert_kernel(const void* src, float* dst, int n, const int* flag){
  int i = blockIdx.x*256 + threadIdx.x;
  if (i >= n) return;
  dst[i] = (*flag != 0) ? ((const float*)src)[i] : bf2f(((const unsigned short*)src)[i]);
}

// (B,C,N) -> (B,N,C) bf16
__global__ __launch_bounds__(256) void transpose_pts_bf16(const void* pts, unsigned short* out, const int* flag){
  __shared__ float tile[64][65];
  int bx = blockIdx.x; int b = bx >> 7; int n0 = (bx & 127) * 64; int tid = threadIdx.x;
  bool isf = (*flag != 0);
  #pragma unroll
  for (int k = 0; k < 16; k++){
    int idx = k*256 + tid; int c = idx >> 6; int ni = idx & 63;
    size_t src = ((size_t)b*CC + c)*NN + n0 + ni;
    tile[c][ni] = isf ? ((const float*)pts)[src] : bf2f(((const unsigned short*)pts)[src]);
  }
  __syncthreads();
  #pragma unroll
  for (int k = 0; k < 16; k++){
    int idx = k*256 + tid; int ni = idx >> 6; int c = idx & 63;
    out[((size_t)b*NN + n0 + ni)*CC + c] = f2bf(tile[c][ni]);
  }
}

// pack weights into MFMA B-fragment order (bf16)
__global__ void pack_w(const void* src, unsigned short* dst, int CTS, int KSTEPS, int IN, int remap, const int* flag){
  int idx = blockIdx.x*256 + threadIdx.x;
  int total = CTS*KSTEPS*512;
  if (idx >= total) return;
  int f = idx >> 9, lane = (idx >> 3) & 63, j = idx & 7;
  int ct = f / KSTEPS, ks = f % KSTEPS;
  int n = ct*16 + (lane & 15);
  int k = ks*32 + (lane >> 4)*8 + j;
  int ksrc;
  if (remap){ ksrc = (k < 64) ? (k + 3) : (k < 67 ? k - 64 : -1); }
  else      { ksrc = (k < IN) ? k : -1; }
  float v = 0.f;
  if (ksrc >= 0){
    size_t si = (size_t)n*IN + ksrc;
    v = (*flag != 0) ? ((const float*)src)[si] : bf2f(((const unsigned short*)src)[si]);
  }
  dst[idx] = f2bf(v);
}

// ---------------- DPP helpers ----------------
template<int C>
__device__ __forceinline__ float dpp_maxf(float v){
  int t = __builtin_amdgcn_update_dpp(0, f2i(v), C, 0xF, 0xF, true);
  return fmaxf(v, i2f(t));
}
template<int C>
__device__ __forceinline__ unsigned dpp_minu(unsigned v){
  unsigned t = (unsigned)__builtin_amdgcn_update_dpp(-1, (int)v, C, 0xF, 0xF, false);
  return v < t ? v : t;
}
template<int C>
__device__ __forceinline__ void dpp_max64(unsigned &lo, unsigned &hi){
  unsigned tlo = (unsigned)__builtin_amdgcn_update_dpp(0, (int)lo, C, 0xF, 0xF, true);
  unsigned thi = (unsigned)__builtin_amdgcn_update_dpp(0, (int)hi, C, 0xF, 0xF, true);
  if (thi > hi || (thi == hi && tlo > lo)){ lo = tlo; hi = thi; }
}

// ---------------- FPS v4 ----------------
// Packed-f32 distance update (v_pk_add/mul), value-only wave max (f32 DPP),
// index recovered by equality scan + u32 DPP min, single barrier per step with
// double-buffered u64 cross-wave table.
__global__ __launch_bounds__(1024, 1) void fps_kernel(const float* xyzf, int* fps_idx,
                                                      void* d_out, const int* flag){
  int b = blockIdx.x, tid = threadIdx.x;
  const float* xb = xyzf + (size_t)b*NN*3;
  __shared__ float sxyz[NN*3];
  __shared__ unsigned long long ru[2][16];
  for (int i = tid; i < NN*3/4; i += 1024)
    ((float4*)sxyz)[i] = ((const float4*)xb)[i];
  // pair packing: element e of pair q is point tid + (2q+e)*1024
  f32x2_t px2[4], py2[4], pz2[4], dmin2[4];
  #pragma unroll
  for (int q = 0; q < 4; q++){
    int p0 = tid + (2*q)*1024, p1 = tid + (2*q+1)*1024;
    px2[q] = (f32x2_t){xb[p0*3],   xb[p1*3]};
    py2[q] = (f32x2_t){xb[p0*3+1], xb[p1*3+1]};
    pz2[q] = (f32x2_t){xb[p0*3+2], xb[p1*3+2]};
    dmin2[q] = (f32x2_t){1e10f, 1e10f};
  }
  __syncthreads();
  int far = 0;
  bool isf32 = (*flag != 0);
  float* outf = (float*)d_out; unsigned short* outh = (unsigned short*)d_out;
  int w = tid >> 6, ln = tid & 63;
  for (int s = 0; s < SS; s++){
    float cx = sxyz[far*3], cy = sxyz[far*3+1], cz = sxyz[far*3+2];
    if (tid == 0){
      fps_idx[b*SS + s] = far;
      size_t o = ((size_t)b*SS + s)*3;
      if (isf32){ outf[o]=cx; outf[o+1]=cy; outf[o+2]=cz; }
      else { outh[o]=f2bf(cx); outh[o+1]=f2bf(cy); outh[o+2]=f2bf(cz); }
    }
    f32x2_t cx2 = (f32x2_t){cx, cx}, cy2 = (f32x2_t){cy, cy}, cz2 = (f32x2_t){cz, cz};
    {
      #pragma clang fp contract(off)
      #pragma unroll
      for (int q = 0; q < 4; q++){
        f32x2_t dx = px2[q] - cx2, dy = py2[q] - cy2, dz = pz2[q] - cz2;
        f32x2_t t = dx*dx;
        t = t + dy*dy;
        t = t + dz*dz;
        dmin2[q].x = fminf(dmin2[q].x, t.x);
        dmin2[q].y = fminf(dmin2[q].y, t.y);
      }
    }
    // lane max of 8 dmin values
    float m0 = fmaxf(fmaxf(dmin2[0].x, dmin2[0].y), fmaxf(dmin2[1].x, dmin2[1].y));
    float m1 = fmaxf(fmaxf(dmin2[2].x, dmin2[2].y), fmaxf(dmin2[3].x, dmin2[3].y));
    float lm = fmaxf(m0, m1);
    // wave max via f32 DPP (VALU, single-reg)
    lm = dpp_maxf<0x111>(lm); lm = dpp_maxf<0x112>(lm);
    lm = dpp_maxf<0x114>(lm); lm = dpp_maxf<0x118>(lm);
    lm = dpp_maxf<0x142>(lm); lm = dpp_maxf<0x143>(lm);
    float wmax = i2f(__builtin_amdgcn_readlane(f2i(lm), 63));
    // lowest index achieving wmax in this wave
    unsigned cand = 0xFFFFFFFFu;
    #pragma unroll
    for (int q = 3; q >= 0; q--){
      if (dmin2[q].y == wmax) cand = (unsigned)(tid + (2*q+1)*1024);
      if (dmin2[q].x == wmax) cand = (unsigned)(tid + (2*q)*1024);
    }
    cand = dpp_minu<0x111>(cand); cand = dpp_minu<0x112>(cand);
    cand = dpp_minu<0x114>(cand); cand = dpp_minu<0x118>(cand);
    cand = dpp_minu<0x142>(cand); cand = dpp_minu<0x143>(cand);
    if (ln == 63)
      ru[s & 1][w] = ((unsigned long long)(unsigned)f2i(wmax) << 32) | (unsigned)(~cand);
    __syncthreads();
    unsigned long long t = ru[s & 1][ln & 15];
    unsigned lo = (unsigned)t, hi = (unsigned)(t >> 32);
    dpp_max64<0x111>(lo, hi); dpp_max64<0x112>(lo, hi);
    dpp_max64<0x114>(lo, hi); dpp_max64<0x118>(lo, hi);
    far = (int)(~(unsigned)__builtin_amdgcn_readlane((int)lo, 63));
  }
}

// ---------------- kNN ----------------
__global__ __launch_bounds__(256) void knn_kernel(const float* xyzf, const int* fps_idx, int* knn){
  int blk = blockIdx.x; int b = blk >> 7; int s0 = (blk & 127) * 16; int tid = threadIdx.x;
  const float* xb = xyzf + (size_t)b*NN*3;
  __shared__ float scc[3]; __shared__ float rv[4]; __shared__ int ri[4];
  __shared__ float swv; __shared__ int swi;
  for (int ci = 0; ci < 16; ci++){
    int s = s0 + ci;
    if (tid == 0){
      int f = fps_idx[b*SS + s];
      scc[0] = xb[f*3]; scc[1] = xb[f*3+1]; scc[2] = xb[f*3+2];
    }
    __syncthreads();
    float cx = scc[0], cy = scc[1], cz = scc[2];
    float dv[32];
    float lmv = 3e38f; int lmi = 0x7FFFFFFF;
    {
      #pragma clang fp contract(off)
      #pragma unroll
      for (int q = 0; q < 8; q++){
        const float4* p4 = (const float4*)(xb + (size_t)tid*96 + q*12);
        float4 A = p4[0], B = p4[1], C = p4[2];
        float xs_[4] = {A.x, A.w, B.z, C.y};
        float ys_[4] = {A.y, B.x, B.w, C.z};
        float zs_[4] = {A.z, B.y, C.x, C.w};
        #pragma unroll
        for (int r = 0; r < 4; r++){
          float dx = cx - xs_[r], dy = cy - ys_[r], dz = cz - zs_[r];
          float d = dx*dx + dy*dy + dz*dz;
          int t = q*4 + r; dv[t] = d;
          int p = tid*32 + t;
          if (d < lmv || (d == lmv && p < lmi)){ lmv = d; lmi = p; }
        }
      }
    }
    int out_base = ((b*SS + s) << 5);
    for (int r = 0; r < 32; r++){
      float v = lmv; int i2 = lmi;
      #pragma unroll
      for (int off = 32; off; off >>= 1){
        float ov = __shfl_down(v, off); int oi = __shfl_down(i2, off);
        if (ov < v || (ov == v && oi < i2)){ v = ov; i2 = oi; }
      }
      if ((tid & 63) == 0){ rv[tid >> 6] = v; ri[tid >> 6] = i2; }
      __syncthreads();
      if (tid == 0){
        float wv = rv[0]; int wi = ri[0];
        #pragma unroll
        for (int q = 1; q < 4; q++){
          if (rv[q] < wv || (rv[q] == wv && ri[q] < wi)){ wv = rv[q]; wi = ri[q]; }
        }
        swv = wv; swi = wi; knn[out_base + r] = wi;
      }
      __syncthreads();
      float wv = swv; int wi = swi;
      if (lmi == wi){
        lmv = 3e38f; lmi = 0x7FFFFFFF;
        #pragma unroll
        for (int t = 0; t < 32; t++){
          int p = tid*32 + t; float d = dv[t];
          bool alive = (d > wv) || (d == wv && p > wi);
          if (alive && (d < lmv || (d == lmv && p < lmi))){ lmv = d; lmi = p; }
        }
      }
    }
  }
}

// ---------------- MFMA recompute chain ----------------
__device__ __forceinline__ bf16x8_t bfrag(const unsigned short* wp, int f, int lane){
  return *(const bf16x8_t*)(wp + ((size_t)f << 9) + (lane << 3));
}

template<int MODE>
__global__ __launch_bounds__(256) void chain_mfma(
    const float* __restrict__ xyzf, const unsigned short* __restrict__ ptsb,
    const int* __restrict__ fpsi, const int* __restrict__ knn,
    const unsigned short* __restrict__ w0p, const unsigned short* __restrict__ w1p,
    const unsigned short* __restrict__ w2p,
    const float* __restrict__ bnac, float* osum, float* osq,
    void* d_out, const int* __restrict__ flag)
{
  __shared__ unsigned short xb0[64*104];
  __shared__ unsigned short xb1[(MODE >= 1) ? 64*72 : 8];
  __shared__ unsigned short xb2[(MODE >= 2) ? 64*136 : 8];
  __shared__ float sacc[(MODE < 3) ? 512 : 1];
  __shared__ float smax[(MODE == 3) ? 1024 : 1];

  int tid = threadIdx.x, lane = tid & 63, w = tid >> 6;
  int l15 = lane & 15, quad = lane >> 4;
  constexpr int TILES = (MODE == 3) ? 1 : 8;
  constexpr int NCT = (MODE == 0) ? 4 : (MODE == 1) ? 8 : 16;

  float ssum[(MODE < 3) ? NCT : 1], ssq[(MODE < 3) ? NCT : 1];
  if (MODE < 3){
    #pragma unroll
    for (int c = 0; c < NCT; c++){ ssum[c] = 0.f; ssq[c] = 0.f; }
    sacc[tid] = 0.f; sacc[tid + 256] = 0.f;
    __syncthreads();
  }

  for (int t = 0; t < TILES; t++){
    int row0 = (blockIdx.x * TILES + t) * 64;
    {
      int r = tid >> 2, p = tid & 3;
      int g = row0 + r;
      int bq = g >> 16, s = (g >> 5) & 2047;
      int n = knn[g];
      const bf16x8_t* pr = (const bf16x8_t*)(ptsb + (((size_t)bq*NN + n) << 6));
      *(bf16x8_t*)&xb0[r*104 + p*16]     = pr[p*2];
      *(bf16x8_t*)&xb0[r*104 + p*16 + 8] = pr[p*2 + 1];
      if (p == 3){
        const float* xbp = xyzf + (size_t)bq*NN*3;
        int f = fpsi[(bq << 11) + s];
        float dx = xbp[n*3]   - xbp[f*3];
        float dy = xbp[n*3+1] - xbp[f*3+1];
        float dz = xbp[n*3+2] - xbp[f*3+2];
        bf16x8_t v = {(short)f2bf(dx), (short)f2bf(dy), (short)f2bf(dz), 0,0,0,0,0};
        bf16x8_t z = {0,0,0,0,0,0,0,0};
        *(bf16x8_t*)&xb0[r*104 + 64] = v;
        *(bf16x8_t*)&xb0[r*104 + 72] = z;
        *(bf16x8_t*)&xb0[r*104 + 80] = z;
        *(bf16x8_t*)&xb0[r*104 + 88] = z;
      }
    }

    bf16x8_t a0[3];
    #pragma unroll
    for (int ks = 0; ks < 3; ks++)
      a0[ks] = *(const bf16x8_t*)&xb0[(w*16 + l15)*104 + ks*32 + quad*8];
    f32x4_t acc0[4];
    #pragma unroll
    for (int ct = 0; ct < 4; ct++){
      f32x4_t a = {0.f,0.f,0.f,0.f};
      #pragma unroll
      for (int ks = 0; ks < 3; ks++)
        a = __builtin_amdgcn_mfma_f32_16x16x32_bf16(a0[ks], bfrag(w0p, ct*3+ks, lane), a, 0, 0, 0);
      acc0[ct] = a;
    }
    if (MODE == 0){
      #pragma unroll
      for (int ct = 0; ct < 4; ct++)
        #pragma unroll
        for (int r = 0; r < 4; r++){ float v = acc0[ct][r]; ssum[ct] += v; ssq[ct] += v*v; }
    } else {
      #pragma unroll
      for (int ct = 0; ct < 4; ct++){
        int o = ct*16 + l15;
        float ga = bnac[o], gc = bnac[64 + o];
        #pragma unroll
        for (int r = 0; r < 4; r++)
          xb1[(w*16 + quad*4 + r)*72 + o] = f2bf(fmaxf(acc0[ct][r]*ga + gc, 0.f));
      }
    }

    if (MODE >= 1){
      bf16x8_t a1[2];
      #pragma unroll
      for (int ks = 0; ks < 2; ks++)
        a1[ks] = *(const bf16x8_t*)&xb1[(w*16 + l15)*72 + ks*32 + quad*8];
      f32x4_t acc1[8];
      #pragma unroll
      for (int ct = 0; ct < 8; ct++){
        f32x4_t a = {0.f,0.f,0.f,0.f};
        #pragma unroll
        for (int ks = 0; ks < 2; ks++)
          a = __builtin_amdgcn_mfma_f32_16x16x32_bf16(a1[ks], bfrag(w1p, ct*2+ks, lane), a, 0, 0, 0);
        acc1[ct] = a;
      }
      if (MODE == 1){
        #pragma unroll
        for (int ct = 0; ct < 8; ct++)
          #pragma unroll
          for (int r = 0; r < 4; r++){ float v = acc1[ct][r]; ssum[ct] += v; ssq[ct] += v*v; }
      } else {
        #pragma unroll
        for (int ct = 0; ct < 8; ct++){
          int o = ct*16 + l15;
          float ga = bnac[128 + o], gc = bnac[256 + o];
          #pragma unroll
          for (int r = 0; r < 4; r++)
            xb2[(w*16 + quad*4 + r)*136 + o] = f2bf(fmaxf(acc1[ct][r]*ga + gc, 0.f));
        }
      }
    }

    if (MODE >= 2){
      bf16x8_t a2[4];
      #pragma unroll
      for (int ks = 0; ks < 4; ks++)
        a2[ks] = *(const bf16x8_t*)&xb2[(w*16 + l15)*136 + ks*32 + quad*8];
      #pragma unroll
      for (int ct = 0; ct < 16; ct++){
        f32x4_t a = {0.f,0.f,0.f,0.f};
        #pragma unroll
        for (int ks = 0; ks < 4; ks++)
          a = __builtin_amdgcn_mfma_f32_16x16x32_bf16(a2[ks], bfrag(w2p, ct*4+ks, lane), a, 0, 0, 0);
        if (MODE == 2){
          #pragma unroll
          for (int r = 0; r < 4; r++){ float v = a[r]; ssum[ct] += v; ssq[ct] += v*v; }
        } else {
          int o = ct*16 + l15;
          float ga = bnac[384 + o], gc = bnac[640 + o];
          float m = fmaxf(fmaxf(a[0]*ga + gc, a[1]*ga + gc), fmaxf(a[2]*ga + gc, a[3]*ga + gc));
          m = fmaxf(m, __shfl_xor(m, 16));
          m = fmaxf(m, __shfl_xor(m, 32));
          if (quad == 0) smax[w*256 + o] = m;
        }
      }
    }
  }

  if (MODE < 3){
    #pragma unroll
    for (int c = 0; c < NCT; c++){
      ssum[c] += __shfl_xor(ssum[c], 16); ssum[c] += __shfl_xor(ssum[c], 32);
      ssq [c] += __shfl_xor(ssq [c], 16); ssq [c] += __shfl_xor(ssq [c], 32);
    }
    if (quad == 0){
      #pragma unroll
      for (int c = 0; c < NCT; c++){
        atomicAdd(&sacc[c*16 + l15], ssum[c]);
        atomicAdd(&sacc[256 + c*16 + l15], ssq[c]);
      }
    }
    __syncthreads();
    if (tid < NCT*16){
      atomicAdd(&osum[tid], sacc[tid]);
      atomicAdd(&osq [tid], sacc[256 + tid]);
    }
  } else {
    __syncthreads();
    float v0 = fmaxf(fmaxf(smax[tid], smax[256 + tid]), 0.f);
    float v1 = fmaxf(fmaxf(smax[512 + tid], smax[768 + tid]), 0.f);
    int cg = blockIdx.x * 2;
    bool isf32 = (*flag != 0);
    int b0 = cg >> 11, s0 = cg & 2047;
    int b1 = (cg+1) >> 11, s1 = (cg+1) & 2047;
    size_t o0 = (size_t)BB*SS*3 + (((size_t)(b0*256 + tid)) << 11) + s0;
    size_t o1 = (size_t)BB*SS*3 + (((size_t)(b1*256 + tid)) << 11) + s1;
    if (isf32){ ((float*)d_out)[o0] = v0; ((float*)d_out)[o1] = v1; }
    else { ((unsigned short*)d_out)[o0] = f2bf(v0); ((unsigned short*)d_out)[o1] = f2bf(v1); }
  }
}

__global__ void bn_finalize(const float* sum, const float* sq, const float* g, const float* bb,
                            float* a, float* c, int n){
  int o = blockIdx.x*64 + threadIdx.x;
  if (o >= n) return;
  const float invM = 1.0f/262144.0f;
  float mu = sum[o]*invM;
  float var = sq[o]*invM - mu*mu; var = fmaxf(var, 0.f);
  float inv = 1.0f/sqrtf(var + 1e-5f);
  float av = g[o]*inv;
  a[o] = av; c[o] = bb[o] - mu*av;
}

// ---------------- workspace layout ----------------
#define OFF_FLAG   0u
#define OFF_FPS    256u
#define OFF_KNN    33024u
#define OFF_STATS  1081600u
#define OFF_BNAC   1085184u
#define OFF_XYZF   1088768u
#define OFF_GB     1481984u
#define OFF_W0P    1485568u
#define OFF_W1P    1497856u
#define OFF_W2P    1514240u
#define OFF_PTSB   1579776u

extern "C" void kernel_launch(void* const* d_in, const int* in_sizes, int n_in,
                              void* d_out, int out_size, void* d_ws, size_t ws_size,
                              hipStream_t stream){
  char* ws = (char*)d_ws;
  int*   flag  = (int*)(ws + OFF_FLAG);
  int*   fpsi  = (int*)(ws + OFF_FPS);
  int*   knn   = (int*)(ws + OFF_KNN);
  float* stats = (float*)(ws + OFF_STATS);
  float* bnac  = (float*)(ws + OFF_BNAC);
  float* xyzf  = (float*)(ws + OFF_XYZF);
  float* gbf   = (float*)(ws + OFF_GB);
  unsigned short* w0p = (unsigned short*)(ws + OFF_W0P);
  unsigned short* w1p = (unsigned short*)(ws + OFF_W1P);
  unsigned short* w2p = (unsigned short*)(ws + OFF_W2P);
  unsigned short* ptsb = (unsigned short*)(ws + OFF_PTSB);

  hipMemsetAsync(ws + OFF_STATS, 0, 896*4, stream);
  detect_kernel<<<1, 256, 0, stream>>>(d_in[1], flag);

  convert_kernel<<<384, 256, 0, stream>>>(d_in[0], xyzf, BB*NN*3, flag);
  convert_kernel<<<1, 256, 0, stream>>>(d_in[3],  gbf + 0,   64,  flag);
  convert_kernel<<<1, 256, 0, stream>>>(d_in[4],  gbf + 64,  64,  flag);
  convert_kernel<<<1, 256, 0, stream>>>(d_in[6],  gbf + 128, 128, flag);
  convert_kernel<<<1, 256, 0, stream>>>(d_in[7],  gbf + 256, 128, flag);
  convert_kernel<<<1, 256, 0, stream>>>(d_in[9],  gbf + 384, 256, flag);
  convert_kernel<<<1, 256, 0, stream>>>(d_in[10], gbf + 640, 256, flag);
  transpose_pts_bf16<<<512, 256, 0, stream>>>(d_in[1], ptsb, flag);

  pack_w<<<24,  256, 0, stream>>>(d_in[2], w0p, 4, 3, 67, 1, flag);
  pack_w<<<32,  256, 0, stream>>>(d_in[5], w1p, 8, 2, 64, 0, flag);
  pack_w<<<128, 256, 0, stream>>>(d_in[8], w2p, 16, 4, 128, 0, flag);

  fps_kernel<<<BB, 1024, 0, stream>>>(xyzf, fpsi, d_out, flag);
  knn_kernel<<<512, 256, 0, stream>>>(xyzf, fpsi, knn);

  chain_mfma<0><<<512, 256, 0, stream>>>(xyzf, ptsb, fpsi, knn, w0p, w1p, w2p, bnac,
                                         stats + 0, stats + 64, d_out, flag);
  bn_finalize<<<1, 64, 0, stream>>>(stats + 0, stats + 64, gbf + 0, gbf + 64, bnac + 0, bnac + 64, 64);

  chain_mfma<1><<<512, 256, 0, stream>>>(xyzf, ptsb, fpsi, knn, w0p, w1p, w2p, bnac,
                                         stats + 128, stats + 256, d_out, flag);
  bn_finalize<<<2, 64, 0, stream>>>(stats + 128, stats + 256, gbf + 128, gbf + 256, bnac + 128, bnac + 256, 128);

  chain_mfma<2><<<512, 256, 0, stream>>>(xyzf, ptsb, fpsi, knn, w0p, w1p, w2p, bnac,
                                         stats + 384, stats + 640, d_out, flag);
  bn_finalize<<<4, 64, 0, stream>>>(stats + 384, stats + 640, gbf + 384, gbf + 640, bnac + 384, bnac + 640, 256);

  chain_mfma<3><<<4096, 256, 0, stream>>>(xyzf, ptsb, fpsi, knn, w0p, w1p, w2p, bnac,
                                          nullptr, nullptr, d_out, flag);
  (void)in_sizes; (void)n_in; (void)out_size; (void)ws_size;
}

// Round 6
// 4649.256 us; speedup vs baseline: 1.5659x; 1.0019x over previous
//
#include <hip/hip_runtime.h>

#define BB 4
#define NN 8192
#define CC 64
#define SS 2048
#define KK 32
#define MROWS (BB*SS*KK)   // 262144

typedef __attribute__((ext_vector_type(8))) short bf16x8_t;
typedef __attribute__((ext_vector_type(4))) float f32x4_t;
typedef __attribute__((ext_vector_type(2))) float f32x2_t;

__device__ __forceinline__ float bf2f(unsigned short u){
  union { unsigned int i; float f; } v; v.i = ((unsigned int)u) << 16; return v.f;
}
__device__ __forceinline__ unsigned short f2bf(float f){
  union { float f; unsigned int i; } v; v.f = f;
  unsigned int u = v.i;
  unsigned int r = (u + 0x7FFFu + ((u >> 16) & 1u)) >> 16;
  return (unsigned short)r;
}
__device__ __forceinline__ float i2f(int i){ union { int i; float f; } v; v.i = i; return v.f; }
__device__ __forceinline__ int f2i(float f){ union { float f; int i; } v; v.f = f; return v.i; }

// ---------------- dtype detection ----------------
__global__ void detect_kernel(const void* pts, int* flag){
  __shared__ int cnt;
  if (threadIdx.x == 0) cnt = 0;
  __syncthreads();
  unsigned short u = ((const unsigned short*)pts)[threadIdx.x];
  int e = (u >> 7) & 0xFF;
  if (e != 0 && (e < 112 || e > 143)) atomicAdd(&cnt, 1);
  __syncthreads();
  if (threadIdx.x == 0) *flag = (cnt > 32) ? 1 : 0;
}

__global__ void convert_kernel(const void* src, float* dst, int n, const int* flag){
  int i = blockIdx.x*256 + threadIdx.x;
  if (i >= n) return;
  dst[i] = (*flag != 0) ? ((const float*)src)[i] : bf2f(((const unsigned short*)src)[i]);
}

// (B,C,N) -> (B,N,C) bf16
__global__ __launch_bounds__(256) void transpose_pts_bf16(const void* pts, unsigned short* out, const int* flag){
  __shared__ float tile[64][65];
  int bx = blockIdx.x; int b = bx >> 7; int n0 = (bx & 127) * 64; int tid = threadIdx.x;
  bool isf = (*flag != 0);
  #pragma unroll
  for (int k = 0; k < 16; k++){
    int idx = k*256 + tid; int c = idx >> 6; int ni = idx & 63;
    size_t src = ((size_t)b*CC + c)*NN + n0 + ni;
    tile[c][ni] = isf ? ((const float*)pts)[src] : bf2f(((const unsigned short*)pts)[src]);
  }
  __syncthreads();
  #pragma unroll
  for (int k = 0; k < 16; k++){
    int idx = k*256 + tid; int ni = idx >> 6; int c = idx & 63;
    out[((size_t)b*NN + n0 + ni)*CC + c] = f2bf(tile[c][ni]);
  }
}

// pack weights into MFMA B-fragment order (bf16)
__global__ void pack_w(const void* src, unsigned short* dst, int CTS, int KSTEPS, int IN, int remap, const int* flag){
  int idx = blockIdx.x*256 + threadIdx.x;
  int total = CTS*KSTEPS*512;
  if (idx >= total) return;
  int f = idx >> 9, lane = (idx >> 3) & 63, j = idx & 7;
  int ct = f / KSTEPS, ks = f % KSTEPS;
  int n = ct*16 + (lane & 15);
  int k = ks*32 + (lane >> 4)*8 + j;
  int ksrc;
  if (remap){ ksrc = (k < 64) ? (k + 3) : (k < 67 ? k - 64 : -1); }
  else      { ksrc = (k < IN) ? k : -1; }
  float v = 0.f;
  if (ksrc >= 0){
    size_t si = (size_t)n*IN + ksrc;
    v = (*flag != 0) ? ((const float*)src)[si] : bf2f(((const unsigned short*)src)[si]);
  }
  dst[idx] = f2bf(v);
}

// ---------------- DPP helpers ----------------
template<int C>
__device__ __forceinline__ float dpp_maxf(float v){
  int t = __builtin_amdgcn_update_dpp(0, f2i(v), C, 0xF, 0xF, true);
  return fmaxf(v, i2f(t));
}
template<int C>
__device__ __forceinline__ unsigned dpp_minu(unsigned v){
  unsigned t = (unsigned)__builtin_amdgcn_update_dpp(-1, (int)v, C, 0xF, 0xF, false);
  return v < t ? v : t;
}
template<int C>
__device__ __forceinline__ void dpp_max64(unsigned &lo, unsigned &hi){
  unsigned tlo = (unsigned)__builtin_amdgcn_update_dpp(0, (int)lo, C, 0xF, 0xF, true);
  unsigned thi = (unsigned)__builtin_amdgcn_update_dpp(0, (int)hi, C, 0xF, 0xF, true);
  if (thi > hi || (thi == hi && tlo > lo)){ lo = tlo; hi = thi; }
}

// ---------------- FPS v4 (unchanged this round) ----------------
__global__ __launch_bounds__(1024, 1) void fps_kernel(const float* xyzf, int* fps_idx,
                                                      void* d_out, const int* flag){
  int b = blockIdx.x, tid = threadIdx.x;
  const float* xb = xyzf + (size_t)b*NN*3;
  __shared__ float sxyz[NN*3];
  __shared__ unsigned long long ru[2][16];
  for (int i = tid; i < NN*3/4; i += 1024)
    ((float4*)sxyz)[i] = ((const float4*)xb)[i];
  f32x2_t px2[4], py2[4], pz2[4], dmin2[4];
  #pragma unroll
  for (int q = 0; q < 4; q++){
    int p0 = tid + (2*q)*1024, p1 = tid + (2*q+1)*1024;
    px2[q] = (f32x2_t){xb[p0*3],   xb[p1*3]};
    py2[q] = (f32x2_t){xb[p0*3+1], xb[p1*3+1]};
    pz2[q] = (f32x2_t){xb[p0*3+2], xb[p1*3+2]};
    dmin2[q] = (f32x2_t){1e10f, 1e10f};
  }
  __syncthreads();
  int far = 0;
  bool isf32 = (*flag != 0);
  float* outf = (float*)d_out; unsigned short* outh = (unsigned short*)d_out;
  int w = tid >> 6, ln = tid & 63;
  for (int s = 0; s < SS; s++){
    float cx = sxyz[far*3], cy = sxyz[far*3+1], cz = sxyz[far*3+2];
    if (tid == 0){
      fps_idx[b*SS + s] = far;
      size_t o = ((size_t)b*SS + s)*3;
      if (isf32){ outf[o]=cx; outf[o+1]=cy; outf[o+2]=cz; }
      else { outh[o]=f2bf(cx); outh[o+1]=f2bf(cy); outh[o+2]=f2bf(cz); }
    }
    f32x2_t cx2 = (f32x2_t){cx, cx}, cy2 = (f32x2_t){cy, cy}, cz2 = (f32x2_t){cz, cz};
    {
      #pragma clang fp contract(off)
      #pragma unroll
      for (int q = 0; q < 4; q++){
        f32x2_t dx = px2[q] - cx2, dy = py2[q] - cy2, dz = pz2[q] - cz2;
        f32x2_t t = dx*dx;
        t = t + dy*dy;
        t = t + dz*dz;
        dmin2[q].x = fminf(dmin2[q].x, t.x);
        dmin2[q].y = fminf(dmin2[q].y, t.y);
      }
    }
    float m0 = fmaxf(fmaxf(dmin2[0].x, dmin2[0].y), fmaxf(dmin2[1].x, dmin2[1].y));
    float m1 = fmaxf(fmaxf(dmin2[2].x, dmin2[2].y), fmaxf(dmin2[3].x, dmin2[3].y));
    float lm = fmaxf(m0, m1);
    lm = dpp_maxf<0x111>(lm); lm = dpp_maxf<0x112>(lm);
    lm = dpp_maxf<0x114>(lm); lm = dpp_maxf<0x118>(lm);
    lm = dpp_maxf<0x142>(lm); lm = dpp_maxf<0x143>(lm);
    float wmax = i2f(__builtin_amdgcn_readlane(f2i(lm), 63));
    unsigned cand = 0xFFFFFFFFu;
    #pragma unroll
    for (int q = 3; q >= 0; q--){
      if (dmin2[q].y == wmax) cand = (unsigned)(tid + (2*q+1)*1024);
      if (dmin2[q].x == wmax) cand = (unsigned)(tid + (2*q)*1024);
    }
    cand = dpp_minu<0x111>(cand); cand = dpp_minu<0x112>(cand);
    cand = dpp_minu<0x114>(cand); cand = dpp_minu<0x118>(cand);
    cand = dpp_minu<0x142>(cand); cand = dpp_minu<0x143>(cand);
    if (ln == 63)
      ru[s & 1][w] = ((unsigned long long)(unsigned)f2i(wmax) << 32) | (unsigned)(~cand);
    __syncthreads();
    unsigned long long t = ru[s & 1][ln & 15];
    unsigned lo = (unsigned)t, hi = (unsigned)(t >> 32);
    dpp_max64<0x111>(lo, hi); dpp_max64<0x112>(lo, hi);
    dpp_max64<0x114>(lo, hi); dpp_max64<0x118>(lo, hi);
    far = (int)(~(unsigned)__builtin_amdgcn_readlane((int)lo, 63));
  }
}

// ---------------- kNN (unchanged) ----------------
__global__ __launch_bounds__(256) void knn_kernel(const float* xyzf, const int* fps_idx, int* knn){
  int blk = blockIdx.x; int b = blk >> 7; int s0 = (blk & 127) * 16; int tid = threadIdx.x;
  const float* xb = xyzf + (size_t)b*NN*3;
  __shared__ float scc[3]; __shared__ float rv[4]; __shared__ int ri[4];
  __shared__ float swv; __shared__ int swi;
  for (int ci = 0; ci < 16; ci++){
    int s = s0 + ci;
    if (tid == 0){
      int f = fps_idx[b*SS + s];
      scc[0] = xb[f*3]; scc[1] = xb[f*3+1]; scc[2] = xb[f*3+2];
    }
    __syncthreads();
    float cx = scc[0], cy = scc[1], cz = scc[2];
    float dv[32];
    float lmv = 3e38f; int lmi = 0x7FFFFFFF;
    {
      #pragma clang fp contract(off)
      #pragma unroll
      for (int q = 0; q < 8; q++){
        const float4* p4 = (const float4*)(xb + (size_t)tid*96 + q*12);
        float4 A = p4[0], B = p4[1], C = p4[2];
        float xs_[4] = {A.x, A.w, B.z, C.y};
        float ys_[4] = {A.y, B.x, B.w, C.z};
        float zs_[4] = {A.z, B.y, C.x, C.w};
        #pragma unroll
        for (int r = 0; r < 4; r++){
          float dx = cx - xs_[r], dy = cy - ys_[r], dz = cz - zs_[r];
          float d = dx*dx + dy*dy + dz*dz;
          int t = q*4 + r; dv[t] = d;
          int p = tid*32 + t;
          if (d < lmv || (d == lmv && p < lmi)){ lmv = d; lmi = p; }
        }
      }
    }
    int out_base = ((b*SS + s) << 5);
    for (int r = 0; r < 32; r++){
      float v = lmv; int i2 = lmi;
      #pragma unroll
      for (int off = 32; off; off >>= 1){
        float ov = __shfl_down(v, off); int oi = __shfl_down(i2, off);
        if (ov < v || (ov == v && oi < i2)){ v = ov; i2 = oi; }
      }
      if ((tid & 63) == 0){ rv[tid >> 6] = v; ri[tid >> 6] = i2; }
      __syncthreads();
      if (tid == 0){
        float wv = rv[0]; int wi = ri[0];
        #pragma unroll
        for (int q = 1; q < 4; q++){
          if (rv[q] < wv || (rv[q] == wv && ri[q] < wi)){ wv = rv[q]; wi = ri[q]; }
        }
        swv = wv; swi = wi; knn[out_base + r] = wi;
      }
      __syncthreads();
      float wv = swv; int wi = swi;
      if (lmi == wi){
        lmv = 3e38f; lmi = 0x7FFFFFFF;
        #pragma unroll
        for (int t = 0; t < 32; t++){
          int p = tid*32 + t; float d = dv[t];
          bool alive = (d > wv) || (d == wv && p > wi);
          if (alive && (d < lmv || (d == lmv && p < lmi))){ lmv = d; lmi = p; }
        }
      }
    }
  }
}

// ---------------- materialized MLP passes ----------------
__device__ __forceinline__ bf16x8_t bfrag(const unsigned short* wp, int f, int lane){
  return *(const bf16x8_t*)(wp + ((size_t)f << 9) + (lane << 3));
}
// apply BN affine+relu to a bf16x8 A-fragment whose elements are channels kbase..kbase+7
__device__ __forceinline__ bf16x8_t bn_frag(bf16x8_t v, const float* a, const float* c, int kbase){
  float4 a0 = *(const float4*)(a + kbase); float4 a1 = *(const float4*)(a + kbase + 4);
  float4 c0 = *(const float4*)(c + kbase); float4 c1 = *(const float4*)(c + kbase + 4);
  float av[8] = {a0.x,a0.y,a0.z,a0.w,a1.x,a1.y,a1.z,a1.w};
  float cv[8] = {c0.x,c0.y,c0.z,c0.w,c1.x,c1.y,c1.z,c1.w};
  bf16x8_t r;
  #pragma unroll
  for (int j = 0; j < 8; j++)
    r[j] = (short)f2bf(fmaxf(bf2f((unsigned short)v[j])*av[j] + cv[j], 0.f));
  return r;
}

// Pass A: gather + L0 -> y0 (bf16 row-major [row][64]) + stats0
template<int TILES>
__global__ __launch_bounds__(256) void passA(
    const float* __restrict__ xyzf, const unsigned short* __restrict__ ptsb,
    const int* __restrict__ fpsi, const int* __restrict__ knn,
    const unsigned short* __restrict__ w0p,
    unsigned short* __restrict__ y0g, float* osum, float* osq)
{
  __shared__ unsigned short xb0[64*104];
  __shared__ unsigned short st[64*72];
  __shared__ float sacc[128];
  int tid = threadIdx.x, lane = tid & 63, w = tid >> 6;
  int l15 = lane & 15, quad = lane >> 4;
  float ssum[4], ssq[4];
  #pragma unroll
  for (int c = 0; c < 4; c++){ ssum[c] = 0.f; ssq[c] = 0.f; }
  if (tid < 128) sacc[tid] = 0.f;
  __syncthreads();

  for (int t = 0; t < TILES; t++){
    int row0 = (blockIdx.x * TILES + t) * 64;
    {
      int r = tid >> 2, p = tid & 3;
      int g = row0 + r;
      int bq = g >> 16, s = (g >> 5) & 2047;
      int n = knn[g];
      const bf16x8_t* pr = (const bf16x8_t*)(ptsb + (((size_t)bq*NN + n) << 6));
      *(bf16x8_t*)&xb0[r*104 + p*16]     = pr[p*2];
      *(bf16x8_t*)&xb0[r*104 + p*16 + 8] = pr[p*2 + 1];
      if (p == 3){
        const float* xbp = xyzf + (size_t)bq*NN*3;
        int f = fpsi[(bq << 11) + s];
        float dx = xbp[n*3]   - xbp[f*3];
        float dy = xbp[n*3+1] - xbp[f*3+1];
        float dz = xbp[n*3+2] - xbp[f*3+2];
        bf16x8_t v = {(short)f2bf(dx), (short)f2bf(dy), (short)f2bf(dz), 0,0,0,0,0};
        bf16x8_t z = {0,0,0,0,0,0,0,0};
        *(bf16x8_t*)&xb0[r*104 + 64] = v;
        *(bf16x8_t*)&xb0[r*104 + 72] = z;
        *(bf16x8_t*)&xb0[r*104 + 80] = z;
        *(bf16x8_t*)&xb0[r*104 + 88] = z;
      }
    }
    // own-wave rows only -> no barrier
    bf16x8_t a0[3];
    #pragma unroll
    for (int ks = 0; ks < 3; ks++)
      a0[ks] = *(const bf16x8_t*)&xb0[(w*16 + l15)*104 + ks*32 + quad*8];
    #pragma unroll
    for (int ct = 0; ct < 4; ct++){
      f32x4_t a = {0.f,0.f,0.f,0.f};
      #pragma unroll
      for (int ks = 0; ks < 3; ks++)
        a = __builtin_amdgcn_mfma_f32_16x16x32_bf16(a0[ks], bfrag(w0p, ct*3+ks, lane), a, 0, 0, 0);
      #pragma unroll
      for (int r = 0; r < 4; r++){
        float v = a[r]; ssum[ct] += v; ssq[ct] += v*v;
        st[(w*16 + quad*4 + r)*72 + ct*16 + l15] = f2bf(v);
      }
    }
    __syncthreads();
    #pragma unroll
    for (int p = 0; p < 2; p++){
      int idx = p*2048 + tid*8; int r = idx >> 6; int c = idx & 63;
      *(bf16x8_t*)(y0g + (size_t)row0*64 + idx) = *(const bf16x8_t*)&st[r*72 + c];
    }
    __syncthreads();
  }
  #pragma unroll
  for (int c = 0; c < 4; c++){
    ssum[c] += __shfl_xor(ssum[c], 16); ssum[c] += __shfl_xor(ssum[c], 32);
    ssq [c] += __shfl_xor(ssq [c], 16); ssq [c] += __shfl_xor(ssq [c], 32);
  }
  if (quad == 0){
    #pragma unroll
    for (int c = 0; c < 4; c++){
      atomicAdd(&sacc[c*16 + l15], ssum[c]);
      atomicAdd(&sacc[64 + c*16 + l15], ssq[c]);
    }
  }
  __syncthreads();
  if (tid < 64){
    atomicAdd(&osum[tid], sacc[tid]);
    atomicAdd(&osq [tid], sacc[64 + tid]);
  }
}

// Pass B: y0 -> bn0+relu -> L1 -> y1 (bf16 [row][128]) + stats1
template<int TILES>
__global__ __launch_bounds__(256) void passB(
    const unsigned short* __restrict__ y0g, const unsigned short* __restrict__ w1p,
    const float* __restrict__ bnac,
    unsigned short* __restrict__ y1g, float* osum, float* osq)
{
  __shared__ unsigned short st[64*136];
  __shared__ float sacc[256];
  int tid = threadIdx.x, lane = tid & 63, w = tid >> 6;
  int l15 = lane & 15, quad = lane >> 4;
  float ssum[8], ssq[8];
  #pragma unroll
  for (int c = 0; c < 8; c++){ ssum[c] = 0.f; ssq[c] = 0.f; }
  sacc[tid] = 0.f;
  __syncthreads();

  for (int t = 0; t < TILES; t++){
    int row0 = (blockIdx.x * TILES + t) * 64;
    int row = row0 + w*16 + l15;
    bf16x8_t a1[2];
    #pragma unroll
    for (int ks = 0; ks < 2; ks++){
      bf16x8_t v = *(const bf16x8_t*)(y0g + (size_t)row*64 + ks*32 + quad*8);
      a1[ks] = bn_frag(v, bnac, bnac + 64, ks*32 + quad*8);
    }
    #pragma unroll
    for (int ct = 0; ct < 8; ct++){
      f32x4_t a = {0.f,0.f,0.f,0.f};
      #pragma unroll
      for (int ks = 0; ks < 2; ks++)
        a = __builtin_amdgcn_mfma_f32_16x16x32_bf16(a1[ks], bfrag(w1p, ct*2+ks, lane), a, 0, 0, 0);
      #pragma unroll
      for (int r = 0; r < 4; r++){
        float v = a[r]; ssum[ct] += v; ssq[ct] += v*v;
        st[(w*16 + quad*4 + r)*136 + ct*16 + l15] = f2bf(v);
      }
    }
    __syncthreads();
    #pragma unroll
    for (int p = 0; p < 4; p++){
      int idx = p*2048 + tid*8; int r = idx >> 7; int c = idx & 127;
      *(bf16x8_t*)(y1g + (size_t)row0*128 + idx) = *(const bf16x8_t*)&st[r*136 + c];
    }
    __syncthreads();
  }
  #pragma unroll
  for (int c = 0; c < 8; c++){
    ssum[c] += __shfl_xor(ssum[c], 16); ssum[c] += __shfl_xor(ssum[c], 32);
    ssq [c] += __shfl_xor(ssq [c], 16); ssq [c] += __shfl_xor(ssq [c], 32);
  }
  if (quad == 0){
    #pragma unroll
    for (int c = 0; c < 8; c++){
      atomicAdd(&sacc[c*16 + l15], ssum[c]);
      atomicAdd(&sacc[128 + c*16 + l15], ssq[c]);
    }
  }
  __syncthreads();
  if (tid < 128){
    atomicAdd(&osum[tid], sacc[tid]);
    atomicAdd(&osq [tid], sacc[128 + tid]);
  }
}

// Pass C: y1 -> bn1+relu -> L2 -> stats2 only (barrier-free until epilogue)
template<int TILES>
__global__ __launch_bounds__(256) void passC(
    const unsigned short* __restrict__ y1g, const unsigned short* __restrict__ w2p,
    const float* __restrict__ bnac, float* osum, float* osq)
{
  __shared__ float sacc[512];
  int tid = threadIdx.x, lane = tid & 63, w = tid >> 6;
  int l15 = lane & 15, quad = lane >> 4;
  float ssum[16], ssq[16];
  #pragma unroll
  for (int c = 0; c < 16; c++){ ssum[c] = 0.f; ssq[c] = 0.f; }
  sacc[tid] = 0.f; sacc[tid + 256] = 0.f;
  __syncthreads();

  for (int t = 0; t < TILES; t++){
    int row0 = (blockIdx.x * TILES + t) * 64;
    int row = row0 + w*16 + l15;
    bf16x8_t a2[4];
    #pragma unroll
    for (int ks = 0; ks < 4; ks++){
      bf16x8_t v = *(const bf16x8_t*)(y1g + (size_t)row*128 + ks*32 + quad*8);
      a2[ks] = bn_frag(v, bnac + 128, bnac + 256, ks*32 + quad*8);
    }
    #pragma unroll
    for (int ct = 0; ct < 16; ct++){
      f32x4_t a = {0.f,0.f,0.f,0.f};
      #pragma unroll
      for (int ks = 0; ks < 4; ks++)
        a = __builtin_amdgcn_mfma_f32_16x16x32_bf16(a2[ks], bfrag(w2p, ct*4+ks, lane), a, 0, 0, 0);
      #pragma unroll
      for (int r = 0; r < 4; r++){ float v = a[r]; ssum[ct] += v; ssq[ct] += v*v; }
    }
  }
  #pragma unroll
  for (int c = 0; c < 16; c++){
    ssum[c] += __shfl_xor(ssum[c], 16); ssum[c] += __shfl_xor(ssum[c], 32);
    ssq [c] += __shfl_xor(ssq [c], 16); ssq [c] += __shfl_xor(ssq [c], 32);
  }
  if (quad == 0){
    #pragma unroll
    for (int c = 0; c < 16; c++){
      atomicAdd(&sacc[c*16 + l15], ssum[c]);
      atomicAdd(&sacc[256 + c*16 + l15], ssq[c]);
    }
  }
  __syncthreads();
  if (tid < 256){
    atomicAdd(&osum[tid], sacc[tid]);
    atomicAdd(&osq [tid], sacc[256 + tid]);
  }
}

// Pass D: y1 -> bn1+relu -> L2 -> bn2+relu -> maxpool -> out (grid 4096, 1 tile)
__global__ __launch_bounds__(256) void passD(
    const unsigned short* __restrict__ y1g, const unsigned short* __restrict__ w2p,
    const float* __restrict__ bnac, void* d_out, const int* __restrict__ flag)
{
  __shared__ float smax[1024];
  int tid = threadIdx.x, lane = tid & 63, w = tid >> 6;
  int l15 = lane & 15, quad = lane >> 4;
  int row0 = blockIdx.x * 64;
  int row = row0 + w*16 + l15;
  bf16x8_t a2[4];
  #pragma unroll
  for (int ks = 0; ks < 4; ks++){
    bf16x8_t v = *(const bf16x8_t*)(y1g + (size_t)row*128 + ks*32 + quad*8);
    a2[ks] = bn_frag(v, bnac + 128, bnac + 256, ks*32 + quad*8);
  }
  #pragma unroll
  for (int ct = 0; ct < 16; ct++){
    f32x4_t a = {0.f,0.f,0.f,0.f};
    #pragma unroll
    for (int ks = 0; ks < 4; ks++)
      a = __builtin_amdgcn_mfma_f32_16x16x32_bf16(a2[ks], bfrag(w2p, ct*4+ks, lane), a, 0, 0, 0);
    int o = ct*16 + l15;
    float ga = bnac[384 + o], gc = bnac[640 + o];
    float m = fmaxf(fmaxf(a[0]*ga + gc, a[1]*ga + gc), fmaxf(a[2]*ga + gc, a[3]*ga + gc));
    m = fmaxf(m, __shfl_xor(m, 16));
    m = fmaxf(m, __shfl_xor(m, 32));
    if (quad == 0) smax[w*256 + o] = m;
  }
  __syncthreads();
  float v0 = fmaxf(fmaxf(smax[tid], smax[256 + tid]), 0.f);
  float v1 = fmaxf(fmaxf(smax[512 + tid], smax[768 + tid]), 0.f);
  int cg = blockIdx.x * 2;
  bool isf32 = (*flag != 0);
  int b0 = cg >> 11, s0 = cg & 2047;
  int b1 = (cg+1) >> 11, s1 = (cg+1) & 2047;
  size_t o0 = (size_t)BB*SS*3 + (((size_t)(b0*256 + tid)) << 11) + s0;
  size_t o1 = (size_t)BB*SS*3 + (((size_t)(b1*256 + tid)) << 11) + s1;
  if (isf32){ ((float*)d_out)[o0] = v0; ((float*)d_out)[o1] = v1; }
  else { ((unsigned short*)d_out)[o0] = f2bf(v0); ((unsigned short*)d_out)[o1] = f2bf(v1); }
}

__global__ void bn_finalize(const float* sum, const float* sq, const float* g, const float* bb,
                            float* a, float* c, int n){
  int o = blockIdx.x*64 + threadIdx.x;
  if (o >= n) return;
  const float invM = 1.0f/262144.0f;
  float mu = sum[o]*invM;
  float var = sq[o]*invM - mu*mu; var = fmaxf(var, 0.f);
  float inv = 1.0f/sqrtf(var + 1e-5f);
  float av = g[o]*inv;
  a[o] = av; c[o] = bb[o] - mu*av;
}

// ---------------- workspace layout (bytes) — total ~101.5 MB ----------------
#define OFF_FLAG   0u
#define OFF_FPS    256u
#define OFF_KNN    33024u
#define OFF_STATS  1081600u
#define OFF_BNAC   1085184u
#define OFF_XYZF   1088768u
#define OFF_GB     1481984u
#define OFF_W0P    1485568u
#define OFF_W1P    1497856u
#define OFF_W2P    1514240u
#define OFF_PTSB   1579776u
#define OFF_Y0     5774336u    // 262144*64 bf16 = 33.5 MB
#define OFF_Y1     39328768u   // 262144*128 bf16 = 67 MB -> ends 106437632

extern "C" void kernel_launch(void* const* d_in, const int* in_sizes, int n_in,
                              void* d_out, int out_size, void* d_ws, size_t ws_size,
                              hipStream_t stream){
  char* ws = (char*)d_ws;
  int*   flag  = (int*)(ws + OFF_FLAG);
  int*   fpsi  = (int*)(ws + OFF_FPS);
  int*   knn   = (int*)(ws + OFF_KNN);
  float* stats = (float*)(ws + OFF_STATS);
  float* bnac  = (float*)(ws + OFF_BNAC);
  float* xyzf  = (float*)(ws + OFF_XYZF);
  float* gbf   = (float*)(ws + OFF_GB);
  unsigned short* w0p = (unsigned short*)(ws + OFF_W0P);
  unsigned short* w1p = (unsigned short*)(ws + OFF_W1P);
  unsigned short* w2p = (unsigned short*)(ws + OFF_W2P);
  unsigned short* ptsb = (unsigned short*)(ws + OFF_PTSB);
  unsigned short* y0g = (unsigned short*)(ws + OFF_Y0);
  unsigned short* y1g = (unsigned short*)(ws + OFF_Y1);

  hipMemsetAsync(ws + OFF_STATS, 0, 896*4, stream);
  detect_kernel<<<1, 256, 0, stream>>>(d_in[1], flag);

  convert_kernel<<<384, 256, 0, stream>>>(d_in[0], xyzf, BB*NN*3, flag);
  convert_kernel<<<1, 256, 0, stream>>>(d_in[3],  gbf + 0,   64,  flag);
  convert_kernel<<<1, 256, 0, stream>>>(d_in[4],  gbf + 64,  64,  flag);
  convert_kernel<<<1, 256, 0, stream>>>(d_in[6],  gbf + 128, 128, flag);
  convert_kernel<<<1, 256, 0, stream>>>(d_in[7],  gbf + 256, 128, flag);
  convert_kernel<<<1, 256, 0, stream>>>(d_in[9],  gbf + 384, 256, flag);
  convert_kernel<<<1, 256, 0, stream>>>(d_in[10], gbf + 640, 256, flag);
  transpose_pts_bf16<<<512, 256, 0, stream>>>(d_in[1], ptsb, flag);

  pack_w<<<24,  256, 0, stream>>>(d_in[2], w0p, 4, 3, 67, 1, flag);
  pack_w<<<32,  256, 0, stream>>>(d_in[5], w1p, 8, 2, 64, 0, flag);
  pack_w<<<128, 256, 0, stream>>>(d_in[8], w2p, 16, 4, 128, 0, flag);

  fps_kernel<<<BB, 1024, 0, stream>>>(xyzf, fpsi, d_out, flag);
  knn_kernel<<<512, 256, 0, stream>>>(xyzf, fpsi, knn);

  passA<4><<<1024, 256, 0, stream>>>(xyzf, ptsb, fpsi, knn, w0p, y0g, stats + 0, stats + 64);
  bn_finalize<<<1, 64, 0, stream>>>(stats + 0, stats + 64, gbf + 0, gbf + 64, bnac + 0, bnac + 64, 64);

  passB<4><<<1024, 256, 0, stream>>>(y0g, w1p, bnac, y1g, stats + 128, stats + 256);
  bn_finalize<<<2, 64, 0, stream>>>(stats + 128, stats + 256, gbf + 128, gbf + 256, bnac + 128, bnac + 256, 128);

  passC<4><<<1024, 256, 0, stream>>>(y1g, w2p, bnac, stats + 384, stats + 640);
  bn_finalize<<<4, 64, 0, stream>>>(stats + 384, stats + 640, gbf + 384, gbf + 640, bnac + 384, bnac + 640, 256);

  passD<<<4096, 256, 0, stream>>>(y1g, w2p, bnac, d_out, flag);
  (void)in_sizes; (void)n_in; (void)out_size; (void)ws_size;
}

// Round 7
// 2926.621 us; speedup vs baseline: 2.4875x; 1.5886x over previous
//
#include <hip/hip_runtime.h>

#define BB 4
#define NN 8192
#define CC 64
#define SS 2048
#define KK 32
#define MROWS (BB*SS*KK)   // 262144

typedef __attribute__((ext_vector_type(8))) short bf16x8_t;
typedef __attribute__((ext_vector_type(4))) float f32x4_t;
typedef __attribute__((ext_vector_type(2))) float f32x2_t;

__device__ __forceinline__ float bf2f(unsigned short u){
  union { unsigned int i; float f; } v; v.i = ((unsigned int)u) << 16; return v.f;
}
__device__ __forceinline__ unsigned short f2bf(float f){
  union { float f; unsigned int i; } v; v.f = f;
  unsigned int u = v.i;
  unsigned int r = (u + 0x7FFFu + ((u >> 16) & 1u)) >> 16;
  return (unsigned short)r;
}
__device__ __forceinline__ float i2f(int i){ union { int i; float f; } v; v.i = i; return v.f; }
__device__ __forceinline__ int f2i(float f){ union { float f; int i; } v; v.f = f; return v.i; }

// ---------------- dtype detection ----------------
__global__ void detect_kernel(const void* pts, int* flag){
  __shared__ int cnt;
  if (threadIdx.x == 0) cnt = 0;
  __syncthreads();
  unsigned short u = ((const unsigned short*)pts)[threadIdx.x];
  int e = (u >> 7) & 0xFF;
  if (e != 0 && (e < 112 || e > 143)) atomicAdd(&cnt, 1);
  __syncthreads();
  if (threadIdx.x == 0) *flag = (cnt > 32) ? 1 : 0;
}

__global__ void convert_kernel(const void* src, float* dst, int n, const int* flag){
  int i = blockIdx.x*256 + threadIdx.x;
  if (i >= n) return;
  dst[i] = (*flag != 0) ? ((const float*)src)[i] : bf2f(((const unsigned short*)src)[i]);
}

// all six gamma/beta vectors in one launch: layout g0@0 b0@64 g1@128 b1@256 g2@384 b2@640
__global__ void convert_gb(const void* g0, const void* b0, const void* g1, const void* b1,
                           const void* g2, const void* b2, float* dst, const int* flag){
  int i = blockIdx.x*256 + threadIdx.x;   // 896 total
  if (i >= 896) return;
  const void* src; int off;
  if      (i < 64)  { src = g0; off = i; }
  else if (i < 128) { src = b0; off = i - 64; }
  else if (i < 256) { src = g1; off = i - 128; }
  else if (i < 384) { src = b1; off = i - 256; }
  else if (i < 640) { src = g2; off = i - 384; }
  else              { src = b2; off = i - 640; }
  dst[i] = (*flag != 0) ? ((const float*)src)[off] : bf2f(((const unsigned short*)src)[off]);
}

// (B,C,N) -> (B,N,C) bf16
__global__ __launch_bounds__(256) void transpose_pts_bf16(const void* pts, unsigned short* out, const int* flag){
  __shared__ float tile[64][65];
  int bx = blockIdx.x; int b = bx >> 7; int n0 = (bx & 127) * 64; int tid = threadIdx.x;
  bool isf = (*flag != 0);
  #pragma unroll
  for (int k = 0; k < 16; k++){
    int idx = k*256 + tid; int c = idx >> 6; int ni = idx & 63;
    size_t src = ((size_t)b*CC + c)*NN + n0 + ni;
    tile[c][ni] = isf ? ((const float*)pts)[src] : bf2f(((const unsigned short*)pts)[src]);
  }
  __syncthreads();
  #pragma unroll
  for (int k = 0; k < 16; k++){
    int idx = k*256 + tid; int ni = idx >> 6; int c = idx & 63;
    out[((size_t)b*NN + n0 + ni)*CC + c] = f2bf(tile[c][ni]);
  }
}

// pack weights into MFMA B-fragment order (bf16)
__global__ void pack_w(const void* src, unsigned short* dst, int CTS, int KSTEPS, int IN, int remap, const int* flag){
  int idx = blockIdx.x*256 + threadIdx.x;
  int total = CTS*KSTEPS*512;
  if (idx >= total) return;
  int f = idx >> 9, lane = (idx >> 3) & 63, j = idx & 7;
  int ct = f / KSTEPS, ks = f % KSTEPS;
  int n = ct*16 + (lane & 15);
  int k = ks*32 + (lane >> 4)*8 + j;
  int ksrc;
  if (remap){ ksrc = (k < 64) ? (k + 3) : (k < 67 ? k - 64 : -1); }
  else      { ksrc = (k < IN) ? k : -1; }
  float v = 0.f;
  if (ksrc >= 0){
    size_t si = (size_t)n*IN + ksrc;
    v = (*flag != 0) ? ((const float*)src)[si] : bf2f(((const unsigned short*)src)[si]);
  }
  dst[idx] = f2bf(v);
}

// ---------------- DPP helpers ----------------
template<int C>
__device__ __forceinline__ float dpp_maxf(float v){
  int t = __builtin_amdgcn_update_dpp(0, f2i(v), C, 0xF, 0xF, true);
  return fmaxf(v, i2f(t));
}
template<int C>
__device__ __forceinline__ unsigned dpp_minu(unsigned v){
  unsigned t = (unsigned)__builtin_amdgcn_update_dpp(-1, (int)v, C, 0xF, 0xF, false);
  return v < t ? v : t;
}
template<int C>
__device__ __forceinline__ void dpp_max64(unsigned &lo, unsigned &hi){
  unsigned tlo = (unsigned)__builtin_amdgcn_update_dpp(0, (int)lo, C, 0xF, 0xF, true);
  unsigned thi = (unsigned)__builtin_amdgcn_update_dpp(0, (int)hi, C, 0xF, 0xF, true);
  if (thi > hi || (thi == hi && tlo > lo)){ lo = tlo; hi = thi; }
}

// ---------------- FPS (unchanged) ----------------
__global__ __launch_bounds__(1024, 1) void fps_kernel(const float* xyzf, int* fps_idx,
                                                      void* d_out, const int* flag){
  int b = blockIdx.x, tid = threadIdx.x;
  const float* xb = xyzf + (size_t)b*NN*3;
  __shared__ float sxyz[NN*3];
  __shared__ unsigned long long ru[2][16];
  for (int i = tid; i < NN*3/4; i += 1024)
    ((float4*)sxyz)[i] = ((const float4*)xb)[i];
  f32x2_t px2[4], py2[4], pz2[4], dmin2[4];
  #pragma unroll
  for (int q = 0; q < 4; q++){
    int p0 = tid + (2*q)*1024, p1 = tid + (2*q+1)*1024;
    px2[q] = (f32x2_t){xb[p0*3],   xb[p1*3]};
    py2[q] = (f32x2_t){xb[p0*3+1], xb[p1*3+1]};
    pz2[q] = (f32x2_t){xb[p0*3+2], xb[p1*3+2]};
    dmin2[q] = (f32x2_t){1e10f, 1e10f};
  }
  __syncthreads();
  int far = 0;
  bool isf32 = (*flag != 0);
  float* outf = (float*)d_out; unsigned short* outh = (unsigned short*)d_out;
  int w = tid >> 6, ln = tid & 63;
  for (int s = 0; s < SS; s++){
    float cx = sxyz[far*3], cy = sxyz[far*3+1], cz = sxyz[far*3+2];
    if (tid == 0){
      fps_idx[b*SS + s] = far;
      size_t o = ((size_t)b*SS + s)*3;
      if (isf32){ outf[o]=cx; outf[o+1]=cy; outf[o+2]=cz; }
      else { outh[o]=f2bf(cx); outh[o+1]=f2bf(cy); outh[o+2]=f2bf(cz); }
    }
    f32x2_t cx2 = (f32x2_t){cx, cx}, cy2 = (f32x2_t){cy, cy}, cz2 = (f32x2_t){cz, cz};
    {
      #pragma clang fp contract(off)
      #pragma unroll
      for (int q = 0; q < 4; q++){
        f32x2_t dx = px2[q] - cx2, dy = py2[q] - cy2, dz = pz2[q] - cz2;
        f32x2_t t = dx*dx;
        t = t + dy*dy;
        t = t + dz*dz;
        dmin2[q].x = fminf(dmin2[q].x, t.x);
        dmin2[q].y = fminf(dmin2[q].y, t.y);
      }
    }
    float m0 = fmaxf(fmaxf(dmin2[0].x, dmin2[0].y), fmaxf(dmin2[1].x, dmin2[1].y));
    float m1 = fmaxf(fmaxf(dmin2[2].x, dmin2[2].y), fmaxf(dmin2[3].x, dmin2[3].y));
    float lm = fmaxf(m0, m1);
    lm = dpp_maxf<0x111>(lm); lm = dpp_maxf<0x112>(lm);
    lm = dpp_maxf<0x114>(lm); lm = dpp_maxf<0x118>(lm);
    lm = dpp_maxf<0x142>(lm); lm = dpp_maxf<0x143>(lm);
    float wmax = i2f(__builtin_amdgcn_readlane(f2i(lm), 63));
    unsigned cand = 0xFFFFFFFFu;
    #pragma unroll
    for (int q = 3; q >= 0; q--){
      if (dmin2[q].y == wmax) cand = (unsigned)(tid + (2*q+1)*1024);
      if (dmin2[q].x == wmax) cand = (unsigned)(tid + (2*q)*1024);
    }
    cand = dpp_minu<0x111>(cand); cand = dpp_minu<0x112>(cand);
    cand = dpp_minu<0x114>(cand); cand = dpp_minu<0x118>(cand);
    cand = dpp_minu<0x142>(cand); cand = dpp_minu<0x143>(cand);
    if (ln == 63)
      ru[s & 1][w] = ((unsigned long long)(unsigned)f2i(wmax) << 32) | (unsigned)(~cand);
    __syncthreads();
    unsigned long long t = ru[s & 1][ln & 15];
    unsigned lo = (unsigned)t, hi = (unsigned)(t >> 32);
    dpp_max64<0x111>(lo, hi); dpp_max64<0x112>(lo, hi);
    dpp_max64<0x114>(lo, hi); dpp_max64<0x118>(lo, hi);
    far = (int)(~(unsigned)__builtin_amdgcn_readlane((int)lo, 63));
  }
}

// ---------------- kNN v2: radix-histogram selection ----------------
// One block per centroid. Select the 32 lex-smallest (d2, idx) pairs (any
// output order — downstream max-pool is permutation invariant).
__global__ __launch_bounds__(256) void knn_kernel(const float* xyzf, const int* fps_idx, int* knn){
  int cg = blockIdx.x;                 // b*SS + s
  int b = cg >> 11;
  int tid = threadIdx.x;
  const float* xb = xyzf + (size_t)b*NN*3;
  __shared__ unsigned hist[4096];
  __shared__ unsigned long long cand[512];
  __shared__ unsigned psum[256];
  __shared__ unsigned exbase[64];
  __shared__ float scc[3];
  __shared__ int sB, sBase, sCl, sCc;
  __shared__ unsigned long long rmin[4];
  __shared__ unsigned long long swin;

  if (tid == 0){
    int f = fps_idx[cg];
    scc[0] = xb[f*3]; scc[1] = xb[f*3+1]; scc[2] = xb[f*3+2];
    sCl = 0; sCc = 0;
  }
  #pragma unroll
  for (int i = 0; i < 16; i++) hist[tid*16 + i] = 0;
  __syncthreads();
  float cx = scc[0], cy = scc[1], cz = scc[2];

  float dv[32];
  {
    #pragma clang fp contract(off)
    #pragma unroll
    for (int q = 0; q < 8; q++){
      const float4* p4 = (const float4*)(xb + (size_t)tid*96 + q*12);
      float4 A = p4[0], B = p4[1], C = p4[2];
      float xs_[4] = {A.x, A.w, B.z, C.y};
      float ys_[4] = {A.y, B.x, B.w, C.z};
      float zs_[4] = {A.z, B.y, C.x, C.w};
      #pragma unroll
      for (int r = 0; r < 4; r++){
        float dx = cx - xs_[r], dy = cy - ys_[r], dz = cz - zs_[r];
        dv[q*4 + r] = dx*dx + dy*dy + dz*dz;
      }
    }
  }
  // histogram on top-12 bits (d2 >= 0 -> bit pattern order-isomorphic)
  #pragma unroll
  for (int t = 0; t < 32; t++)
    atomicAdd(&hist[((unsigned)f2i(dv[t])) >> 20], 1u);
  __syncthreads();
  // two-level exclusive scan to locate threshold bin
  unsigned lsum = 0;
  #pragma unroll
  for (int i = 0; i < 16; i++) lsum += hist[tid*16 + i];
  psum[tid] = lsum;
  __syncthreads();
  if (tid < 64){
    unsigned s4 = psum[tid*4] + psum[tid*4+1] + psum[tid*4+2] + psum[tid*4+3];
    unsigned inc = s4;
    #pragma unroll
    for (int off = 1; off < 64; off <<= 1){
      unsigned o = __shfl_up(inc, off);
      if (tid >= off) inc += o;
    }
    exbase[tid] = inc - s4;
  }
  __syncthreads();
  {
    int g4 = tid >> 2;
    unsigned ex = exbase[g4];
    for (int j = g4*4; j < tid; j++) ex += psum[j];
    unsigned run = ex;
    #pragma unroll
    for (int i = 0; i < 16; i++){
      unsigned c = hist[tid*16 + i];
      if (run < 32u && run + c >= 32u){ sB = tid*16 + i; sBase = (int)run; }
      run += c;
    }
  }
  __syncthreads();
  int Bbin = sB, base = sBase;
  int out = cg << 5;
  #pragma unroll
  for (int t = 0; t < 32; t++){
    unsigned bits = (unsigned)f2i(dv[t]);
    unsigned hb = bits >> 20;
    int idx = tid*32 + t;
    if ((int)hb < Bbin){
      int sl = atomicAdd(&sCl, 1);
      knn[out + sl] = idx;
    } else if ((int)hb == Bbin){
      int c = atomicAdd(&sCc, 1);
      if (c < 512) cand[c] = (((unsigned long long)bits) << 32) | (unsigned)idx;
    }
  }
  __syncthreads();
  int cc = sCc; if (cc > 512) cc = 512;
  int r = 32 - base;
  for (int round = 0; round < r; round++){
    unsigned long long lm = ~0ull;
    for (int i = tid; i < cc; i += 256){
      unsigned long long v = cand[i];
      if (v < lm) lm = v;
    }
    #pragma unroll
    for (int off = 1; off < 64; off <<= 1){
      unsigned long long o = __shfl_xor(lm, off);
      if (o < lm) lm = o;
    }
    if ((tid & 63) == 0) rmin[tid >> 6] = lm;
    __syncthreads();
    if (tid == 0){
      unsigned long long m = rmin[0];
      #pragma unroll
      for (int q = 1; q < 4; q++) if (rmin[q] < m) m = rmin[q];
      swin = m;
      knn[out + base + round] = (int)(unsigned)m;
    }
    __syncthreads();
    unsigned long long m = swin;
    for (int i = tid; i < cc; i += 256)
      if (cand[i] == m) cand[i] = ~0ull;
    __syncthreads();
  }
}

// ---------------- materialized MLP passes ----------------
__device__ __forceinline__ bf16x8_t bfrag(const unsigned short* wp, int f, int lane){
  return *(const bf16x8_t*)(wp + ((size_t)f << 9) + (lane << 3));
}
__device__ __forceinline__ bf16x8_t bn_frag(bf16x8_t v, const float* a, const float* c, int kbase){
  float4 a0 = *(const float4*)(a + kbase); float4 a1 = *(const float4*)(a + kbase + 4);
  float4 c0 = *(const float4*)(c + kbase); float4 c1 = *(const float4*)(c + kbase + 4);
  float av[8] = {a0.x,a0.y,a0.z,a0.w,a1.x,a1.y,a1.z,a1.w};
  float cv[8] = {c0.x,c0.y,c0.z,c0.w,c1.x,c1.y,c1.z,c1.w};
  bf16x8_t r;
  #pragma unroll
  for (int j = 0; j < 8; j++)
    r[j] = (short)f2bf(fmaxf(bf2f((unsigned short)v[j])*av[j] + cv[j], 0.f));
  return r;
}

template<int TILES>
__global__ __launch_bounds__(256) void passA(
    const float* __restrict__ xyzf, const unsigned short* __restrict__ ptsb,
    const int* __restrict__ fpsi, const int* __restrict__ knn,
    const unsigned short* __restrict__ w0p,
    unsigned short* __restrict__ y0g, float* osum, float* osq)
{
  __shared__ unsigned short xb0[64*104];
  __shared__ unsigned short st[64*72];
  __shared__ float sacc[128];
  int tid = threadIdx.x, lane = tid & 63, w = tid >> 6;
  int l15 = lane & 15, quad = lane >> 4;
  float ssum[4], ssq[4];
  #pragma unroll
  for (int c = 0; c < 4; c++){ ssum[c] = 0.f; ssq[c] = 0.f; }
  if (tid < 128) sacc[tid] = 0.f;
  __syncthreads();

  for (int t = 0; t < TILES; t++){
    int row0 = (blockIdx.x * TILES + t) * 64;
    {
      int r = tid >> 2, p = tid & 3;
      int g = row0 + r;
      int bq = g >> 16, s = (g >> 5) & 2047;
      int n = knn[g];
      const bf16x8_t* pr = (const bf16x8_t*)(ptsb + (((size_t)bq*NN + n) << 6));
      *(bf16x8_t*)&xb0[r*104 + p*16]     = pr[p*2];
      *(bf16x8_t*)&xb0[r*104 + p*16 + 8] = pr[p*2 + 1];
      if (p == 3){
        const float* xbp = xyzf + (size_t)bq*NN*3;
        int f = fpsi[(bq << 11) + s];
        float dx = xbp[n*3]   - xbp[f*3];
        float dy = xbp[n*3+1] - xbp[f*3+1];
        float dz = xbp[n*3+2] - xbp[f*3+2];
        bf16x8_t v = {(short)f2bf(dx), (short)f2bf(dy), (short)f2bf(dz), 0,0,0,0,0};
        bf16x8_t z = {0,0,0,0,0,0,0,0};
        *(bf16x8_t*)&xb0[r*104 + 64] = v;
        *(bf16x8_t*)&xb0[r*104 + 72] = z;
        *(bf16x8_t*)&xb0[r*104 + 80] = z;
        *(bf16x8_t*)&xb0[r*104 + 88] = z;
      }
    }
    bf16x8_t a0[3];
    #pragma unroll
    for (int ks = 0; ks < 3; ks++)
      a0[ks] = *(const bf16x8_t*)&xb0[(w*16 + l15)*104 + ks*32 + quad*8];
    #pragma unroll
    for (int ct = 0; ct < 4; ct++){
      f32x4_t a = {0.f,0.f,0.f,0.f};
      #pragma unroll
      for (int ks = 0; ks < 3; ks++)
        a = __builtin_amdgcn_mfma_f32_16x16x32_bf16(a0[ks], bfrag(w0p, ct*3+ks, lane), a, 0, 0, 0);
      #pragma unroll
      for (int r = 0; r < 4; r++){
        float v = a[r]; ssum[ct] += v; ssq[ct] += v*v;
        st[(w*16 + quad*4 + r)*72 + ct*16 + l15] = f2bf(v);
      }
    }
    __syncthreads();
    #pragma unroll
    for (int p = 0; p < 2; p++){
      int idx = p*2048 + tid*8; int r = idx >> 6; int c = idx & 63;
      *(bf16x8_t*)(y0g + (size_t)row0*64 + idx) = *(const bf16x8_t*)&st[r*72 + c];
    }
    __syncthreads();
  }
  #pragma unroll
  for (int c = 0; c < 4; c++){
    ssum[c] += __shfl_xor(ssum[c], 16); ssum[c] += __shfl_xor(ssum[c], 32);
    ssq [c] += __shfl_xor(ssq [c], 16); ssq [c] += __shfl_xor(ssq [c], 32);
  }
  if (quad == 0){
    #pragma unroll
    for (int c = 0; c < 4; c++){
      atomicAdd(&sacc[c*16 + l15], ssum[c]);
      atomicAdd(&sacc[64 + c*16 + l15], ssq[c]);
    }
  }
  __syncthreads();
  if (tid < 64){
    atomicAdd(&osum[tid], sacc[tid]);
    atomicAdd(&osq [tid], sacc[64 + tid]);
  }
}

template<int TILES>
__global__ __launch_bounds__(256) void passB(
    const unsigned short* __restrict__ y0g, const unsigned short* __restrict__ w1p,
    const float* __restrict__ bnac,
    unsigned short* __restrict__ y1g, float* osum, float* osq)
{
  __shared__ unsigned short st[64*136];
  __shared__ float sacc[256];
  int tid = threadIdx.x, lane = tid & 63, w = tid >> 6;
  int l15 = lane & 15, quad = lane >> 4;
  float ssum[8], ssq[8];
  #pragma unroll
  for (int c = 0; c < 8; c++){ ssum[c] = 0.f; ssq[c] = 0.f; }
  sacc[tid] = 0.f;
  __syncthreads();

  for (int t = 0; t < TILES; t++){
    int row0 = (blockIdx.x * TILES + t) * 64;
    int row = row0 + w*16 + l15;
    bf16x8_t a1[2];
    #pragma unroll
    for (int ks = 0; ks < 2; ks++){
      bf16x8_t v = *(const bf16x8_t*)(y0g + (size_t)row*64 + ks*32 + quad*8);
      a1[ks] = bn_frag(v, bnac, bnac + 64, ks*32 + quad*8);
    }
    #pragma unroll
    for (int ct = 0; ct < 8; ct++){
      f32x4_t a = {0.f,0.f,0.f,0.f};
      #pragma unroll
      for (int ks = 0; ks < 2; ks++)
        a = __builtin_amdgcn_mfma_f32_16x16x32_bf16(a1[ks], bfrag(w1p, ct*2+ks, lane), a, 0, 0, 0);
      #pragma unroll
      for (int r = 0; r < 4; r++){
        float v = a[r]; ssum[ct] += v; ssq[ct] += v*v;
        st[(w*16 + quad*4 + r)*136 + ct*16 + l15] = f2bf(v);
      }
    }
    __syncthreads();
    #pragma unroll
    for (int p = 0; p < 4; p++){
      int idx = p*2048 + tid*8; int r = idx >> 7; int c = idx & 127;
      *(bf16x8_t*)(y1g + (size_t)row0*128 + idx) = *(const bf16x8_t*)&st[r*136 + c];
    }
    __syncthreads();
  }
  #pragma unroll
  for (int c = 0; c < 8; c++){
    ssum[c] += __shfl_xor(ssum[c], 16); ssum[c] += __shfl_xor(ssum[c], 32);
    ssq [c] += __shfl_xor(ssq [c], 16); ssq [c] += __shfl_xor(ssq [c], 32);
  }
  if (quad == 0){
    #pragma unroll
    for (int c = 0; c < 8; c++){
      atomicAdd(&sacc[c*16 + l15], ssum[c]);
      atomicAdd(&sacc[128 + c*16 + l15], ssq[c]);
    }
  }
  __syncthreads();
  if (tid < 128){
    atomicAdd(&osum[tid], sacc[tid]);
    atomicAdd(&osq [tid], sacc[128 + tid]);
  }
}

template<int TILES>
__global__ __launch_bounds__(256) void passC(
    const unsigned short* __restrict__ y1g, const unsigned short* __restrict__ w2p,
    const float* __restrict__ bnac, float* osum, float* osq)
{
  __shared__ float sacc[512];
  int tid = threadIdx.x, lane = tid & 63, w = tid >> 6;
  int l15 = lane & 15, quad = lane >> 4;
  float ssum[16], ssq[16];
  #pragma unroll
  for (int c = 0; c < 16; c++){ ssum[c] = 0.f; ssq[c] = 0.f; }
  sacc[tid] = 0.f; sacc[tid + 256] = 0.f;
  __syncthreads();

  for (int t = 0; t < TILES; t++){
    int row0 = (blockIdx.x * TILES + t) * 64;
    int row = row0 + w*16 + l15;
    bf16x8_t a2[4];
    #pragma unroll
    for (int ks = 0; ks < 4; ks++){
      bf16x8_t v = *(const bf16x8_t*)(y1g + (size_t)row*128 + ks*32 + quad*8);
      a2[ks] = bn_frag(v, bnac + 128, bnac + 256, ks*32 + quad*8);
    }
    #pragma unroll
    for (int ct = 0; ct < 16; ct++){
      f32x4_t a = {0.f,0.f,0.f,0.f};
      #pragma unroll
      for (int ks = 0; ks < 4; ks++)
        a = __builtin_amdgcn_mfma_f32_16x16x32_bf16(a2[ks], bfrag(w2p, ct*4+ks, lane), a, 0, 0, 0);
      #pragma unroll
      for (int r = 0; r < 4; r++){ float v = a[r]; ssum[ct] += v; ssq[ct] += v*v; }
    }
  }
  #pragma unroll
  for (int c = 0; c < 16; c++){
    ssum[c] += __shfl_xor(ssum[c], 16); ssum[c] += __shfl_xor(ssum[c], 32);
    ssq [c] += __shfl_xor(ssq [c], 16); ssq [c] += __shfl_xor(ssq [c], 32);
  }
  if (quad == 0){
    #pragma unroll
    for (int c = 0; c < 16; c++){
      atomicAdd(&sacc[c*16 + l15], ssum[c]);
      atomicAdd(&sacc[256 + c*16 + l15], ssq[c]);
    }
  }
  __syncthreads();
  if (tid < 256){
    atomicAdd(&osum[tid], sacc[tid]);
    atomicAdd(&osq [tid], sacc[256 + tid]);
  }
}

__global__ __launch_bounds__(256) void passD(
    const unsigned short* __restrict__ y1g, const unsigned short* __restrict__ w2p,
    const float* __restrict__ bnac, void* d_out, const int* __restrict__ flag)
{
  __shared__ float smax[1024];
  int tid = threadIdx.x, lane = tid & 63, w = tid >> 6;
  int l15 = lane & 15, quad = lane >> 4;
  int row0 = blockIdx.x * 64;
  int row = row0 + w*16 + l15;
  bf16x8_t a2[4];
  #pragma unroll
  for (int ks = 0; ks < 4; ks++){
    bf16x8_t v = *(const bf16x8_t*)(y1g + (size_t)row*128 + ks*32 + quad*8);
    a2[ks] = bn_frag(v, bnac + 128, bnac + 256, ks*32 + quad*8);
  }
  #pragma unroll
  for (int ct = 0; ct < 16; ct++){
    f32x4_t a = {0.f,0.f,0.f,0.f};
    #pragma unroll
    for (int ks = 0; ks < 4; ks++)
      a = __builtin_amdgcn_mfma_f32_16x16x32_bf16(a2[ks], bfrag(w2p, ct*4+ks, lane), a, 0, 0, 0);
    int o = ct*16 + l15;
    float ga = bnac[384 + o], gc = bnac[640 + o];
    float m = fmaxf(fmaxf(a[0]*ga + gc, a[1]*ga + gc), fmaxf(a[2]*ga + gc, a[3]*ga + gc));
    m = fmaxf(m, __shfl_xor(m, 16));
    m = fmaxf(m, __shfl_xor(m, 32));
    if (quad == 0) smax[w*256 + o] = m;
  }
  __syncthreads();
  float v0 = fmaxf(fmaxf(smax[tid], smax[256 + tid]), 0.f);
  float v1 = fmaxf(fmaxf(smax[512 + tid], smax[768 + tid]), 0.f);
  int cg = blockIdx.x * 2;
  bool isf32 = (*flag != 0);
  int b0 = cg >> 11, s0 = cg & 2047;
  int b1 = (cg+1) >> 11, s1 = (cg+1) & 2047;
  size_t o0 = (size_t)BB*SS*3 + (((size_t)(b0*256 + tid)) << 11) + s0;
  size_t o1 = (size_t)BB*SS*3 + (((size_t)(b1*256 + tid)) << 11) + s1;
  if (isf32){ ((float*)d_out)[o0] = v0; ((float*)d_out)[o1] = v1; }
  else { ((unsigned short*)d_out)[o0] = f2bf(v0); ((unsigned short*)d_out)[o1] = f2bf(v1); }
}

__global__ void bn_finalize(const float* sum, const float* sq, const float* g, const float* bb,
                            float* a, float* c, int n){
  int o = blockIdx.x*64 + threadIdx.x;
  if (o >= n) return;
  const float invM = 1.0f/262144.0f;
  float mu = sum[o]*invM;
  float var = sq[o]*invM - mu*mu; var = fmaxf(var, 0.f);
  float inv = 1.0f/sqrtf(var + 1e-5f);
  float av = g[o]*inv;
  a[o] = av; c[o] = bb[o] - mu*av;
}

// ---------------- workspace layout (bytes) — total ~101.5 MB ----------------
#define OFF_FLAG   0u
#define OFF_FPS    256u
#define OFF_KNN    33024u
#define OFF_STATS  1081600u
#define OFF_BNAC   1085184u
#define OFF_XYZF   1088768u
#define OFF_GB     1481984u
#define OFF_W0P    1485568u
#define OFF_W1P    1497856u
#define OFF_W2P    1514240u
#define OFF_PTSB   1579776u
#define OFF_Y0     5774336u
#define OFF_Y1     39328768u

extern "C" void kernel_launch(void* const* d_in, const int* in_sizes, int n_in,
                              void* d_out, int out_size, void* d_ws, size_t ws_size,
                              hipStream_t stream){
  char* ws = (char*)d_ws;
  int*   flag  = (int*)(ws + OFF_FLAG);
  int*   fpsi  = (int*)(ws + OFF_FPS);
  int*   knn   = (int*)(ws + OFF_KNN);
  float* stats = (float*)(ws + OFF_STATS);
  float* bnac  = (float*)(ws + OFF_BNAC);
  float* xyzf  = (float*)(ws + OFF_XYZF);
  float* gbf   = (float*)(ws + OFF_GB);
  unsigned short* w0p = (unsigned short*)(ws + OFF_W0P);
  unsigned short* w1p = (unsigned short*)(ws + OFF_W1P);
  unsigned short* w2p = (unsigned short*)(ws + OFF_W2P);
  unsigned short* ptsb = (unsigned short*)(ws + OFF_PTSB);
  unsigned short* y0g = (unsigned short*)(ws + OFF_Y0);
  unsigned short* y1g = (unsigned short*)(ws + OFF_Y1);

  hipMemsetAsync(ws + OFF_STATS, 0, 896*4, stream);
  detect_kernel<<<1, 256, 0, stream>>>(d_in[1], flag);

  convert_kernel<<<384, 256, 0, stream>>>(d_in[0], xyzf, BB*NN*3, flag);
  convert_gb<<<4, 256, 0, stream>>>(d_in[3], d_in[4], d_in[6], d_in[7], d_in[9], d_in[10], gbf, flag);
  transpose_pts_bf16<<<512, 256, 0, stream>>>(d_in[1], ptsb, flag);

  pack_w<<<24,  256, 0, stream>>>(d_in[2], w0p, 4, 3, 67, 1, flag);
  pack_w<<<32,  256, 0, stream>>>(d_in[5], w1p, 8, 2, 64, 0, flag);
  pack_w<<<128, 256, 0, stream>>>(d_in[8], w2p, 16, 4, 128, 0, flag);

  fps_kernel<<<BB, 1024, 0, stream>>>(xyzf, fpsi, d_out, flag);
  knn_kernel<<<BB*SS, 256, 0, stream>>>(xyzf, fpsi, knn);

  passA<4><<<1024, 256, 0, stream>>>(xyzf, ptsb, fpsi, knn, w0p, y0g, stats + 0, stats + 64);
  bn_finalize<<<1, 64, 0, stream>>>(stats + 0, stats + 64, gbf + 0, gbf + 64, bnac + 0, bnac + 64, 64);

  passB<4><<<1024, 256, 0, stream>>>(y0g, w1p, bnac, y1g, stats + 128, stats + 256);
  bn_finalize<<<2, 64, 0, stream>>>(stats + 128, stats + 256, gbf + 128, gbf + 256, bnac + 128, bnac + 256, 128);

  passC<4><<<1024, 256, 0, stream>>>(y1g, w2p, bnac, stats + 384, stats + 640);
  bn_finalize<<<4, 64, 0, stream>>>(stats + 384, stats + 640, gbf + 384, gbf + 640, bnac + 384, bnac + 640, 256);

  passD<<<4096, 256, 0, stream>>>(y1g, w2p, bnac, d_out, flag);
  (void)in_sizes; (void)n_in; (void)out_size; (void)ws_size;
}

// Round 8
// 2669.971 us; speedup vs baseline: 2.7267x; 1.0961x over previous
//
#include <hip/hip_runtime.h>

#define BB 4
#define NN 8192
#define CC 64
#define SS 2048
#define KK 32
#define MROWS (BB*SS*KK)   // 262144

typedef __attribute__((ext_vector_type(8))) short bf16x8_t;
typedef __attribute__((ext_vector_type(4))) float f32x4_t;
typedef __attribute__((ext_vector_type(2))) float f32x2_t;

__device__ __forceinline__ float bf2f(unsigned short u){
  union { unsigned int i; float f; } v; v.i = ((unsigned int)u) << 16; return v.f;
}
__device__ __forceinline__ unsigned short f2bf(float f){
  union { float f; unsigned int i; } v; v.f = f;
  unsigned int u = v.i;
  unsigned int r = (u + 0x7FFFu + ((u >> 16) & 1u)) >> 16;
  return (unsigned short)r;
}
__device__ __forceinline__ float i2f(int i){ union { int i; float f; } v; v.i = i; return v.f; }
__device__ __forceinline__ int f2i(float f){ union { float f; int i; } v; v.f = f; return v.i; }

// ---------------- dtype detection ----------------
__global__ void detect_kernel(const void* pts, int* flag){
  __shared__ int cnt;
  if (threadIdx.x == 0) cnt = 0;
  __syncthreads();
  unsigned short u = ((const unsigned short*)pts)[threadIdx.x];
  int e = (u >> 7) & 0xFF;
  if (e != 0 && (e < 112 || e > 143)) atomicAdd(&cnt, 1);
  __syncthreads();
  if (threadIdx.x == 0) *flag = (cnt > 32) ? 1 : 0;
}

__global__ void convert_kernel(const void* src, float* dst, int n, const int* flag){
  int i = blockIdx.x*256 + threadIdx.x;
  if (i >= n) return;
  dst[i] = (*flag != 0) ? ((const float*)src)[i] : bf2f(((const unsigned short*)src)[i]);
}

__global__ void convert_gb(const void* g0, const void* b0, const void* g1, const void* b1,
                           const void* g2, const void* b2, float* dst, const int* flag){
  int i = blockIdx.x*256 + threadIdx.x;   // 896 total
  if (i >= 896) return;
  const void* src; int off;
  if      (i < 64)  { src = g0; off = i; }
  else if (i < 128) { src = b0; off = i - 64; }
  else if (i < 256) { src = g1; off = i - 128; }
  else if (i < 384) { src = b1; off = i - 256; }
  else if (i < 640) { src = g2; off = i - 384; }
  else              { src = b2; off = i - 640; }
  dst[i] = (*flag != 0) ? ((const float*)src)[off] : bf2f(((const unsigned short*)src)[off]);
}

// (B,C,N) -> (B,N,C) bf16
__global__ __launch_bounds__(256) void transpose_pts_bf16(const void* pts, unsigned short* out, const int* flag){
  __shared__ float tile[64][65];
  int bx = blockIdx.x; int b = bx >> 7; int n0 = (bx & 127) * 64; int tid = threadIdx.x;
  bool isf = (*flag != 0);
  #pragma unroll
  for (int k = 0; k < 16; k++){
    int idx = k*256 + tid; int c = idx >> 6; int ni = idx & 63;
    size_t src = ((size_t)b*CC + c)*NN + n0 + ni;
    tile[c][ni] = isf ? ((const float*)pts)[src] : bf2f(((const unsigned short*)pts)[src]);
  }
  __syncthreads();
  #pragma unroll
  for (int k = 0; k < 16; k++){
    int idx = k*256 + tid; int ni = idx >> 6; int c = idx & 63;
    out[((size_t)b*NN + n0 + ni)*CC + c] = f2bf(tile[c][ni]);
  }
}

// pack weights into MFMA B-fragment order (bf16)
__global__ void pack_w(const void* src, unsigned short* dst, int CTS, int KSTEPS, int IN, int remap, const int* flag){
  int idx = blockIdx.x*256 + threadIdx.x;
  int total = CTS*KSTEPS*512;
  if (idx >= total) return;
  int f = idx >> 9, lane = (idx >> 3) & 63, j = idx & 7;
  int ct = f / KSTEPS, ks = f % KSTEPS;
  int n = ct*16 + (lane & 15);
  int k = ks*32 + (lane >> 4)*8 + j;
  int ksrc;
  if (remap){ ksrc = (k < 64) ? (k + 3) : (k < 67 ? k - 64 : -1); }
  else      { ksrc = (k < IN) ? k : -1; }
  float v = 0.f;
  if (ksrc >= 0){
    size_t si = (size_t)n*IN + ksrc;
    v = (*flag != 0) ? ((const float*)src)[si] : bf2f(((const unsigned short*)src)[si]);
  }
  dst[idx] = f2bf(v);
}

// ---------------- Morton sort (one block per batch) ----------------
__device__ __forceinline__ unsigned mspread(unsigned v){
  v = (v | (v << 16)) & 0x030000FFu;
  v = (v | (v <<  8)) & 0x0300F00Fu;
  v = (v | (v <<  4)) & 0x030C30C3u;
  v = (v | (v <<  2)) & 0x09249249u;
  return v;
}
__global__ __launch_bounds__(1024) void morton_sort(const float* xyzf,
    float* psx, float* psy, float* psz, int* iorig){
  int b = blockIdx.x, tid = threadIdx.x;
  const float* xb = xyzf + (size_t)b*NN*3;
  __shared__ unsigned long long keys[NN];   // 64 KB
  __shared__ float rbb[96];
  float x[8], y[8], z[8];
  {
    const float4* p4 = (const float4*)(xb + (size_t)tid*24);
    float4 A=p4[0],B2=p4[1],C=p4[2],D=p4[3],E=p4[4],F=p4[5];
    x[0]=A.x;  y[0]=A.y;  z[0]=A.z;
    x[1]=A.w;  y[1]=B2.x; z[1]=B2.y;
    x[2]=B2.z; y[2]=B2.w; z[2]=C.x;
    x[3]=C.y;  y[3]=C.z;  z[3]=C.w;
    x[4]=D.x;  y[4]=D.y;  z[4]=D.z;
    x[5]=D.w;  y[5]=E.x;  z[5]=E.y;
    x[6]=E.z;  y[6]=E.w;  z[6]=F.x;
    x[7]=F.y;  y[7]=F.z;  z[7]=F.w;
  }
  float lx=x[0],hx=x[0],ly=y[0],hy=y[0],lz=z[0],hz=z[0];
  #pragma unroll
  for (int j = 1; j < 8; j++){
    lx=fminf(lx,x[j]); hx=fmaxf(hx,x[j]);
    ly=fminf(ly,y[j]); hy=fmaxf(hy,y[j]);
    lz=fminf(lz,z[j]); hz=fmaxf(hz,z[j]);
  }
  #pragma unroll
  for (int off = 1; off < 64; off <<= 1){
    lx=fminf(lx,__shfl_xor(lx,off)); hx=fmaxf(hx,__shfl_xor(hx,off));
    ly=fminf(ly,__shfl_xor(ly,off)); hy=fmaxf(hy,__shfl_xor(hy,off));
    lz=fminf(lz,__shfl_xor(lz,off)); hz=fmaxf(hz,__shfl_xor(hz,off));
  }
  int w = tid >> 6;
  if ((tid & 63) == 0){
    rbb[w]=lx; rbb[16+w]=hx; rbb[32+w]=ly; rbb[48+w]=hy; rbb[64+w]=lz; rbb[80+w]=hz;
  }
  __syncthreads();
  #pragma unroll
  for (int i = 0; i < 16; i++){
    lx=fminf(lx,rbb[i]); hx=fmaxf(hx,rbb[16+i]);
    ly=fminf(ly,rbb[32+i]); hy=fmaxf(hy,rbb[48+i]);
    lz=fminf(lz,rbb[64+i]); hz=fmaxf(hz,rbb[80+i]);
  }
  float sx = 1023.0f/fmaxf(hx-lx,1e-20f);
  float sy = 1023.0f/fmaxf(hy-ly,1e-20f);
  float sz = 1023.0f/fmaxf(hz-lz,1e-20f);
  #pragma unroll
  for (int j = 0; j < 8; j++){
    int qx = (int)((x[j]-lx)*sx); qx = qx < 0 ? 0 : (qx > 1023 ? 1023 : qx);
    int qy = (int)((y[j]-ly)*sy); qy = qy < 0 ? 0 : (qy > 1023 ? 1023 : qy);
    int qz = (int)((z[j]-lz)*sz); qz = qz < 0 ? 0 : (qz > 1023 ? 1023 : qz);
    unsigned code = mspread((unsigned)qx) | (mspread((unsigned)qy) << 1) | (mspread((unsigned)qz) << 2);
    keys[tid*8 + j] = (((unsigned long long)code) << 13) | (unsigned)(tid*8 + j);
  }
  __syncthreads();
  for (unsigned k = 2; k <= NN; k <<= 1){
    for (unsigned j = k >> 1; j > 0; j >>= 1){
      #pragma unroll
      for (int v = 0; v < 8; v++){
        int i = v*1024 + tid;
        int l = i ^ (int)j;
        if (l > i){
          unsigned long long a = keys[i], c = keys[l];
          bool asc = ((i & (int)k) == 0);
          if ((a > c) == asc){ keys[i] = c; keys[l] = a; }
        }
      }
      __syncthreads();
    }
  }
  for (int v = 0; v < 8; v++){
    int i = v*1024 + tid;
    int p = (int)(keys[i] & 8191u);
    psx[b*NN + i] = xb[p*3];
    psy[b*NN + i] = xb[p*3+1];
    psz[b*NN + i] = xb[p*3+2];
    iorig[b*NN + i] = p;
  }
}

// ---------------- DPP helpers ----------------
template<int C>
__device__ __forceinline__ float dpp_maxf(float v){
  int t = __builtin_amdgcn_update_dpp(0, f2i(v), C, 0xF, 0xF, true);
  return fmaxf(v, i2f(t));
}
template<int C>
__device__ __forceinline__ unsigned dpp_minu(unsigned v){
  unsigned t = (unsigned)__builtin_amdgcn_update_dpp(-1, (int)v, C, 0xF, 0xF, false);
  return v < t ? v : t;
}
template<int C>
__device__ __forceinline__ void dpp_max64(unsigned &lo, unsigned &hi){
  unsigned tlo = (unsigned)__builtin_amdgcn_update_dpp(0, (int)lo, C, 0xF, 0xF, true);
  unsigned thi = (unsigned)__builtin_amdgcn_update_dpp(0, (int)hi, C, 0xF, 0xF, true);
  if (thi > hi || (thi == hi && tlo > lo)){ lo = tlo; hi = thi; }
}

// ---------------- FPS v5: Morton-sorted + wave bbox pruning (exact) ----------------
// Wave w holds sorted points [w*512, (w+1)*512), 8/lane. A wave skips its whole
// update when dist(bbox, c)^2 * (1-1e-5) >= cached wave max dmin — provably a
// no-op on every dmin in the wave (fp margin >> bound rounding error), so the
// scan state stays bit-exact vs the reference.
__global__ __launch_bounds__(1024, 1) void fps_kernel(const float* xyzf,
    const float* psx, const float* psy, const float* psz, const int* iorig,
    int* fps_idx, void* d_out, const int* flag){
  int b = blockIdx.x, tid = threadIdx.x;
  const float* xb = xyzf + (size_t)b*NN*3;
  __shared__ float sxyz[NN*3];
  __shared__ unsigned long long ru[2][16];
  for (int i = tid; i < NN*3/4; i += 1024)
    ((float4*)sxyz)[i] = ((const float4*)xb)[i];
  f32x2_t px2[4], py2[4], pz2[4], dmin2[4];
  int io[8];
  {
    const float4* qx = (const float4*)(psx + b*NN + tid*8);
    const float4* qy = (const float4*)(psy + b*NN + tid*8);
    const float4* qz = (const float4*)(psz + b*NN + tid*8);
    float4 a, c;
    a = qx[0]; c = qx[1];
    px2[0]=(f32x2_t){a.x,a.y}; px2[1]=(f32x2_t){a.z,a.w}; px2[2]=(f32x2_t){c.x,c.y}; px2[3]=(f32x2_t){c.z,c.w};
    a = qy[0]; c = qy[1];
    py2[0]=(f32x2_t){a.x,a.y}; py2[1]=(f32x2_t){a.z,a.w}; py2[2]=(f32x2_t){c.x,c.y}; py2[3]=(f32x2_t){c.z,c.w};
    a = qz[0]; c = qz[1];
    pz2[0]=(f32x2_t){a.x,a.y}; pz2[1]=(f32x2_t){a.z,a.w}; pz2[2]=(f32x2_t){c.x,c.y}; pz2[3]=(f32x2_t){c.z,c.w};
    const int4* qi = (const int4*)(iorig + b*NN + tid*8);
    int4 i0 = qi[0], i1 = qi[1];
    io[0]=i0.x; io[1]=i0.y; io[2]=i0.z; io[3]=i0.w;
    io[4]=i1.x; io[5]=i1.y; io[6]=i1.z; io[7]=i1.w;
  }
  #pragma unroll
  for (int q = 0; q < 4; q++) dmin2[q] = (f32x2_t){1e10f, 1e10f};
  // wave bbox (all lanes end with identical values)
  float blox, bhix, bloy, bhiy, bloz, bhiz;
  {
    float lx = fminf(fminf(px2[0].x,px2[0].y), fminf(px2[1].x,px2[1].y));
    lx = fminf(lx, fminf(fminf(px2[2].x,px2[2].y), fminf(px2[3].x,px2[3].y)));
    float hx = fmaxf(fmaxf(px2[0].x,px2[0].y), fmaxf(px2[1].x,px2[1].y));
    hx = fmaxf(hx, fmaxf(fmaxf(px2[2].x,px2[2].y), fmaxf(px2[3].x,px2[3].y)));
    float ly = fminf(fminf(py2[0].x,py2[0].y), fminf(py2[1].x,py2[1].y));
    ly = fminf(ly, fminf(fminf(py2[2].x,py2[2].y), fminf(py2[3].x,py2[3].y)));
    float hy = fmaxf(fmaxf(py2[0].x,py2[0].y), fmaxf(py2[1].x,py2[1].y));
    hy = fmaxf(hy, fmaxf(fmaxf(py2[2].x,py2[2].y), fmaxf(py2[3].x,py2[3].y)));
    float lz = fminf(fminf(pz2[0].x,pz2[0].y), fminf(pz2[1].x,pz2[1].y));
    lz = fminf(lz, fminf(fminf(pz2[2].x,pz2[2].y), fminf(pz2[3].x,pz2[3].y)));
    float hz = fmaxf(fmaxf(pz2[0].x,pz2[0].y), fmaxf(pz2[1].x,pz2[1].y));
    hz = fmaxf(hz, fmaxf(fmaxf(pz2[2].x,pz2[2].y), fmaxf(pz2[3].x,pz2[3].y)));
    #pragma unroll
    for (int off = 1; off < 64; off <<= 1){
      lx=fminf(lx,__shfl_xor(lx,off)); hx=fmaxf(hx,__shfl_xor(hx,off));
      ly=fminf(ly,__shfl_xor(ly,off)); hy=fmaxf(hy,__shfl_xor(hy,off));
      lz=fminf(lz,__shfl_xor(lz,off)); hz=fmaxf(hz,__shfl_xor(hz,off));
    }
    blox=lx; bhix=hx; bloy=ly; bhiy=hy; bloz=lz; bhiz=hz;
  }
  __syncthreads();
  int far = 0;
  bool isf32 = (*flag != 0);
  float* outf = (float*)d_out; unsigned short* outh = (unsigned short*)d_out;
  int w = tid >> 6, ln = tid & 63;
  unsigned cached_lo = 0u, cached_hi = 0u;
  for (int s = 0; s < SS; s++){
    float cx = sxyz[far*3], cy = sxyz[far*3+1], cz = sxyz[far*3+2];
    if (tid == 0){
      fps_idx[b*SS + s] = far;
      size_t o = ((size_t)b*SS + s)*3;
      if (isf32){ outf[o]=cx; outf[o+1]=cy; outf[o+2]=cz; }
      else { outh[o]=f2bf(cx); outh[o+1]=f2bf(cy); outh[o+2]=f2bf(cz); }
    }
    // wave-uniform prune test
    float dxl = fmaxf(fmaxf(blox - cx, cx - bhix), 0.f);
    float dyl = fmaxf(fmaxf(bloy - cy, cy - bhiy), 0.f);
    float dzl = fmaxf(fmaxf(bloz - cz, cz - bhiz), 0.f);
    float d2bb = (dxl*dxl + dyl*dyl + dzl*dzl) * 0.99999f;
    bool upd = (s == 0) || (d2bb < i2f((int)cached_hi));
    if (upd){
      f32x2_t cx2 = (f32x2_t){cx, cx}, cy2 = (f32x2_t){cy, cy}, cz2 = (f32x2_t){cz, cz};
      {
        #pragma clang fp contract(off)
        #pragma unroll
        for (int q = 0; q < 4; q++){
          f32x2_t dx = px2[q] - cx2, dy = py2[q] - cy2, dz = pz2[q] - cz2;
          f32x2_t t = dx*dx;
          t = t + dy*dy;
          t = t + dz*dz;
          dmin2[q].x = fminf(dmin2[q].x, t.x);
          dmin2[q].y = fminf(dmin2[q].y, t.y);
        }
      }
      float m0 = fmaxf(fmaxf(dmin2[0].x, dmin2[0].y), fmaxf(dmin2[1].x, dmin2[1].y));
      float m1 = fmaxf(fmaxf(dmin2[2].x, dmin2[2].y), fmaxf(dmin2[3].x, dmin2[3].y));
      float lm = fmaxf(m0, m1);
      lm = dpp_maxf<0x111>(lm); lm = dpp_maxf<0x112>(lm);
      lm = dpp_maxf<0x114>(lm); lm = dpp_maxf<0x118>(lm);
      lm = dpp_maxf<0x142>(lm); lm = dpp_maxf<0x143>(lm);
      float wmax = i2f(__builtin_amdgcn_readlane(f2i(lm), 63));
      unsigned cand = 0xFFFFFFFFu;
      #pragma unroll
      for (int q = 0; q < 4; q++){
        if (dmin2[q].x == wmax){ unsigned u = (unsigned)io[2*q];   cand = u < cand ? u : cand; }
        if (dmin2[q].y == wmax){ unsigned u = (unsigned)io[2*q+1]; cand = u < cand ? u : cand; }
      }
      cand = dpp_minu<0x111>(cand); cand = dpp_minu<0x112>(cand);
      cand = dpp_minu<0x114>(cand); cand = dpp_minu<0x118>(cand);
      cand = dpp_minu<0x142>(cand); cand = dpp_minu<0x143>(cand);
      unsigned cmin = (unsigned)__builtin_amdgcn_readlane((int)cand, 63);
      cached_hi = (unsigned)f2i(wmax);
      cached_lo = ~cmin;
    }
    if (ln == 63) ru[s & 1][w] = (((unsigned long long)cached_hi) << 32) | cached_lo;
    __syncthreads();
    unsigned long long t = ru[s & 1][ln & 15];
    unsigned lo = (unsigned)t, hi = (unsigned)(t >> 32);
    dpp_max64<0x111>(lo, hi); dpp_max64<0x112>(lo, hi);
    dpp_max64<0x114>(lo, hi); dpp_max64<0x118>(lo, hi);
    far = (int)(~(unsigned)__builtin_amdgcn_readlane((int)lo, 63));
  }
}

// ---------------- kNN: radix-histogram selection (unchanged) ----------------
__global__ __launch_bounds__(256) void knn_kernel(const float* xyzf, const int* fps_idx, int* knn){
  int cg = blockIdx.x;
  int b = cg >> 11;
  int tid = threadIdx.x;
  const float* xb = xyzf + (size_t)b*NN*3;
  __shared__ unsigned hist[4096];
  __shared__ unsigned long long cand[512];
  __shared__ unsigned psum[256];
  __shared__ unsigned exbase[64];
  __shared__ float scc[3];
  __shared__ int sB, sBase, sCl, sCc;
  __shared__ unsigned long long rmin[4];
  __shared__ unsigned long long swin;

  if (tid == 0){
    int f = fps_idx[cg];
    scc[0] = xb[f*3]; scc[1] = xb[f*3+1]; scc[2] = xb[f*3+2];
    sCl = 0; sCc = 0;
  }
  #pragma unroll
  for (int i = 0; i < 16; i++) hist[tid*16 + i] = 0;
  __syncthreads();
  float cx = scc[0], cy = scc[1], cz = scc[2];

  float dv[32];
  {
    #pragma clang fp contract(off)
    #pragma unroll
    for (int q = 0; q < 8; q++){
      const float4* p4 = (const float4*)(xb + (size_t)tid*96 + q*12);
      float4 A = p4[0], B = p4[1], C = p4[2];
      float xs_[4] = {A.x, A.w, B.z, C.y};
      float ys_[4] = {A.y, B.x, B.w, C.z};
      float zs_[4] = {A.z, B.y, C.x, C.w};
      #pragma unroll
      for (int r = 0; r < 4; r++){
        float dx = cx - xs_[r], dy = cy - ys_[r], dz = cz - zs_[r];
        dv[q*4 + r] = dx*dx + dy*dy + dz*dz;
      }
    }
  }
  #pragma unroll
  for (int t = 0; t < 32; t++)
    atomicAdd(&hist[((unsigned)f2i(dv[t])) >> 20], 1u);
  __syncthreads();
  unsigned lsum = 0;
  #pragma unroll
  for (int i = 0; i < 16; i++) lsum += hist[tid*16 + i];
  psum[tid] = lsum;
  __syncthreads();
  if (tid < 64){
    unsigned s4 = psum[tid*4] + psum[tid*4+1] + psum[tid*4+2] + psum[tid*4+3];
    unsigned inc = s4;
    #pragma unroll
    for (int off = 1; off < 64; off <<= 1){
      unsigned o = __shfl_up(inc, off);
      if (tid >= off) inc += o;
    }
    exbase[tid] = inc - s4;
  }
  __syncthreads();
  {
    int g4 = tid >> 2;
    unsigned ex = exbase[g4];
    for (int j = g4*4; j < tid; j++) ex += psum[j];
    unsigned run = ex;
    #pragma unroll
    for (int i = 0; i < 16; i++){
      unsigned c = hist[tid*16 + i];
      if (run < 32u && run + c >= 32u){ sB = tid*16 + i; sBase = (int)run; }
      run += c;
    }
  }
  __syncthreads();
  int Bbin = sB, base = sBase;
  int out = cg << 5;
  #pragma unroll
  for (int t = 0; t < 32; t++){
    unsigned bits = (unsigned)f2i(dv[t]);
    unsigned hb = bits >> 20;
    int idx = tid*32 + t;
    if ((int)hb < Bbin){
      int sl = atomicAdd(&sCl, 1);
      knn[out + sl] = idx;
    } else if ((int)hb == Bbin){
      int c = atomicAdd(&sCc, 1);
      if (c < 512) cand[c] = (((unsigned long long)bits) << 32) | (unsigned)idx;
    }
  }
  __syncthreads();
  int cc = sCc; if (cc > 512) cc = 512;
  int r = 32 - base;
  for (int round = 0; round < r; round++){
    unsigned long long lm = ~0ull;
    for (int i = tid; i < cc; i += 256){
      unsigned long long v = cand[i];
      if (v < lm) lm = v;
    }
    #pragma unroll
    for (int off = 1; off < 64; off <<= 1){
      unsigned long long o = __shfl_xor(lm, off);
      if (o < lm) lm = o;
    }
    if ((tid & 63) == 0) rmin[tid >> 6] = lm;
    __syncthreads();
    if (tid == 0){
      unsigned long long m = rmin[0];
      #pragma unroll
      for (int q = 1; q < 4; q++) if (rmin[q] < m) m = rmin[q];
      swin = m;
      knn[out + base + round] = (int)(unsigned)m;
    }
    __syncthreads();
    unsigned long long m = swin;
    for (int i = tid; i < cc; i += 256)
      if (cand[i] == m) cand[i] = ~0ull;
    __syncthreads();
  }
}

// ---------------- materialized MLP passes (unchanged) ----------------
__device__ __forceinline__ bf16x8_t bfrag(const unsigned short* wp, int f, int lane){
  return *(const bf16x8_t*)(wp + ((size_t)f << 9) + (lane << 3));
}
__device__ __forceinline__ bf16x8_t bn_frag(bf16x8_t v, const float* a, const float* c, int kbase){
  float4 a0 = *(const float4*)(a + kbase); float4 a1 = *(const float4*)(a + kbase + 4);
  float4 c0 = *(const float4*)(c + kbase); float4 c1 = *(const float4*)(c + kbase + 4);
  float av[8] = {a0.x,a0.y,a0.z,a0.w,a1.x,a1.y,a1.z,a1.w};
  float cv[8] = {c0.x,c0.y,c0.z,c0.w,c1.x,c1.y,c1.z,c1.w};
  bf16x8_t r;
  #pragma unroll
  for (int j = 0; j < 8; j++)
    r[j] = (short)f2bf(fmaxf(bf2f((unsigned short)v[j])*av[j] + cv[j], 0.f));
  return r;
}

template<int TILES>
__global__ __launch_bounds__(256) void passA(
    const float* __restrict__ xyzf, const unsigned short* __restrict__ ptsb,
    const int* __restrict__ fpsi, const int* __restrict__ knn,
    const unsigned short* __restrict__ w0p,
    unsigned short* __restrict__ y0g, float* osum, float* osq)
{
  __shared__ unsigned short xb0[64*104];
  __shared__ unsigned short st[64*72];
  __shared__ float sacc[128];
  int tid = threadIdx.x, lane = tid & 63, w = tid >> 6;
  int l15 = lane & 15, quad = lane >> 4;
  float ssum[4], ssq[4];
  #pragma unroll
  for (int c = 0; c < 4; c++){ ssum[c] = 0.f; ssq[c] = 0.f; }
  if (tid < 128) sacc[tid] = 0.f;
  __syncthreads();

  for (int t = 0; t < TILES; t++){
    int row0 = (blockIdx.x * TILES + t) * 64;
    {
      int r = tid >> 2, p = tid & 3;
      int g = row0 + r;
      int bq = g >> 16, s = (g >> 5) & 2047;
      int n = knn[g];
      const bf16x8_t* pr = (const bf16x8_t*)(ptsb + (((size_t)bq*NN + n) << 6));
      *(bf16x8_t*)&xb0[r*104 + p*16]     = pr[p*2];
      *(bf16x8_t*)&xb0[r*104 + p*16 + 8] = pr[p*2 + 1];
      if (p == 3){
        const float* xbp = xyzf + (size_t)bq*NN*3;
        int f = fpsi[(bq << 11) + s];
        float dx = xbp[n*3]   - xbp[f*3];
        float dy = xbp[n*3+1] - xbp[f*3+1];
        float dz = xbp[n*3+2] - xbp[f*3+2];
        bf16x8_t v = {(short)f2bf(dx), (short)f2bf(dy), (short)f2bf(dz), 0,0,0,0,0};
        bf16x8_t z = {0,0,0,0,0,0,0,0};
        *(bf16x8_t*)&xb0[r*104 + 64] = v;
        *(bf16x8_t*)&xb0[r*104 + 72] = z;
        *(bf16x8_t*)&xb0[r*104 + 80] = z;
        *(bf16x8_t*)&xb0[r*104 + 88] = z;
      }
    }
    bf16x8_t a0[3];
    #pragma unroll
    for (int ks = 0; ks < 3; ks++)
      a0[ks] = *(const bf16x8_t*)&xb0[(w*16 + l15)*104 + ks*32 + quad*8];
    #pragma unroll
    for (int ct = 0; ct < 4; ct++){
      f32x4_t a = {0.f,0.f,0.f,0.f};
      #pragma unroll
      for (int ks = 0; ks < 3; ks++)
        a = __builtin_amdgcn_mfma_f32_16x16x32_bf16(a0[ks], bfrag(w0p, ct*3+ks, lane), a, 0, 0, 0);
      #pragma unroll
      for (int r = 0; r < 4; r++){
        float v = a[r]; ssum[ct] += v; ssq[ct] += v*v;
        st[(w*16 + quad*4 + r)*72 + ct*16 + l15] = f2bf(v);
      }
    }
    __syncthreads();
    #pragma unroll
    for (int p = 0; p < 2; p++){
      int idx = p*2048 + tid*8; int r = idx >> 6; int c = idx & 63;
      *(bf16x8_t*)(y0g + (size_t)row0*64 + idx) = *(const bf16x8_t*)&st[r*72 + c];
    }
    __syncthreads();
  }
  #pragma unroll
  for (int c = 0; c < 4; c++){
    ssum[c] += __shfl_xor(ssum[c], 16); ssum[c] += __shfl_xor(ssum[c], 32);
    ssq [c] += __shfl_xor(ssq [c], 16); ssq [c] += __shfl_xor(ssq [c], 32);
  }
  if (quad == 0){
    #pragma unroll
    for (int c = 0; c < 4; c++){
      atomicAdd(&sacc[c*16 + l15], ssum[c]);
      atomicAdd(&sacc[64 + c*16 + l15], ssq[c]);
    }
  }
  __syncthreads();
  if (tid < 64){
    atomicAdd(&osum[tid], sacc[tid]);
    atomicAdd(&osq [tid], sacc[64 + tid]);
  }
}

template<int TILES>
__global__ __launch_bounds__(256) void passB(
    const unsigned short* __restrict__ y0g, const unsigned short* __restrict__ w1p,
    const float* __restrict__ bnac,
    unsigned short* __restrict__ y1g, float* osum, float* osq)
{
  __shared__ unsigned short st[64*136];
  __shared__ float sacc[256];
  int tid = threadIdx.x, lane = tid & 63, w = tid >> 6;
  int l15 = lane & 15, quad = lane >> 4;
  float ssum[8], ssq[8];
  #pragma unroll
  for (int c = 0; c < 8; c++){ ssum[c] = 0.f; ssq[c] = 0.f; }
  sacc[tid] = 0.f;
  __syncthreads();

  for (int t = 0; t < TILES; t++){
    int row0 = (blockIdx.x * TILES + t) * 64;
    int row = row0 + w*16 + l15;
    bf16x8_t a1[2];
    #pragma unroll
    for (int ks = 0; ks < 2; ks++){
      bf16x8_t v = *(const bf16x8_t*)(y0g + (size_t)row*64 + ks*32 + quad*8);
      a1[ks] = bn_frag(v, bnac, bnac + 64, ks*32 + quad*8);
    }
    #pragma unroll
    for (int ct = 0; ct < 8; ct++){
      f32x4_t a = {0.f,0.f,0.f,0.f};
      #pragma unroll
      for (int ks = 0; ks < 2; ks++)
        a = __builtin_amdgcn_mfma_f32_16x16x32_bf16(a1[ks], bfrag(w1p, ct*2+ks, lane), a, 0, 0, 0);
      #pragma unroll
      for (int r = 0; r < 4; r++){
        float v = a[r]; ssum[ct] += v; ssq[ct] += v*v;
        st[(w*16 + quad*4 + r)*136 + ct*16 + l15] = f2bf(v);
      }
    }
    __syncthreads();
    #pragma unroll
    for (int p = 0; p < 4; p++){
      int idx = p*2048 + tid*8; int r = idx >> 7; int c = idx & 127;
      *(bf16x8_t*)(y1g + (size_t)row0*128 + idx) = *(const bf16x8_t*)&st[r*136 + c];
    }
    __syncthreads();
  }
  #pragma unroll
  for (int c = 0; c < 8; c++){
    ssum[c] += __shfl_xor(ssum[c], 16); ssum[c] += __shfl_xor(ssum[c], 32);
    ssq [c] += __shfl_xor(ssq [c], 16); ssq [c] += __shfl_xor(ssq [c], 32);
  }
  if (quad == 0){
    #pragma unroll
    for (int c = 0; c < 8; c++){
      atomicAdd(&sacc[c*16 + l15], ssum[c]);
      atomicAdd(&sacc[128 + c*16 + l15], ssq[c]);
    }
  }
  __syncthreads();
  if (tid < 128){
    atomicAdd(&osum[tid], sacc[tid]);
    atomicAdd(&osq [tid], sacc[128 + tid]);
  }
}

template<int TILES>
__global__ __launch_bounds__(256) void passC(
    const unsigned short* __restrict__ y1g, const unsigned short* __restrict__ w2p,
    const float* __restrict__ bnac, float* osum, float* osq)
{
  __shared__ float sacc[512];
  int tid = threadIdx.x, lane = tid & 63, w = tid >> 6;
  int l15 = lane & 15, quad = lane >> 4;
  float ssum[16], ssq[16];
  #pragma unroll
  for (int c = 0; c < 16; c++){ ssum[c] = 0.f; ssq[c] = 0.f; }
  sacc[tid] = 0.f; sacc[tid + 256] = 0.f;
  __syncthreads();

  for (int t = 0; t < TILES; t++){
    int row0 = (blockIdx.x * TILES + t) * 64;
    int row = row0 + w*16 + l15;
    bf16x8_t a2[4];
    #pragma unroll
    for (int ks = 0; ks < 4; ks++){
      bf16x8_t v = *(const bf16x8_t*)(y1g + (size_t)row*128 + ks*32 + quad*8);
      a2[ks] = bn_frag(v, bnac + 128, bnac + 256, ks*32 + quad*8);
    }
    #pragma unroll
    for (int ct = 0; ct < 16; ct++){
      f32x4_t a = {0.f,0.f,0.f,0.f};
      #pragma unroll
      for (int ks = 0; ks < 4; ks++)
        a = __builtin_amdgcn_mfma_f32_16x16x32_bf16(a2[ks], bfrag(w2p, ct*4+ks, lane), a, 0, 0, 0);
      #pragma unroll
      for (int r = 0; r < 4; r++){ float v = a[r]; ssum[ct] += v; ssq[ct] += v*v; }
    }
  }
  #pragma unroll
  for (int c = 0; c < 16; c++){
    ssum[c] += __shfl_xor(ssum[c], 16); ssum[c] += __shfl_xor(ssum[c], 32);
    ssq [c] += __shfl_xor(ssq [c], 16); ssq [c] += __shfl_xor(ssq [c], 32);
  }
  if (quad == 0){
    #pragma unroll
    for (int c = 0; c < 16; c++){
      atomicAdd(&sacc[c*16 + l15], ssum[c]);
      atomicAdd(&sacc[256 + c*16 + l15], ssq[c]);
    }
  }
  __syncthreads();
  if (tid < 256){
    atomicAdd(&osum[tid], sacc[tid]);
    atomicAdd(&osq [tid], sacc[256 + tid]);
  }
}

__global__ __launch_bounds__(256) void passD(
    const unsigned short* __restrict__ y1g, const unsigned short* __restrict__ w2p,
    const float* __restrict__ bnac, void* d_out, const int* __restrict__ flag)
{
  __shared__ float smax[1024];
  int tid = threadIdx.x, lane = tid & 63, w = tid >> 6;
  int l15 = lane & 15, quad = lane >> 4;
  int row0 = blockIdx.x * 64;
  int row = row0 + w*16 + l15;
  bf16x8_t a2[4];
  #pragma unroll
  for (int ks = 0; ks < 4; ks++){
    bf16x8_t v = *(const bf16x8_t*)(y1g + (size_t)row*128 + ks*32 + quad*8);
    a2[ks] = bn_frag(v, bnac + 128, bnac + 256, ks*32 + quad*8);
  }
  #pragma unroll
  for (int ct = 0; ct < 16; ct++){
    f32x4_t a = {0.f,0.f,0.f,0.f};
    #pragma unroll
    for (int ks = 0; ks < 4; ks++)
      a = __builtin_amdgcn_mfma_f32_16x16x32_bf16(a2[ks], bfrag(w2p, ct*4+ks, lane), a, 0, 0, 0);
    int o = ct*16 + l15;
    float ga = bnac[384 + o], gc = bnac[640 + o];
    float m = fmaxf(fmaxf(a[0]*ga + gc, a[1]*ga + gc), fmaxf(a[2]*ga + gc, a[3]*ga + gc));
    m = fmaxf(m, __shfl_xor(m, 16));
    m = fmaxf(m, __shfl_xor(m, 32));
    if (quad == 0) smax[w*256 + o] = m;
  }
  __syncthreads();
  float v0 = fmaxf(fmaxf(smax[tid], smax[256 + tid]), 0.f);
  float v1 = fmaxf(fmaxf(smax[512 + tid], smax[768 + tid]), 0.f);
  int cg = blockIdx.x * 2;
  bool isf32 = (*flag != 0);
  int b0 = cg >> 11, s0 = cg & 2047;
  int b1 = (cg+1) >> 11, s1 = (cg+1) & 2047;
  size_t o0 = (size_t)BB*SS*3 + (((size_t)(b0*256 + tid)) << 11) + s0;
  size_t o1 = (size_t)BB*SS*3 + (((size_t)(b1*256 + tid)) << 11) + s1;
  if (isf32){ ((float*)d_out)[o0] = v0; ((float*)d_out)[o1] = v1; }
  else { ((unsigned short*)d_out)[o0] = f2bf(v0); ((unsigned short*)d_out)[o1] = f2bf(v1); }
}

__global__ void bn_finalize(const float* sum, const float* sq, const float* g, const float* bb,
                            float* a, float* c, int n){
  int o = blockIdx.x*64 + threadIdx.x;
  if (o >= n) return;
  const float invM = 1.0f/262144.0f;
  float mu = sum[o]*invM;
  float var = sq[o]*invM - mu*mu; var = fmaxf(var, 0.f);
  float inv = 1.0f/sqrtf(var + 1e-5f);
  float av = g[o]*inv;
  a[o] = av; c[o] = bb[o] - mu*av;
}

// ---------------- workspace layout (bytes) ----------------
// Sorted-point arrays overlap the y0 region: they are consumed by fps_kernel,
// which completes before passA writes y0 (stream-ordered).
#define OFF_FLAG   0u
#define OFF_FPS    256u
#define OFF_KNN    33024u
#define OFF_STATS  1081600u
#define OFF_BNAC   1085184u
#define OFF_XYZF   1088768u
#define OFF_GB     1481984u
#define OFF_W0P    1485568u
#define OFF_W1P    1497856u
#define OFF_W2P    1514240u
#define OFF_PTSB   1579776u
#define OFF_Y0     5774336u
#define OFF_Y1     39328768u
#define OFF_PSX    (OFF_Y0)
#define OFF_PSY    (OFF_Y0 + 131072u)
#define OFF_PSZ    (OFF_Y0 + 262144u)
#define OFF_IOR    (OFF_Y0 + 393216u)

extern "C" void kernel_launch(void* const* d_in, const int* in_sizes, int n_in,
                              void* d_out, int out_size, void* d_ws, size_t ws_size,
                              hipStream_t stream){
  char* ws = (char*)d_ws;
  int*   flag  = (int*)(ws + OFF_FLAG);
  int*   fpsi  = (int*)(ws + OFF_FPS);
  int*   knn   = (int*)(ws + OFF_KNN);
  float* stats = (float*)(ws + OFF_STATS);
  float* bnac  = (float*)(ws + OFF_BNAC);
  float* xyzf  = (float*)(ws + OFF_XYZF);
  float* gbf   = (float*)(ws + OFF_GB);
  unsigned short* w0p = (unsigned short*)(ws + OFF_W0P);
  unsigned short* w1p = (unsigned short*)(ws + OFF_W1P);
  unsigned short* w2p = (unsigned short*)(ws + OFF_W2P);
  unsigned short* ptsb = (unsigned short*)(ws + OFF_PTSB);
  unsigned short* y0g = (unsigned short*)(ws + OFF_Y0);
  unsigned short* y1g = (unsigned short*)(ws + OFF_Y1);
  float* psx = (float*)(ws + OFF_PSX);
  float* psy = (float*)(ws + OFF_PSY);
  float* psz = (float*)(ws + OFF_PSZ);
  int*   ior = (int*)(ws + OFF_IOR);

  hipMemsetAsync(ws + OFF_STATS, 0, 896*4, stream);
  detect_kernel<<<1, 256, 0, stream>>>(d_in[1], flag);

  convert_kernel<<<384, 256, 0, stream>>>(d_in[0], xyzf, BB*NN*3, flag);
  convert_gb<<<4, 256, 0, stream>>>(d_in[3], d_in[4], d_in[6], d_in[7], d_in[9], d_in[10], gbf, flag);
  transpose_pts_bf16<<<512, 256, 0, stream>>>(d_in[1], ptsb, flag);

  pack_w<<<24,  256, 0, stream>>>(d_in[2], w0p, 4, 3, 67, 1, flag);
  pack_w<<<32,  256, 0, stream>>>(d_in[5], w1p, 8, 2, 64, 0, flag);
  pack_w<<<128, 256, 0, stream>>>(d_in[8], w2p, 16, 4, 128, 0, flag);

  morton_sort<<<BB, 1024, 0, stream>>>(xyzf, psx, psy, psz, ior);
  fps_kernel<<<BB, 1024, 0, stream>>>(xyzf, psx, psy, psz, ior, fpsi, d_out, flag);
  knn_kernel<<<BB*SS, 256, 0, stream>>>(xyzf, fpsi, knn);

  passA<4><<<1024, 256, 0, stream>>>(xyzf, ptsb, fpsi, knn, w0p, y0g, stats + 0, stats + 64);
  bn_finalize<<<1, 64, 0, stream>>>(stats + 0, stats + 64, gbf + 0, gbf + 64, bnac + 0, bnac + 64, 64);

  passB<4><<<1024, 256, 0, stream>>>(y0g, w1p, bnac, y1g, stats + 128, stats + 256);
  bn_finalize<<<2, 64, 0, stream>>>(stats + 128, stats + 256, gbf + 128, gbf + 256, bnac + 128, bnac + 256, 128);

  passC<4><<<1024, 256, 0, stream>>>(y1g, w2p, bnac, stats + 384, stats + 640);
  bn_finalize<<<4, 64, 0, stream>>>(stats + 384, stats + 640, gbf + 384, gbf + 640, bnac + 384, bnac + 640, 256);

  passD<<<4096, 256, 0, stream>>>(y1g, w2p, bnac, d_out, flag);
  (void)in_sizes; (void)n_in; (void)out_size; (void)ws_size;
}

// Round 10
// 2636.637 us; speedup vs baseline: 2.7611x; 1.0126x over previous
//
#include <hip/hip_runtime.h>

#define BB 4
#define NN 8192
#define CC 64
#define SS 2048
#define KK 32
#define MROWS (BB*SS*KK)   // 262144

typedef __attribute__((ext_vector_type(8))) short bf16x8_t;
typedef __attribute__((ext_vector_type(4))) float f32x4_t;
typedef __attribute__((ext_vector_type(2))) float f32x2_t;

__device__ __forceinline__ float bf2f(unsigned short u){
  union { unsigned int i; float f; } v; v.i = ((unsigned int)u) << 16; return v.f;
}
__device__ __forceinline__ unsigned short f2bf(float f){
  union { float f; unsigned int i; } v; v.f = f;
  unsigned int u = v.i;
  unsigned int r = (u + 0x7FFFu + ((u >> 16) & 1u)) >> 16;
  return (unsigned short)r;
}
__device__ __forceinline__ float i2f(int i){ union { int i; float f; } v; v.i = i; return v.f; }
__device__ __forceinline__ int f2i(float f){ union { float f; int i; } v; v.f = f; return v.i; }

// ---------------- dtype detection ----------------
__global__ void detect_kernel(const void* pts, int* flag){
  __shared__ int cnt;
  if (threadIdx.x == 0) cnt = 0;
  __syncthreads();
  unsigned short u = ((const unsigned short*)pts)[threadIdx.x];
  int e = (u >> 7) & 0xFF;
  if (e != 0 && (e < 112 || e > 143)) atomicAdd(&cnt, 1);
  __syncthreads();
  if (threadIdx.x == 0) *flag = (cnt > 32) ? 1 : 0;
}

__global__ void convert_kernel(const void* src, float* dst, int n, const int* flag){
  int i = blockIdx.x*256 + threadIdx.x;
  if (i >= n) return;
  dst[i] = (*flag != 0) ? ((const float*)src)[i] : bf2f(((const unsigned short*)src)[i]);
}

__global__ void convert_gb(const void* g0, const void* b0, const void* g1, const void* b1,
                           const void* g2, const void* b2, float* dst, const int* flag){
  int i = blockIdx.x*256 + threadIdx.x;   // 896 total
  if (i >= 896) return;
  const void* src; int off;
  if      (i < 64)  { src = g0; off = i; }
  else if (i < 128) { src = b0; off = i - 64; }
  else if (i < 256) { src = g1; off = i - 128; }
  else if (i < 384) { src = b1; off = i - 256; }
  else if (i < 640) { src = g2; off = i - 384; }
  else              { src = b2; off = i - 640; }
  dst[i] = (*flag != 0) ? ((const float*)src)[off] : bf2f(((const unsigned short*)src)[off]);
}

// (B,C,N) -> (B,N,C) bf16
__global__ __launch_bounds__(256) void transpose_pts_bf16(const void* pts, unsigned short* out, const int* flag){
  __shared__ float tile[64][65];
  int bx = blockIdx.x; int b = bx >> 7; int n0 = (bx & 127) * 64; int tid = threadIdx.x;
  bool isf = (*flag != 0);
  #pragma unroll
  for (int k = 0; k < 16; k++){
    int idx = k*256 + tid; int c = idx >> 6; int ni = idx & 63;
    size_t src = ((size_t)b*CC + c)*NN + n0 + ni;
    tile[c][ni] = isf ? ((const float*)pts)[src] : bf2f(((const unsigned short*)pts)[src]);
  }
  __syncthreads();
  #pragma unroll
  for (int k = 0; k < 16; k++){
    int idx = k*256 + tid; int ni = idx >> 6; int c = idx & 63;
    out[((size_t)b*NN + n0 + ni)*CC + c] = f2bf(tile[c][ni]);
  }
}

// pack weights into MFMA B-fragment order (bf16)
__global__ void pack_w(const void* src, unsigned short* dst, int CTS, int KSTEPS, int IN, int remap, const int* flag){
  int idx = blockIdx.x*256 + threadIdx.x;
  int total = CTS*KSTEPS*512;
  if (idx >= total) return;
  int f = idx >> 9, lane = (idx >> 3) & 63, j = idx & 7;
  int ct = f / KSTEPS, ks = f % KSTEPS;
  int n = ct*16 + (lane & 15);
  int k = ks*32 + (lane >> 4)*8 + j;
  int ksrc;
  if (remap){ ksrc = (k < 64) ? (k + 3) : (k < 67 ? k - 64 : -1); }
  else      { ksrc = (k < IN) ? k : -1; }
  float v = 0.f;
  if (ksrc >= 0){
    size_t si = (size_t)n*IN + ksrc;
    v = (*flag != 0) ? ((const float*)src)[si] : bf2f(((const unsigned short*)src)[si]);
  }
  dst[idx] = f2bf(v);
}

// ---------------- Morton bucket scatter (one block per batch) ----------------
__device__ __forceinline__ unsigned mspread(unsigned v){
  v = (v | (v << 16)) & 0x030000FFu;
  v = (v | (v <<  8)) & 0x0300F00Fu;
  v = (v | (v <<  4)) & 0x030C30C3u;
  v = (v | (v <<  2)) & 0x09249249u;
  return v;
}
__global__ __launch_bounds__(1024) void morton_sort(const float* xyzf,
    float* psx, float* psy, float* psz, int* iorig){
  int b = blockIdx.x, tid = threadIdx.x;
  const float* xb = xyzf + (size_t)b*NN*3;
  __shared__ unsigned codes[NN];   // 32 KB
  __shared__ unsigned hist[256];
  __shared__ unsigned curs[256];
  __shared__ float rbb[96];
  float x[8], y[8], z[8];
  {
    const float4* p4 = (const float4*)(xb + (size_t)tid*24);
    float4 A=p4[0],B2=p4[1],C=p4[2],D=p4[3],E=p4[4],F=p4[5];
    x[0]=A.x;  y[0]=A.y;  z[0]=A.z;
    x[1]=A.w;  y[1]=B2.x; z[1]=B2.y;
    x[2]=B2.z; y[2]=B2.w; z[2]=C.x;
    x[3]=C.y;  y[3]=C.z;  z[3]=C.w;
    x[4]=D.x;  y[4]=D.y;  z[4]=D.z;
    x[5]=D.w;  y[5]=E.x;  z[5]=E.y;
    x[6]=E.z;  y[6]=E.w;  z[6]=F.x;
    x[7]=F.y;  y[7]=F.z;  z[7]=F.w;
  }
  float lx=x[0],hx=x[0],ly=y[0],hy=y[0],lz=z[0],hz=z[0];
  #pragma unroll
  for (int j = 1; j < 8; j++){
    lx=fminf(lx,x[j]); hx=fmaxf(hx,x[j]);
    ly=fminf(ly,y[j]); hy=fmaxf(hy,y[j]);
    lz=fminf(lz,z[j]); hz=fmaxf(hz,z[j]);
  }
  #pragma unroll
  for (int off = 1; off < 64; off <<= 1){
    lx=fminf(lx,__shfl_xor(lx,off)); hx=fmaxf(hx,__shfl_xor(hx,off));
    ly=fminf(ly,__shfl_xor(ly,off)); hy=fmaxf(hy,__shfl_xor(hy,off));
    lz=fminf(lz,__shfl_xor(lz,off)); hz=fmaxf(hz,__shfl_xor(hz,off));
  }
  int w = tid >> 6;
  if ((tid & 63) == 0){
    rbb[w]=lx; rbb[16+w]=hx; rbb[32+w]=ly; rbb[48+w]=hy; rbb[64+w]=lz; rbb[80+w]=hz;
  }
  if (tid < 256) hist[tid] = 0;
  __syncthreads();
  #pragma unroll
  for (int i = 0; i < 16; i++){
    lx=fminf(lx,rbb[i]); hx=fmaxf(hx,rbb[16+i]);
    ly=fminf(ly,rbb[32+i]); hy=fmaxf(hy,rbb[48+i]);
    lz=fminf(lz,rbb[64+i]); hz=fmaxf(hz,rbb[80+i]);
  }
  float sx = 1023.0f/fmaxf(hx-lx,1e-20f);
  float sy = 1023.0f/fmaxf(hy-ly,1e-20f);
  float sz = 1023.0f/fmaxf(hz-lz,1e-20f);
  #pragma unroll
  for (int j = 0; j < 8; j++){
    int qx = (int)((x[j]-lx)*sx); qx = qx < 0 ? 0 : (qx > 1023 ? 1023 : qx);
    int qy = (int)((y[j]-ly)*sy); qy = qy < 0 ? 0 : (qy > 1023 ? 1023 : qy);
    int qz = (int)((z[j]-lz)*sz); qz = qz < 0 ? 0 : (qz > 1023 ? 1023 : qz);
    unsigned code = mspread((unsigned)qx) | (mspread((unsigned)qy) << 1) | (mspread((unsigned)qz) << 2);
    codes[tid*8 + j] = code;
    atomicAdd(&hist[code >> 22], 1u);
  }
  __syncthreads();
  if (tid < 64){
    unsigned h0 = hist[tid*4], h1 = hist[tid*4+1], h2 = hist[tid*4+2], h3 = hist[tid*4+3];
    unsigned s4 = h0 + h1 + h2 + h3;
    unsigned inc = s4;
    #pragma unroll
    for (int off = 1; off < 64; off <<= 1){
      unsigned o = __shfl_up(inc, off);
      if (tid >= off) inc += o;
    }
    unsigned base = inc - s4;
    curs[tid*4]   = base;
    curs[tid*4+1] = base + h0;
    curs[tid*4+2] = base + h0 + h1;
    curs[tid*4+3] = base + h0 + h1 + h2;
  }
  __syncthreads();
  #pragma unroll
  for (int j = 0; j < 8; j++){
    unsigned c = codes[tid*8 + j] >> 22;
    unsigned pos = atomicAdd(&curs[c], 1u);
    psx[b*NN + pos] = x[j];
    psy[b*NN + pos] = y[j];
    psz[b*NN + pos] = z[j];
    iorig[b*NN + pos] = tid*8 + j;
  }
}

// ---------------- DPP helpers ----------------
template<int C>
__device__ __forceinline__ float dpp_maxf(float v){
  int t = __builtin_amdgcn_update_dpp(0, f2i(v), C, 0xF, 0xF, true);
  return fmaxf(v, i2f(t));
}
template<int C>
__device__ __forceinline__ unsigned dpp_minu(unsigned v){
  unsigned t = (unsigned)__builtin_amdgcn_update_dpp(-1, (int)v, C, 0xF, 0xF, false);
  return v < t ? v : t;
}
template<int C>
__device__ __forceinline__ void dpp_max64(unsigned &lo, unsigned &hi){
  unsigned tlo = (unsigned)__builtin_amdgcn_update_dpp(0, (int)lo, C, 0xF, 0xF, true);
  unsigned thi = (unsigned)__builtin_amdgcn_update_dpp(0, (int)hi, C, 0xF, 0xF, true);
  if (thi > hi || (thi == hi && tlo > lo)){ lo = tlo; hi = thi; }
}

// ---------------- FPS: Morton-grouped + wave bbox pruning (exact) ----------------
__global__ __launch_bounds__(1024, 1) void fps_kernel(const float* xyzf,
    const float* psx, const float* psy, const float* psz, const int* iorig,
    int* fps_idx, void* d_out, const int* flag){
  int b = blockIdx.x, tid = threadIdx.x;
  const float* xb = xyzf + (size_t)b*NN*3;
  __shared__ float sxyz[NN*3];
  __shared__ unsigned long long ru[2][16];
  for (int i = tid; i < NN*3/4; i += 1024)
    ((float4*)sxyz)[i] = ((const float4*)xb)[i];
  f32x2_t px2[4], py2[4], pz2[4], dmin2[4];
  int io[8];
  {
    const float4* qx = (const float4*)(psx + b*NN + tid*8);
    const float4* qy = (const float4*)(psy + b*NN + tid*8);
    const float4* qz = (const float4*)(psz + b*NN + tid*8);
    float4 a, c;
    a = qx[0]; c = qx[1];
    px2[0]=(f32x2_t){a.x,a.y}; px2[1]=(f32x2_t){a.z,a.w}; px2[2]=(f32x2_t){c.x,c.y}; px2[3]=(f32x2_t){c.z,c.w};
    a = qy[0]; c = qy[1];
    py2[0]=(f32x2_t){a.x,a.y}; py2[1]=(f32x2_t){a.z,a.w}; py2[2]=(f32x2_t){c.x,c.y}; py2[3]=(f32x2_t){c.z,c.w};
    a = qz[0]; c = qz[1];
    pz2[0]=(f32x2_t){a.x,a.y}; pz2[1]=(f32x2_t){a.z,a.w}; pz2[2]=(f32x2_t){c.x,c.y}; pz2[3]=(f32x2_t){c.z,c.w};
    const int4* qi = (const int4*)(iorig + b*NN + tid*8);
    int4 i0 = qi[0], i1 = qi[1];
    io[0]=i0.x; io[1]=i0.y; io[2]=i0.z; io[3]=i0.w;
    io[4]=i1.x; io[5]=i1.y; io[6]=i1.z; io[7]=i1.w;
  }
  #pragma unroll
  for (int q = 0; q < 4; q++) dmin2[q] = (f32x2_t){1e10f, 1e10f};
  float blox, bhix, bloy, bhiy, bloz, bhiz;
  {
    float lx = fminf(fminf(px2[0].x,px2[0].y), fminf(px2[1].x,px2[1].y));
    lx = fminf(lx, fminf(fminf(px2[2].x,px2[2].y), fminf(px2[3].x,px2[3].y)));
    float hx = fmaxf(fmaxf(px2[0].x,px2[0].y), fmaxf(px2[1].x,px2[1].y));
    hx = fmaxf(hx, fmaxf(fmaxf(px2[2].x,px2[2].y), fmaxf(px2[3].x,px2[3].y)));
    float ly = fminf(fminf(py2[0].x,py2[0].y), fminf(py2[1].x,py2[1].y));
    ly = fminf(ly, fminf(fminf(py2[2].x,py2[2].y), fminf(py2[3].x,py2[3].y)));
    float hy = fmaxf(fmaxf(py2[0].x,py2[0].y), fmaxf(py2[1].x,py2[1].y));
    hy = fmaxf(hy, fmaxf(fmaxf(py2[2].x,py2[2].y), fmaxf(py2[3].x,py2[3].y)));
    float lz = fminf(fminf(pz2[0].x,pz2[0].y), fminf(pz2[1].x,pz2[1].y));
    lz = fminf(lz, fminf(fminf(pz2[2].x,pz2[2].y), fminf(pz2[3].x,pz2[3].y)));
    float hz = fmaxf(fmaxf(pz2[0].x,pz2[0].y), fmaxf(pz2[1].x,pz2[1].y));
    hz = fmaxf(hz, fmaxf(fmaxf(pz2[2].x,pz2[2].y), fmaxf(pz2[3].x,pz2[3].y)));
    #pragma unroll
    for (int off = 1; off < 64; off <<= 1){
      lx=fminf(lx,__shfl_xor(lx,off)); hx=fmaxf(hx,__shfl_xor(hx,off));
      ly=fminf(ly,__shfl_xor(ly,off)); hy=fmaxf(hy,__shfl_xor(hy,off));
      lz=fminf(lz,__shfl_xor(lz,off)); hz=fmaxf(hz,__shfl_xor(hz,off));
    }
    blox=lx; bhix=hx; bloy=ly; bhiy=hy; bloz=lz; bhiz=hz;
  }
  __syncthreads();
  int far = 0;
  bool isf32 = (*flag != 0);
  float* outf = (float*)d_out; unsigned short* outh = (unsigned short*)d_out;
  int w = tid >> 6, ln = tid & 63;
  unsigned cached_lo = 0u, cached_hi = 0u;
  for (int s = 0; s < SS; s++){
    float cx = sxyz[far*3], cy = sxyz[far*3+1], cz = sxyz[far*3+2];
    if (tid == 0){
      fps_idx[b*SS + s] = far;
      size_t o = ((size_t)b*SS + s)*3;
      if (isf32){ outf[o]=cx; outf[o+1]=cy; outf[o+2]=cz; }
      else { outh[o]=f2bf(cx); outh[o+1]=f2bf(cy); outh[o+2]=f2bf(cz); }
    }
    float dxl = fmaxf(fmaxf(blox - cx, cx - bhix), 0.f);
    float dyl = fmaxf(fmaxf(bloy - cy, cy - bhiy), 0.f);
    float dzl = fmaxf(fmaxf(bloz - cz, cz - bhiz), 0.f);
    float d2bb = (dxl*dxl + dyl*dyl + dzl*dzl) * 0.99999f;
    bool upd = (s == 0) || (d2bb < i2f((int)cached_hi));
    if (upd){
      f32x2_t cx2 = (f32x2_t){cx, cx}, cy2 = (f32x2_t){cy, cy}, cz2 = (f32x2_t){cz, cz};
      {
        #pragma clang fp contract(off)
        #pragma unroll
        for (int q = 0; q < 4; q++){
          f32x2_t dx = px2[q] - cx2, dy = py2[q] - cy2, dz = pz2[q] - cz2;
          f32x2_t t = dx*dx;
          t = t + dy*dy;
          t = t + dz*dz;
          dmin2[q].x = fminf(dmin2[q].x, t.x);
          dmin2[q].y = fminf(dmin2[q].y, t.y);
        }
      }
      float m0 = fmaxf(fmaxf(dmin2[0].x, dmin2[0].y), fmaxf(dmin2[1].x, dmin2[1].y));
      float m1 = fmaxf(fmaxf(dmin2[2].x, dmin2[2].y), fmaxf(dmin2[3].x, dmin2[3].y));
      float lm = fmaxf(m0, m1);
      lm = dpp_maxf<0x111>(lm); lm = dpp_maxf<0x112>(lm);
      lm = dpp_maxf<0x114>(lm); lm = dpp_maxf<0x118>(lm);
      lm = dpp_maxf<0x142>(lm); lm = dpp_maxf<0x143>(lm);
      float wmax = i2f(__builtin_amdgcn_readlane(f2i(lm), 63));
      unsigned cand = 0xFFFFFFFFu;
      #pragma unroll
      for (int q = 0; q < 4; q++){
        if (dmin2[q].x == wmax){ unsigned u = (unsigned)io[2*q];   cand = u < cand ? u : cand; }
        if (dmin2[q].y == wmax){ unsigned u = (unsigned)io[2*q+1]; cand = u < cand ? u : cand; }
      }
      cand = dpp_minu<0x111>(cand); cand = dpp_minu<0x112>(cand);
      cand = dpp_minu<0x114>(cand); cand = dpp_minu<0x118>(cand);
      cand = dpp_minu<0x142>(cand); cand = dpp_minu<0x143>(cand);
      unsigned cmin = (unsigned)__builtin_amdgcn_readlane((int)cand, 63);
      cached_hi = (unsigned)f2i(wmax);
      cached_lo = ~cmin;
    }
    if (ln == 63) ru[s & 1][w] = (((unsigned long long)cached_hi) << 32) | cached_lo;
    __syncthreads();
    unsigned long long t = ru[s & 1][ln & 15];
    unsigned lo = (unsigned)t, hi = (unsigned)(t >> 32);
    dpp_max64<0x111>(lo, hi); dpp_max64<0x112>(lo, hi);
    dpp_max64<0x114>(lo, hi); dpp_max64<0x118>(lo, hi);
    far = (int)(~(unsigned)__builtin_amdgcn_readlane((int)lo, 63));
  }
}

// ---------------- kNN v3: radix-histogram selection, coalesced planar loads ----------------
__global__ __launch_bounds__(256) void knn_kernel(
    const float* psx, const float* psy, const float* psz, const int* ior,
    const float* xyzf, const int* fps_idx, int* knn){
  int cg = blockIdx.x;
  int b = cg >> 11;
  int tid = threadIdx.x;
  const float* xb = xyzf + (size_t)b*NN*3;
  __shared__ unsigned hist[4096];
  __shared__ unsigned long long cand[512];
  __shared__ unsigned psum[256];
  __shared__ unsigned exbase[64];
  __shared__ float scc[3];
  __shared__ int sB, sBase, sCl, sCc;
  __shared__ unsigned long long rmin[4];
  __shared__ unsigned long long swin;

  if (tid == 0){
    int f = fps_idx[cg];
    scc[0] = xb[f*3]; scc[1] = xb[f*3+1]; scc[2] = xb[f*3+2];
    sCl = 0; sCc = 0;
  }
  #pragma unroll
  for (int i = 0; i < 16; i++) hist[tid*16 + i] = 0;
  __syncthreads();
  float cx = scc[0], cy = scc[1], cz = scc[2];

  float dv[32]; int iv[32];
  const float4* qx = (const float4*)(psx + b*NN);
  const float4* qy = (const float4*)(psy + b*NN);
  const float4* qz = (const float4*)(psz + b*NN);
  const int4*   qi = (const int4*)(ior + b*NN);
  {
    #pragma clang fp contract(off)
    #pragma unroll
    for (int k = 0; k < 8; k++){
      float4 X = qx[k*256 + tid];
      float4 Y = qy[k*256 + tid];
      float4 Z = qz[k*256 + tid];
      int4   I = qi[k*256 + tid];
      float xs_[4] = {X.x, X.y, X.z, X.w};
      float ys_[4] = {Y.x, Y.y, Y.z, Y.w};
      float zs_[4] = {Z.x, Z.y, Z.z, Z.w};
      int   is_[4] = {I.x, I.y, I.z, I.w};
      #pragma unroll
      for (int r = 0; r < 4; r++){
        float dx = cx - xs_[r], dy = cy - ys_[r], dz = cz - zs_[r];
        dv[k*4 + r] = dx*dx + dy*dy + dz*dz;
        iv[k*4 + r] = is_[r];
      }
    }
  }
  #pragma unroll
  for (int t = 0; t < 32; t++)
    atomicAdd(&hist[((unsigned)f2i(dv[t])) >> 20], 1u);
  __syncthreads();
  unsigned lsum = 0;
  #pragma unroll
  for (int i = 0; i < 16; i++) lsum += hist[tid*16 + i];
  psum[tid] = lsum;
  __syncthreads();
  if (tid < 64){
    unsigned s4 = psum[tid*4] + psum[tid*4+1] + psum[tid*4+2] + psum[tid*4+3];
    unsigned inc = s4;
    #pragma unroll
    for (int off = 1; off < 64; off <<= 1){
      unsigned o = __shfl_up(inc, off);
      if (tid >= off) inc += o;
    }
    exbase[tid] = inc - s4;
  }
  __syncthreads();
  {
    int g4 = tid >> 2;
    unsigned ex = exbase[g4];
    for (int j = g4*4; j < tid; j++) ex += psum[j];
    unsigned run = ex;
    #pragma unroll
    for (int i = 0; i < 16; i++){
      unsigned c = hist[tid*16 + i];
      if (run < 32u && run + c >= 32u){ sB = tid*16 + i; sBase = (int)run; }
      run += c;
    }
  }
  __syncthreads();
  int Bbin = sB, base = sBase;
  int out = cg << 5;
  #pragma unroll
  for (int t = 0; t < 32; t++){
    unsigned bits = (unsigned)f2i(dv[t]);
    unsigned hb = bits >> 20;
    int idx = iv[t];
    if ((int)hb < Bbin){
      int sl = atomicAdd(&sCl, 1);
      knn[out + sl] = idx;
    } else if ((int)hb == Bbin){
      int c = atomicAdd(&sCc, 1);
      if (c < 512) cand[c] = (((unsigned long long)bits) << 32) | (unsigned)idx;
    }
  }
  __syncthreads();
  int cc = sCc; if (cc > 512) cc = 512;
  int r = 32 - base;
  for (int round = 0; round < r; round++){
    unsigned long long lm = ~0ull;
    for (int i = tid; i < cc; i += 256){
      unsigned long long v = cand[i];
      if (v < lm) lm = v;
    }
    #pragma unroll
    for (int off = 1; off < 64; off <<= 1){
      unsigned long long o = __shfl_xor(lm, off);
      if (o < lm) lm = o;
    }
    if ((tid & 63) == 0) rmin[tid >> 6] = lm;
    __syncthreads();
    if (tid == 0){
      unsigned long long m = rmin[0];
      #pragma unroll
      for (int q = 1; q < 4; q++) if (rmin[q] < m) m = rmin[q];
      swin = m;
      knn[out + base + round] = (int)(unsigned)m;
    }
    __syncthreads();
    unsigned long long m = swin;
    for (int i = tid; i < cc; i += 256)
      if (cand[i] == m) cand[i] = ~0ull;
    __syncthreads();
  }
}

// ---------------- materialized MLP passes (unchanged) ----------------
__device__ __forceinline__ bf16x8_t bfrag(const unsigned short* wp, int f, int lane){
  return *(const bf16x8_t*)(wp + ((size_t)f << 9) + (lane << 3));
}
__device__ __forceinline__ bf16x8_t bn_frag(bf16x8_t v, const float* a, const float* c, int kbase){
  float4 a0 = *(const float4*)(a + kbase); float4 a1 = *(const float4*)(a + kbase + 4);
  float4 c0 = *(const float4*)(c + kbase); float4 c1 = *(const float4*)(c + kbase + 4);
  float av[8] = {a0.x,a0.y,a0.z,a0.w,a1.x,a1.y,a1.z,a1.w};
  float cv[8] = {c0.x,c0.y,c0.z,c0.w,c1.x,c1.y,c1.z,c1.w};
  bf16x8_t r;
  #pragma unroll
  for (int j = 0; j < 8; j++)
    r[j] = (short)f2bf(fmaxf(bf2f((unsigned short)v[j])*av[j] + cv[j], 0.f));
  return r;
}

template<int TILES>
__global__ __launch_bounds__(256) void passA(
    const float* __restrict__ xyzf, const unsigned short* __restrict__ ptsb,
    const int* __restrict__ fpsi, const int* __restrict__ knn,
    const unsigned short* __restrict__ w0p,
    unsigned short* __restrict__ y0g, float* osum, float* osq)
{
  __shared__ unsigned short xb0[64*104];
  __shared__ unsigned short st[64*72];
  __shared__ float sacc[128];
  int tid = threadIdx.x, lane = tid & 63, w = tid >> 6;
  int l15 = lane & 15, quad = lane >> 4;
  float ssum[4], ssq[4];
  #pragma unroll
  for (int c = 0; c < 4; c++){ ssum[c] = 0.f; ssq[c] = 0.f; }
  if (tid < 128) sacc[tid] = 0.f;
  __syncthreads();

  for (int t = 0; t < TILES; t++){
    int row0 = (blockIdx.x * TILES + t) * 64;
    {
      int r = tid >> 2, p = tid & 3;
      int g = row0 + r;
      int bq = g >> 16, s = (g >> 5) & 2047;
      int n = knn[g];
      const bf16x8_t* pr = (const bf16x8_t*)(ptsb + (((size_t)bq*NN + n) << 6));
      *(bf16x8_t*)&xb0[r*104 + p*16]     = pr[p*2];
      *(bf16x8_t*)&xb0[r*104 + p*16 + 8] = pr[p*2 + 1];
      if (p == 3){
        const float* xbp = xyzf + (size_t)bq*NN*3;
        int f = fpsi[(bq << 11) + s];
        float dx = xbp[n*3]   - xbp[f*3];
        float dy = xbp[n*3+1] - xbp[f*3+1];
        float dz = xbp[n*3+2] - xbp[f*3+2];
        bf16x8_t v = {(short)f2bf(dx), (short)f2bf(dy), (short)f2bf(dz), 0,0,0,0,0};
        bf16x8_t z = {0,0,0,0,0,0,0,0};
        *(bf16x8_t*)&xb0[r*104 + 64] = v;
        *(bf16x8_t*)&xb0[r*104 + 72] = z;
        *(bf16x8_t*)&xb0[r*104 + 80] = z;
        *(bf16x8_t*)&xb0[r*104 + 88] = z;
      }
    }
    bf16x8_t a0[3];
    #pragma unroll
    for (int ks = 0; ks < 3; ks++)
      a0[ks] = *(const bf16x8_t*)&xb0[(w*16 + l15)*104 + ks*32 + quad*8];
    #pragma unroll
    for (int ct = 0; ct < 4; ct++){
      f32x4_t a = {0.f,0.f,0.f,0.f};
      #pragma unroll
      for (int ks = 0; ks < 3; ks++)
        a = __builtin_amdgcn_mfma_f32_16x16x32_bf16(a0[ks], bfrag(w0p, ct*3+ks, lane), a, 0, 0, 0);
      #pragma unroll
      for (int r = 0; r < 4; r++){
        float v = a[r]; ssum[ct] += v; ssq[ct] += v*v;
        st[(w*16 + quad*4 + r)*72 + ct*16 + l15] = f2bf(v);
      }
    }
    __syncthreads();
    #pragma unroll
    for (int p = 0; p < 2; p++){
      int idx = p*2048 + tid*8; int r = idx >> 6; int c = idx & 63;
      *(bf16x8_t*)(y0g + (size_t)row0*64 + idx) = *(const bf16x8_t*)&st[r*72 + c];
    }
    __syncthreads();
  }
  #pragma unroll
  for (int c = 0; c < 4; c++){
    ssum[c] += __shfl_xor(ssum[c], 16); ssum[c] += __shfl_xor(ssum[c], 32);
    ssq [c] += __shfl_xor(ssq [c], 16); ssq [c] += __shfl_xor(ssq [c], 32);
  }
  if (quad == 0){
    #pragma unroll
    for (int c = 0; c < 4; c++){
      atomicAdd(&sacc[c*16 + l15], ssum[c]);
      atomicAdd(&sacc[64 + c*16 + l15], ssq[c]);
    }
  }
  __syncthreads();
  if (tid < 64){
    atomicAdd(&osum[tid], sacc[tid]);
    atomicAdd(&osq [tid], sacc[64 + tid]);
  }
}

template<int TILES>
__global__ __launch_bounds__(256) void passB(
    const unsigned short* __restrict__ y0g, const unsigned short* __restrict__ w1p,
    const float* __restrict__ bnac,
    unsigned short* __restrict__ y1g, float* osum, float* osq)
{
  __shared__ unsigned short st[64*136];
  __shared__ float sacc[256];
  int tid = threadIdx.x, lane = tid & 63, w = tid >> 6;
  int l15 = lane & 15, quad = lane >> 4;
  float ssum[8], ssq[8];
  #pragma unroll
  for (int c = 0; c < 8; c++){ ssum[c] = 0.f; ssq[c] = 0.f; }
  sacc[tid] = 0.f;
  __syncthreads();

  for (int t = 0; t < TILES; t++){
    int row0 = (blockIdx.x * TILES + t) * 64;
    int row = row0 + w*16 + l15;
    bf16x8_t a1[2];
    #pragma unroll
    for (int ks = 0; ks < 2; ks++){
      bf16x8_t v = *(const bf16x8_t*)(y0g + (size_t)row*64 + ks*32 + quad*8);
      a1[ks] = bn_frag(v, bnac, bnac + 64, ks*32 + quad*8);
    }
    #pragma unroll
    for (int ct = 0; ct < 8; ct++){
      f32x4_t a = {0.f,0.f,0.f,0.f};
      #pragma unroll
      for (int ks = 0; ks < 2; ks++)
        a = __builtin_amdgcn_mfma_f32_16x16x32_bf16(a1[ks], bfrag(w1p, ct*2+ks, lane), a, 0, 0, 0);
      #pragma unroll
      for (int r = 0; r < 4; r++){
        float v = a[r]; ssum[ct] += v; ssq[ct] += v*v;
        st[(w*16 + quad*4 + r)*136 + ct*16 + l15] = f2bf(v);
      }
    }
    __syncthreads();
    #pragma unroll
    for (int p = 0; p < 4; p++){
      int idx = p*2048 + tid*8; int r = idx >> 7; int c = idx & 127;
      *(bf16x8_t*)(y1g + (size_t)row0*128 + idx) = *(const bf16x8_t*)&st[r*136 + c];
    }
    __syncthreads();
  }
  #pragma unroll
  for (int c = 0; c < 8; c++){
    ssum[c] += __shfl_xor(ssum[c], 16); ssum[c] += __shfl_xor(ssum[c], 32);
    ssq [c] += __shfl_xor(ssq [c], 16); ssq [c] += __shfl_xor(ssq [c], 32);
  }
  if (quad == 0){
    #pragma unroll
    for (int c = 0; c < 8; c++){
      atomicAdd(&sacc[c*16 + l15], ssum[c]);
      atomicAdd(&sacc[128 + c*16 + l15], ssq[c]);
    }
  }
  __syncthreads();
  if (tid < 128){
    atomicAdd(&osum[tid], sacc[tid]);
    atomicAdd(&osq [tid], sacc[128 + tid]);
  }
}

template<int TILES>
__global__ __launch_bounds__(256) void passC(
    const unsigned short* __restrict__ y1g, const unsigned short* __restrict__ w2p,
    const float* __restrict__ bnac, float* osum, float* osq)
{
  __shared__ float sacc[512];
  int tid = threadIdx.x, lane = tid & 63, w = tid >> 6;
  int l15 = lane & 15, quad = lane >> 4;
  float ssum[16], ssq[16];
  #pragma unroll
  for (int c = 0; c < 16; c++){ ssum[c] = 0.f; ssq[c] = 0.f; }
  sacc[tid] = 0.f; sacc[tid + 256] = 0.f;
  __syncthreads();

  for (int t = 0; t < TILES; t++){
    int row0 = (blockIdx.x * TILES + t) * 64;
    int row = row0 + w*16 + l15;
    bf16x8_t a2[4];
    #pragma unroll
    for (int ks = 0; ks < 4; ks++){
      bf16x8_t v = *(const bf16x8_t*)(y1g + (size_t)row*128 + ks*32 + quad*8);
      a2[ks] = bn_frag(v, bnac + 128, bnac + 256, ks*32 + quad*8);
    }
    #pragma unroll
    for (int ct = 0; ct < 16; ct++){
      f32x4_t a = {0.f,0.f,0.f,0.f};
      #pragma unroll
      for (int ks = 0; ks < 4; ks++)
        a = __builtin_amdgcn_mfma_f32_16x16x32_bf16(a2[ks], bfrag(w2p, ct*4+ks, lane), a, 0, 0, 0);
      #pragma unroll
      for (int r = 0; r < 4; r++){ float v = a[r]; ssum[ct] += v; ssq[ct] += v*v; }
    }
  }
  #pragma unroll
  for (int c = 0; c < 16; c++){
    ssum[c] += __shfl_xor(ssum[c], 16); ssum[c] += __shfl_xor(ssum[c], 32);
    ssq [c] += __shfl_xor(ssq [c], 16); ssq [c] += __shfl_xor(ssq [c], 32);
  }
  if (quad == 0){
    #pragma unroll
    for (int c = 0; c < 16; c++){
      atomicAdd(&sacc[c*16 + l15], ssum[c]);
      atomicAdd(&sacc[256 + c*16 + l15], ssq[c]);
    }
  }
  __syncthreads();
  if (tid < 256){
    atomicAdd(&osum[tid], sacc[tid]);
    atomicAdd(&osq [tid], sacc[256 + tid]);
  }
}

__global__ __launch_bounds__(256) void passD(
    const unsigned short* __restrict__ y1g, const unsigned short* __restrict__ w2p,
    const float* __restrict__ bnac, void* d_out, const int* __restrict__ flag)
{
  __shared__ float smax[1024];
  int tid = threadIdx.x, lane = tid & 63, w = tid >> 6;
  int l15 = lane & 15, quad = lane >> 4;
  int row0 = blockIdx.x * 64;
  int row = row0 + w*16 + l15;
  bf16x8_t a2[4];
  #pragma unroll
  for (int ks = 0; ks < 4; ks++){
    bf16x8_t v = *(const bf16x8_t*)(y1g + (size_t)row*128 + ks*32 + quad*8);
    a2[ks] = bn_frag(v, bnac + 128, bnac + 256, ks*32 + quad*8);
  }
  #pragma unroll
  for (int ct = 0; ct < 16; ct++){
    f32x4_t a = {0.f,0.f,0.f,0.f};
    #pragma unroll
    for (int ks = 0; ks < 4; ks++)
      a = __builtin_amdgcn_mfma_f32_16x16x32_bf16(a2[ks], bfrag(w2p, ct*4+ks, lane), a, 0, 0, 0);
    int o = ct*16 + l15;
    float ga = bnac[384 + o], gc = bnac[640 + o];
    float m = fmaxf(fmaxf(a[0]*ga + gc, a[1]*ga + gc), fmaxf(a[2]*ga + gc, a[3]*ga + gc));
    m = fmaxf(m, __shfl_xor(m, 16));
    m = fmaxf(m, __shfl_xor(m, 32));
    if (quad == 0) smax[w*256 + o] = m;
  }
  __syncthreads();
  float v0 = fmaxf(fmaxf(smax[tid], smax[256 + tid]), 0.f);
  float v1 = fmaxf(fmaxf(smax[512 + tid], smax[768 + tid]), 0.f);
  int cg = blockIdx.x * 2;
  bool isf32 = (*flag != 0);
  int b0 = cg >> 11, s0 = cg & 2047;
  int b1 = (cg+1) >> 11, s1 = (cg+1) & 2047;
  size_t o0 = (size_t)BB*SS*3 + (((size_t)(b0*256 + tid)) << 11) + s0;
  size_t o1 = (size_t)BB*SS*3 + (((size_t)(b1*256 + tid)) << 11) + s1;
  if (isf32){ ((float*)d_out)[o0] = v0; ((float*)d_out)[o1] = v1; }
  else { ((unsigned short*)d_out)[o0] = f2bf(v0); ((unsigned short*)d_out)[o1] = f2bf(v1); }
}

__global__ void bn_finalize(const float* sum, const float* sq, const float* g, const float* bb,
                            float* a, float* c, int n){
  int o = blockIdx.x*64 + threadIdx.x;
  if (o >= n) return;
  const float invM = 1.0f/262144.0f;
  float mu = sum[o]*invM;
  float var = sq[o]*invM - mu*mu; var = fmaxf(var, 0.f);
  float inv = 1.0f/sqrtf(var + 1e-5f);
  float av = g[o]*inv;
  a[o] = av; c[o] = bb[o] - mu*av;
}

// ---------------- workspace layout (bytes) ----------------
#define OFF_FLAG   0u
#define OFF_FPS    256u
#define OFF_KNN    33024u
#define OFF_STATS  1081600u
#define OFF_BNAC   1085184u
#define OFF_XYZF   1088768u
#define OFF_GB     1481984u
#define OFF_W0P    1485568u
#define OFF_W1P    1497856u
#define OFF_W2P    1514240u
#define OFF_PTSB   1579776u
#define OFF_Y0     5774336u
#define OFF_Y1     39328768u
// Sorted planar arrays: used by fps + knn, then dead before passB writes y1;
// placed in the y1 region (passA only writes y0).
#define OFF_PSX    (OFF_Y1)
#define OFF_PSY    (OFF_Y1 + 131072u)
#define OFF_PSZ    (OFF_Y1 + 262144u)
#define OFF_IOR    (OFF_Y1 + 393216u)

extern "C" void kernel_launch(void* const* d_in, const int* in_sizes, int n_in,
                              void* d_out, int out_size, void* d_ws, size_t ws_size,
                              hipStream_t stream){
  char* ws = (char*)d_ws;
  int*   flag  = (int*)(ws + OFF_FLAG);
  int*   fpsi  = (int*)(ws + OFF_FPS);
  int*   knn   = (int*)(ws + OFF_KNN);
  float* stats = (float*)(ws + OFF_STATS);
  float* bnac  = (float*)(ws + OFF_BNAC);
  float* xyzf  = (float*)(ws + OFF_XYZF);
  float* gbf   = (float*)(ws + OFF_GB);
  unsigned short* w0p = (unsigned short*)(ws + OFF_W0P);
  unsigned short* w1p = (unsigned short*)(ws + OFF_W1P);
  unsigned short* w2p = (unsigned short*)(ws + OFF_W2P);
  unsigned short* ptsb = (unsigned short*)(ws + OFF_PTSB);
  unsigned short* y0g = (unsigned short*)(ws + OFF_Y0);
  unsigned short* y1g = (unsigned short*)(ws + OFF_Y1);
  float* psx = (float*)(ws + OFF_PSX);
  float* psy = (float*)(ws + OFF_PSY);
  float* psz = (float*)(ws + OFF_PSZ);
  int*   ior = (int*)(ws + OFF_IOR);

  (void)hipMemsetAsync(ws + OFF_STATS, 0, 896*4, stream);
  detect_kernel<<<1, 256, 0, stream>>>(d_in[1], flag);

  convert_kernel<<<384, 256, 0, stream>>>(d_in[0], xyzf, BB*NN*3, flag);
  convert_gb<<<4, 256, 0, stream>>>(d_in[3], d_in[4], d_in[6], d_in[7], d_in[9], d_in[10], gbf, flag);
  transpose_pts_bf16<<<512, 256, 0, stream>>>(d_in[1], ptsb, flag);

  pack_w<<<24,  256, 0, stream>>>(d_in[2], w0p, 4, 3, 67, 1, flag);
  pack_w<<<32,  256, 0, stream>>>(d_in[5], w1p, 8, 2, 64, 0, flag);
  pack_w<<<128, 256, 0, stream>>>(d_in[8], w2p, 16, 4, 128, 0, flag);

  morton_sort<<<BB, 1024, 0, stream>>>(xyzf, psx, psy, psz, ior);
  fps_kernel<<<BB, 1024, 0, stream>>>(xyzf, psx, psy, psz, ior, fpsi, d_out, flag);
  knn_kernel<<<BB*SS, 256, 0, stream>>>(psx, psy, psz, ior, xyzf, fpsi, knn);

  passA<4><<<1024, 256, 0, stream>>>(xyzf, ptsb, fpsi, knn, w0p, y0g, stats + 0, stats + 64);
  bn_finalize<<<1, 64, 0, stream>>>(stats + 0, stats + 64, gbf + 0, gbf + 64, bnac + 0, bnac + 64, 64);

  passB<4><<<1024, 256, 0, stream>>>(y0g, w1p, bnac, y1g, stats + 128, stats + 256);
  bn_finalize<<<2, 64, 0, stream>>>(stats + 128, stats + 256, gbf + 128, gbf + 256, bnac + 128, bnac + 256, 128);

  passC<4><<<1024, 256, 0, stream>>>(y1g, w2p, bnac, stats + 384, stats + 640);
  bn_finalize<<<4, 64, 0, stream>>>(stats + 384, stats + 640, gbf + 384, gbf + 640, bnac + 384, bnac + 640, 256);

  passD<<<4096, 256, 0, stream>>>(y1g, w2p, bnac, d_out, flag);
  (void)in_sizes; (void)n_in; (void)out_size; (void)ws_size;
}

// Round 12
// 2606.871 us; speedup vs baseline: 2.7927x; 1.0114x over previous
//
#include <hip/hip_runtime.h>

#define BB 4
#define NN 8192
#define CC 64
#define SS 2048
#define KK 32
#define MROWS (BB*SS*KK)   // 262144

typedef __attribute__((ext_vector_type(8))) short bf16x8_t;
typedef __attribute__((ext_vector_type(4))) float f32x4_t;
typedef __attribute__((ext_vector_type(2))) float f32x2_t;

__device__ __forceinline__ float bf2f(unsigned short u){
  union { unsigned int i; float f; } v; v.i = ((unsigned int)u) << 16; return v.f;
}
__device__ __forceinline__ unsigned short f2bf(float f){
  union { float f; unsigned int i; } v; v.f = f;
  unsigned int u = v.i;
  unsigned int r = (u + 0x7FFFu + ((u >> 16) & 1u)) >> 16;
  return (unsigned short)r;
}
__device__ __forceinline__ float i2f(int i){ union { int i; float f; } v; v.i = i; return v.f; }
__device__ __forceinline__ int f2i(float f){ union { float f; int i; } v; v.f = f; return v.i; }

// ---------------- dtype detection ----------------
__global__ void detect_kernel(const void* pts, int* flag){
  __shared__ int cnt;
  if (threadIdx.x == 0) cnt = 0;
  __syncthreads();
  unsigned short u = ((const unsigned short*)pts)[threadIdx.x];
  int e = (u >> 7) & 0xFF;
  if (e != 0 && (e < 112 || e > 143)) atomicAdd(&cnt, 1);
  __syncthreads();
  if (threadIdx.x == 0) *flag = (cnt > 32) ? 1 : 0;
}

// ---------------- merged prep: transpose + converts + weight packs + stats zero ----------------
__device__ __forceinline__ void pack_dev(const void* src, unsigned short* dst,
    int CTS, int KSTEPS, int IN, int remap, int idx, bool isf){
  int total = CTS*KSTEPS*512;
  if (idx >= total) return;
  int f = idx >> 9, lane = (idx >> 3) & 63, j = idx & 7;
  int ct = f / KSTEPS, ks = f % KSTEPS;
  int n = ct*16 + (lane & 15);
  int k = ks*32 + (lane >> 4)*8 + j;
  int ksrc;
  if (remap){ ksrc = (k < 64) ? (k + 3) : (k < 67 ? k - 64 : -1); }
  else      { ksrc = (k < IN) ? k : -1; }
  float v = 0.f;
  if (ksrc >= 0){
    size_t si = (size_t)n*IN + ksrc;
    v = isf ? ((const float*)src)[si] : bf2f(((const unsigned short*)src)[si]);
  }
  dst[idx] = f2bf(v);
}

__global__ __launch_bounds__(256) void prep_kernel(
    const void* xyz_in, const void* pts_in,
    const void* w0_in, const void* w1_in, const void* w2_in,
    const void* g0, const void* b0, const void* g1, const void* b1,
    const void* g2, const void* b2,
    float* xyzf, unsigned short* ptsb,
    unsigned short* w0p, unsigned short* w1p, unsigned short* w2p,
    float* gbf, float* stats, const int* flag)
{
  __shared__ float tile[64][65];
  int blk = blockIdx.x, tid = threadIdx.x;
  bool isf = (*flag != 0);
  if (blk < 512){
    int b = blk >> 7, n0 = (blk & 127) * 64;
    #pragma unroll
    for (int k = 0; k < 16; k++){
      int idx = k*256 + tid; int c = idx >> 6; int ni = idx & 63;
      size_t src = ((size_t)b*CC + c)*NN + n0 + ni;
      tile[c][ni] = isf ? ((const float*)pts_in)[src] : bf2f(((const unsigned short*)pts_in)[src]);
    }
    __syncthreads();
    #pragma unroll
    for (int k = 0; k < 16; k++){
      int idx = k*256 + tid; int ni = idx >> 6; int c = idx & 63;
      ptsb[((size_t)b*NN + n0 + ni)*CC + c] = f2bf(tile[c][ni]);
    }
  } else if (blk < 896){
    int i = (blk - 512)*256 + tid;
    if (i < BB*NN*3)
      xyzf[i] = isf ? ((const float*)xyz_in)[i] : bf2f(((const unsigned short*)xyz_in)[i]);
  } else if (blk < 900){
    int i = (blk - 896)*256 + tid;
    if (i < 896){
      const void* src; int off;
      if      (i < 64)  { src = g0; off = i; }
      else if (i < 128) { src = b0; off = i - 64; }
      else if (i < 256) { src = g1; off = i - 128; }
      else if (i < 384) { src = b1; off = i - 256; }
      else if (i < 640) { src = g2; off = i - 384; }
      else              { src = b2; off = i - 640; }
      gbf[i] = isf ? ((const float*)src)[off] : bf2f(((const unsigned short*)src)[off]);
      stats[i] = 0.f;
    }
  } else if (blk < 924){
    pack_dev(w0_in, w0p, 4, 3, 67, 1, (blk-900)*256 + tid, isf);
  } else if (blk < 956){
    pack_dev(w1_in, w1p, 8, 2, 64, 0, (blk-924)*256 + tid, isf);
  } else {
    pack_dev(w2_in, w2p, 16, 4, 128, 0, (blk-956)*256 + tid, isf);
  }
}

// ---------------- Morton bucket scatter (one block per batch) ----------------
__device__ __forceinline__ unsigned mspread(unsigned v){
  v = (v | (v << 16)) & 0x030000FFu;
  v = (v | (v <<  8)) & 0x0300F00Fu;
  v = (v | (v <<  4)) & 0x030C30C3u;
  v = (v | (v <<  2)) & 0x09249249u;
  return v;
}
__global__ __launch_bounds__(1024) void morton_sort(const float* xyzf,
    float* psx, float* psy, float* psz, int* iorig){
  int b = blockIdx.x, tid = threadIdx.x;
  const float* xb = xyzf + (size_t)b*NN*3;
  __shared__ unsigned codes[NN];
  __shared__ unsigned hist[256];
  __shared__ unsigned curs[256];
  __shared__ float rbb[96];
  float x[8], y[8], z[8];
  {
    const float4* p4 = (const float4*)(xb + (size_t)tid*24);
    float4 A=p4[0],B2=p4[1],C=p4[2],D=p4[3],E=p4[4],F=p4[5];
    x[0]=A.x;  y[0]=A.y;  z[0]=A.z;
    x[1]=A.w;  y[1]=B2.x; z[1]=B2.y;
    x[2]=B2.z; y[2]=B2.w; z[2]=C.x;
    x[3]=C.y;  y[3]=C.z;  z[3]=C.w;
    x[4]=D.x;  y[4]=D.y;  z[4]=D.z;
    x[5]=D.w;  y[5]=E.x;  z[5]=E.y;
    x[6]=E.z;  y[6]=E.w;  z[6]=F.x;
    x[7]=F.y;  y[7]=F.z;  z[7]=F.w;
  }
  float lx=x[0],hx=x[0],ly=y[0],hy=y[0],lz=z[0],hz=z[0];
  #pragma unroll
  for (int j = 1; j < 8; j++){
    lx=fminf(lx,x[j]); hx=fmaxf(hx,x[j]);
    ly=fminf(ly,y[j]); hy=fmaxf(hy,y[j]);
    lz=fminf(lz,z[j]); hz=fmaxf(hz,z[j]);
  }
  #pragma unroll
  for (int off = 1; off < 64; off <<= 1){
    lx=fminf(lx,__shfl_xor(lx,off)); hx=fmaxf(hx,__shfl_xor(hx,off));
    ly=fminf(ly,__shfl_xor(ly,off)); hy=fmaxf(hy,__shfl_xor(hy,off));
    lz=fminf(lz,__shfl_xor(lz,off)); hz=fmaxf(hz,__shfl_xor(hz,off));
  }
  int w = tid >> 6;
  if ((tid & 63) == 0){
    rbb[w]=lx; rbb[16+w]=hx; rbb[32+w]=ly; rbb[48+w]=hy; rbb[64+w]=lz; rbb[80+w]=hz;
  }
  if (tid < 256) hist[tid] = 0;
  __syncthreads();
  #pragma unroll
  for (int i = 0; i < 16; i++){
    lx=fminf(lx,rbb[i]); hx=fmaxf(hx,rbb[16+i]);
    ly=fminf(ly,rbb[32+i]); hy=fmaxf(hy,rbb[48+i]);
    lz=fminf(lz,rbb[64+i]); hz=fmaxf(hz,rbb[80+i]);
  }
  float sx = 1023.0f/fmaxf(hx-lx,1e-20f);
  float sy = 1023.0f/fmaxf(hy-ly,1e-20f);
  float sz = 1023.0f/fmaxf(hz-lz,1e-20f);
  #pragma unroll
  for (int j = 0; j < 8; j++){
    int qx = (int)((x[j]-lx)*sx); qx = qx < 0 ? 0 : (qx > 1023 ? 1023 : qx);
    int qy = (int)((y[j]-ly)*sy); qy = qy < 0 ? 0 : (qy > 1023 ? 1023 : qy);
    int qz = (int)((z[j]-lz)*sz); qz = qz < 0 ? 0 : (qz > 1023 ? 1023 : qz);
    unsigned code = mspread((unsigned)qx) | (mspread((unsigned)qy) << 1) | (mspread((unsigned)qz) << 2);
    codes[tid*8 + j] = code;
    atomicAdd(&hist[code >> 22], 1u);
  }
  __syncthreads();
  if (tid < 64){
    unsigned h0 = hist[tid*4], h1 = hist[tid*4+1], h2 = hist[tid*4+2], h3 = hist[tid*4+3];
    unsigned s4 = h0 + h1 + h2 + h3;
    unsigned inc = s4;
    #pragma unroll
    for (int off = 1; off < 64; off <<= 1){
      unsigned o = __shfl_up(inc, off);
      if (tid >= off) inc += o;
    }
    unsigned base = inc - s4;
    curs[tid*4]   = base;
    curs[tid*4+1] = base + h0;
    curs[tid*4+2] = base + h0 + h1;
    curs[tid*4+3] = base + h0 + h1 + h2;
  }
  __syncthreads();
  #pragma unroll
  for (int j = 0; j < 8; j++){
    unsigned c = codes[tid*8 + j] >> 22;
    unsigned pos = atomicAdd(&curs[c], 1u);
    psx[b*NN + pos] = x[j];
    psy[b*NN + pos] = y[j];
    psz[b*NN + pos] = z[j];
    iorig[b*NN + pos] = tid*8 + j;
  }
}

// ---------------- DPP helpers ----------------
template<int C>
__device__ __forceinline__ float dpp_maxf(float v){
  int t = __builtin_amdgcn_update_dpp(0, f2i(v), C, 0xF, 0xF, true);
  return fmaxf(v, i2f(t));
}
template<int C>
__device__ __forceinline__ unsigned dpp_minu(unsigned v){
  unsigned t = (unsigned)__builtin_amdgcn_update_dpp(-1, (int)v, C, 0xF, 0xF, false);
  return v < t ? v : t;
}
template<int C>
__device__ __forceinline__ void dpp_max64(unsigned &lo, unsigned &hi){
  unsigned tlo = (unsigned)__builtin_amdgcn_update_dpp(0, (int)lo, C, 0xF, 0xF, true);
  unsigned thi = (unsigned)__builtin_amdgcn_update_dpp(0, (int)hi, C, 0xF, 0xF, true);
  if (thi > hi || (thi == hi && tlo > lo)){ lo = tlo; hi = thi; }
}

// ---------------- FPS: Morton-grouped + wave bbox pruning (R10 proven version) ----------------
__global__ __launch_bounds__(1024, 1) void fps_kernel(const float* xyzf,
    const float* psx, const float* psy, const float* psz, const int* iorig,
    int* fps_idx, void* d_out, const int* flag){
  int b = blockIdx.x, tid = threadIdx.x;
  const float* xb = xyzf + (size_t)b*NN*3;
  __shared__ float sxyz[NN*3];
  __shared__ unsigned long long ru[2][16];
  for (int i = tid; i < NN*3/4; i += 1024)
    ((float4*)sxyz)[i] = ((const float4*)xb)[i];
  f32x2_t px2[4], py2[4], pz2[4], dmin2[4];
  int io[8];
  {
    const float4* qx = (const float4*)(psx + b*NN + tid*8);
    const float4* qy = (const float4*)(psy + b*NN + tid*8);
    const float4* qz = (const float4*)(psz + b*NN + tid*8);
    float4 a, c;
    a = qx[0]; c = qx[1];
    px2[0]=(f32x2_t){a.x,a.y}; px2[1]=(f32x2_t){a.z,a.w}; px2[2]=(f32x2_t){c.x,c.y}; px2[3]=(f32x2_t){c.z,c.w};
    a = qy[0]; c = qy[1];
    py2[0]=(f32x2_t){a.x,a.y}; py2[1]=(f32x2_t){a.z,a.w}; py2[2]=(f32x2_t){c.x,c.y}; py2[3]=(f32x2_t){c.z,c.w};
    a = qz[0]; c = qz[1];
    pz2[0]=(f32x2_t){a.x,a.y}; pz2[1]=(f32x2_t){a.z,a.w}; pz2[2]=(f32x2_t){c.x,c.y}; pz2[3]=(f32x2_t){c.z,c.w};
    const int4* qi = (const int4*)(iorig + b*NN + tid*8);
    int4 i0 = qi[0], i1 = qi[1];
    io[0]=i0.x; io[1]=i0.y; io[2]=i0.z; io[3]=i0.w;
    io[4]=i1.x; io[5]=i1.y; io[6]=i1.z; io[7]=i1.w;
  }
  #pragma unroll
  for (int q = 0; q < 4; q++) dmin2[q] = (f32x2_t){1e10f, 1e10f};
  float blox, bhix, bloy, bhiy, bloz, bhiz;
  {
    float lx = fminf(fminf(px2[0].x,px2[0].y), fminf(px2[1].x,px2[1].y));
    lx = fminf(lx, fminf(fminf(px2[2].x,px2[2].y), fminf(px2[3].x,px2[3].y)));
    float hx = fmaxf(fmaxf(px2[0].x,px2[0].y), fmaxf(px2[1].x,px2[1].y));
    hx = fmaxf(hx, fmaxf(fmaxf(px2[2].x,px2[2].y), fmaxf(px2[3].x,px2[3].y)));
    float ly = fminf(fminf(py2[0].x,py2[0].y), fminf(py2[1].x,py2[1].y));
    ly = fminf(ly, fminf(fminf(py2[2].x,py2[2].y), fminf(py2[3].x,py2[3].y)));
    float hy = fmaxf(fmaxf(py2[0].x,py2[0].y), fmaxf(py2[1].x,py2[1].y));
    hy = fmaxf(hy, fmaxf(fmaxf(py2[2].x,py2[2].y), fmaxf(py2[3].x,py2[3].y)));
    float lz = fminf(fminf(pz2[0].x,pz2[0].y), fminf(pz2[1].x,pz2[1].y));
    lz = fminf(lz, fminf(fminf(pz2[2].x,pz2[2].y), fminf(pz2[3].x,pz2[3].y)));
    float hz = fmaxf(fmaxf(pz2[0].x,pz2[0].y), fmaxf(pz2[1].x,pz2[1].y));
    hz = fmaxf(hz, fmaxf(fmaxf(pz2[2].x,pz2[2].y), fmaxf(pz2[3].x,pz2[3].y)));
    #pragma unroll
    for (int off = 1; off < 64; off <<= 1){
      lx=fminf(lx,__shfl_xor(lx,off)); hx=fmaxf(hx,__shfl_xor(hx,off));
      ly=fminf(ly,__shfl_xor(ly,off)); hy=fmaxf(hy,__shfl_xor(hy,off));
      lz=fminf(lz,__shfl_xor(lz,off)); hz=fmaxf(hz,__shfl_xor(hz,off));
    }
    blox=lx; bhix=hx; bloy=ly; bhiy=hy; bloz=lz; bhiz=hz;
  }
  __syncthreads();
  int far = 0;
  bool isf32 = (*flag != 0);
  float* outf = (float*)d_out; unsigned short* outh = (unsigned short*)d_out;
  int w = tid >> 6, ln = tid & 63;
  unsigned cached_lo = 0u, cached_hi = 0u;
  for (int s = 0; s < SS; s++){
    float cx = sxyz[far*3], cy = sxyz[far*3+1], cz = sxyz[far*3+2];
    if (tid == 0){
      fps_idx[b*SS + s] = far;
      size_t o = ((size_t)b*SS + s)*3;
      if (isf32){ outf[o]=cx; outf[o+1]=cy; outf[o+2]=cz; }
      else { outh[o]=f2bf(cx); outh[o+1]=f2bf(cy); outh[o+2]=f2bf(cz); }
    }
    float dxl = fmaxf(fmaxf(blox - cx, cx - bhix), 0.f);
    float dyl = fmaxf(fmaxf(bloy - cy, cy - bhiy), 0.f);
    float dzl = fmaxf(fmaxf(bloz - cz, cz - bhiz), 0.f);
    float d2bb = (dxl*dxl + dyl*dyl + dzl*dzl) * 0.99999f;
    bool upd = (s == 0) || (d2bb < i2f((int)cached_hi));
    if (upd){
      f32x2_t cx2 = (f32x2_t){cx, cx}, cy2 = (f32x2_t){cy, cy}, cz2 = (f32x2_t){cz, cz};
      {
        #pragma clang fp contract(off)
        #pragma unroll
        for (int q = 0; q < 4; q++){
          f32x2_t dx = px2[q] - cx2, dy = py2[q] - cy2, dz = pz2[q] - cz2;
          f32x2_t t = dx*dx;
          t = t + dy*dy;
          t = t + dz*dz;
          dmin2[q].x = fminf(dmin2[q].x, t.x);
          dmin2[q].y = fminf(dmin2[q].y, t.y);
        }
      }
      float m0 = fmaxf(fmaxf(dmin2[0].x, dmin2[0].y), fmaxf(dmin2[1].x, dmin2[1].y));
      float m1 = fmaxf(fmaxf(dmin2[2].x, dmin2[2].y), fmaxf(dmin2[3].x, dmin2[3].y));
      float lm = fmaxf(m0, m1);
      lm = dpp_maxf<0x111>(lm); lm = dpp_maxf<0x112>(lm);
      lm = dpp_maxf<0x114>(lm); lm = dpp_maxf<0x118>(lm);
      lm = dpp_maxf<0x142>(lm); lm = dpp_maxf<0x143>(lm);
      float wmax = i2f(__builtin_amdgcn_readlane(f2i(lm), 63));
      unsigned cand = 0xFFFFFFFFu;
      #pragma unroll
      for (int q = 0; q < 4; q++){
        if (dmin2[q].x == wmax){ unsigned u = (unsigned)io[2*q];   cand = u < cand ? u : cand; }
        if (dmin2[q].y == wmax){ unsigned u = (unsigned)io[2*q+1]; cand = u < cand ? u : cand; }
      }
      cand = dpp_minu<0x111>(cand); cand = dpp_minu<0x112>(cand);
      cand = dpp_minu<0x114>(cand); cand = dpp_minu<0x118>(cand);
      cand = dpp_minu<0x142>(cand); cand = dpp_minu<0x143>(cand);
      unsigned cmin = (unsigned)__builtin_amdgcn_readlane((int)cand, 63);
      cached_hi = (unsigned)f2i(wmax);
      cached_lo = ~cmin;
    }
    if (ln == 63) ru[s & 1][w] = (((unsigned long long)cached_hi) << 32) | cached_lo;
    __syncthreads();
    unsigned long long t = ru[s & 1][ln & 15];
    unsigned lo = (unsigned)t, hi = (unsigned)(t >> 32);
    dpp_max64<0x111>(lo, hi); dpp_max64<0x112>(lo, hi);
    dpp_max64<0x114>(lo, hi); dpp_max64<0x118>(lo, hi);
    far = (int)(~(unsigned)__builtin_amdgcn_readlane((int)lo, 63));
  }
}

// ---------------- kNN: radix-histogram selection, coalesced planar loads ----------------
__global__ __launch_bounds__(256) void knn_kernel(
    const float* psx, const float* psy, const float* psz, const int* ior,
    const float* xyzf, const int* fps_idx, int* knn){
  int cg = blockIdx.x;
  int b = cg >> 11;
  int tid = threadIdx.x;
  const float* xb = xyzf + (size_t)b*NN*3;
  __shared__ unsigned hist[4096];
  __shared__ unsigned long long cand[512];
  __shared__ unsigned psum[256];
  __shared__ unsigned exbase[64];
  __shared__ float scc[3];
  __shared__ int sB, sBase, sCl, sCc;
  __shared__ unsigned long long rmin[4];
  __shared__ unsigned long long swin;

  if (tid == 0){
    int f = fps_idx[cg];
    scc[0] = xb[f*3]; scc[1] = xb[f*3+1]; scc[2] = xb[f*3+2];
    sCl = 0; sCc = 0;
  }
  #pragma unroll
  for (int i = 0; i < 16; i++) hist[tid*16 + i] = 0;
  __syncthreads();
  float cx = scc[0], cy = scc[1], cz = scc[2];

  float dv[32]; int iv[32];
  const float4* qx = (const float4*)(psx + b*NN);
  const float4* qy = (const float4*)(psy + b*NN);
  const float4* qz = (const float4*)(psz + b*NN);
  const int4*   qi = (const int4*)(ior + b*NN);
  {
    #pragma clang fp contract(off)
    #pragma unroll
    for (int k = 0; k < 8; k++){
      float4 X = qx[k*256 + tid];
      float4 Y = qy[k*256 + tid];
      float4 Z = qz[k*256 + tid];
      int4   I = qi[k*256 + tid];
      float xs_[4] = {X.x, X.y, X.z, X.w};
      float ys_[4] = {Y.x, Y.y, Y.z, Y.w};
      float zs_[4] = {Z.x, Z.y, Z.z, Z.w};
      int   is_[4] = {I.x, I.y, I.z, I.w};
      #pragma unroll
      for (int r = 0; r < 4; r++){
        float dx = cx - xs_[r], dy = cy - ys_[r], dz = cz - zs_[r];
        dv[k*4 + r] = dx*dx + dy*dy + dz*dz;
        iv[k*4 + r] = is_[r];
      }
    }
  }
  #pragma unroll
  for (int t = 0; t < 32; t++)
    atomicAdd(&hist[((unsigned)f2i(dv[t])) >> 20], 1u);
  __syncthreads();
  unsigned lsum = 0;
  #pragma unroll
  for (int i = 0; i < 16; i++) lsum += hist[tid*16 + i];
  psum[tid] = lsum;
  __syncthreads();
  if (tid < 64){
    unsigned s4 = psum[tid*4] + psum[tid*4+1] + psum[tid*4+2] + psum[tid*4+3];
    unsigned inc = s4;
    #pragma unroll
    for (int off = 1; off < 64; off <<= 1){
      unsigned o = __shfl_up(inc, off);
      if (tid >= off) inc += o;
    }
    exbase[tid] = inc - s4;
  }
  __syncthreads();
  {
    int g4 = tid >> 2;
    unsigned ex = exbase[g4];
    for (int j = g4*4; j < tid; j++) ex += psum[j];
    unsigned run = ex;
    #pragma unroll
    for (int i = 0; i < 16; i++){
      unsigned c = hist[tid*16 + i];
      if (run < 32u && run + c >= 32u){ sB = tid*16 + i; sBase = (int)run; }
      run += c;
    }
  }
  __syncthreads();
  int Bbin = sB, base = sBase;
  int out = cg << 5;
  #pragma unroll
  for (int t = 0; t < 32; t++){
    unsigned bits = (unsigned)f2i(dv[t]);
    unsigned hb = bits >> 20;
    int idx = iv[t];
    if ((int)hb < Bbin){
      int sl = atomicAdd(&sCl, 1);
      knn[out + sl] = idx;
    } else if ((int)hb == Bbin){
      int c = atomicAdd(&sCc, 1);
      if (c < 512) cand[c] = (((unsigned long long)bits) << 32) | (unsigned)idx;
    }
  }
  __syncthreads();
  int cc = sCc; if (cc > 512) cc = 512;
  int r = 32 - base;
  for (int round = 0; round < r; round++){
    unsigned long long lm = ~0ull;
    for (int i = tid; i < cc; i += 256){
      unsigned long long v = cand[i];
      if (v < lm) lm = v;
    }
    #pragma unroll
    for (int off = 1; off < 64; off <<= 1){
      unsigned long long o = __shfl_xor(lm, off);
      if (o < lm) lm = o;
    }
    if ((tid & 63) == 0) rmin[tid >> 6] = lm;
    __syncthreads();
    if (tid == 0){
      unsigned long long m = rmin[0];
      #pragma unroll
      for (int q = 1; q < 4; q++) if (rmin[q] < m) m = rmin[q];
      swin = m;
      knn[out + base + round] = (int)(unsigned)m;
    }
    __syncthreads();
    unsigned long long m = swin;
    for (int i = tid; i < cc; i += 256)
      if (cand[i] == m) cand[i] = ~0ull;
    __syncthreads();
  }
}

// ---------------- materialized MLP passes (BN finalize folded in) ----------------
__device__ __forceinline__ bf16x8_t bfrag(const unsigned short* wp, int f, int lane){
  return *(const bf16x8_t*)(wp + ((size_t)f << 9) + (lane << 3));
}
__device__ __forceinline__ bf16x8_t bn_frag(bf16x8_t v, const float* a, const float* c, int kbase){
  float4 a0 = *(const float4*)(a + kbase); float4 a1 = *(const float4*)(a + kbase + 4);
  float4 c0 = *(const float4*)(c + kbase); float4 c1 = *(const float4*)(c + kbase + 4);
  float av[8] = {a0.x,a0.y,a0.z,a0.w,a1.x,a1.y,a1.z,a1.w};
  float cv[8] = {c0.x,c0.y,c0.z,c0.w,c1.x,c1.y,c1.z,c1.w};
  bf16x8_t r;
  #pragma unroll
  for (int j = 0; j < 8; j++)
    r[j] = (short)f2bf(fmaxf(bf2f((unsigned short)v[j])*av[j] + cv[j], 0.f));
  return r;
}

template<int TILES>
__global__ __launch_bounds__(256) void passA(
    const float* __restrict__ xyzf, const unsigned short* __restrict__ ptsb,
    const int* __restrict__ fpsi, const int* __restrict__ knn,
    const unsigned short* __restrict__ w0p,
    unsigned short* __restrict__ y0g, float* osum, float* osq)
{
  __shared__ unsigned short xb0[64*104];
  __shared__ unsigned short st[64*72];
  __shared__ float sacc[128];
  int tid = threadIdx.x, lane = tid & 63, w = tid >> 6;
  int l15 = lane & 15, quad = lane >> 4;
  float ssum[4], ssq[4];
  #pragma unroll
  for (int c = 0; c < 4; c++){ ssum[c] = 0.f; ssq[c] = 0.f; }
  if (tid < 128) sacc[tid] = 0.f;
  __syncthreads();

  for (int t = 0; t < TILES; t++){
    int row0 = (blockIdx.x * TILES + t) * 64;
    {
      int r = tid >> 2, p = tid & 3;
      int g = row0 + r;
      int bq = g >> 16, s = (g >> 5) & 2047;
      int n = knn[g];
      const bf16x8_t* pr = (const bf16x8_t*)(ptsb + (((size_t)bq*NN + n) << 6));
      *(bf16x8_t*)&xb0[r*104 + p*16]     = pr[p*2];
      *(bf16x8_t*)&xb0[r*104 + p*16 + 8] = pr[p*2 + 1];
      if (p == 3){
        const float* xbp = xyzf + (size_t)bq*NN*3;
        int f = fpsi[(bq << 11) + s];
        float dx = xbp[n*3]   - xbp[f*3];
        float dy = xbp[n*3+1] - xbp[f*3+1];
        float dz = xbp[n*3+2] - xbp[f*3+2];
        bf16x8_t v = {(short)f2bf(dx), (short)f2bf(dy), (short)f2bf(dz), 0,0,0,0,0};
        bf16x8_t z = {0,0,0,0,0,0,0,0};
        *(bf16x8_t*)&xb0[r*104 + 64] = v;
        *(bf16x8_t*)&xb0[r*104 + 72] = z;
        *(bf16x8_t*)&xb0[r*104 + 80] = z;
        *(bf16x8_t*)&xb0[r*104 + 88] = z;
      }
    }
    bf16x8_t a0[3];
    #pragma unroll
    for (int ks = 0; ks < 3; ks++)
      a0[ks] = *(const bf16x8_t*)&xb0[(w*16 + l15)*104 + ks*32 + quad*8];
    #pragma unroll
    for (int ct = 0; ct < 4; ct++){
      f32x4_t a = {0.f,0.f,0.f,0.f};
      #pragma unroll
      for (int ks = 0; ks < 3; ks++)
        a = __builtin_amdgcn_mfma_f32_16x16x32_bf16(a0[ks], bfrag(w0p, ct*3+ks, lane), a, 0, 0, 0);
      #pragma unroll
      for (int r = 0; r < 4; r++){
        float v = a[r]; ssum[ct] += v; ssq[ct] += v*v;
        st[(w*16 + quad*4 + r)*72 + ct*16 + l15] = f2bf(v);
      }
    }
    __syncthreads();
    #pragma unroll
    for (int p = 0; p < 2; p++){
      int idx = p*2048 + tid*8; int r = idx >> 6; int c = idx & 63;
      *(bf16x8_t*)(y0g + (size_t)row0*64 + idx) = *(const bf16x8_t*)&st[r*72 + c];
    }
    __syncthreads();
  }
  #pragma unroll
  for (int c = 0; c < 4; c++){
    ssum[c] += __shfl_xor(ssum[c], 16); ssum[c] += __shfl_xor(ssum[c], 32);
    ssq [c] += __shfl_xor(ssq [c], 16); ssq [c] += __shfl_xor(ssq [c], 32);
  }
  if (quad == 0){
    #pragma unroll
    for (int c = 0; c < 4; c++){
      atomicAdd(&sacc[c*16 + l15], ssum[c]);
      atomicAdd(&sacc[64 + c*16 + l15], ssq[c]);
    }
  }
  __syncthreads();
  if (tid < 64){
    atomicAdd(&osum[tid], sacc[tid]);
    atomicAdd(&osq [tid], sacc[64 + tid]);
  }
}

template<int TILES>
__global__ __launch_bounds__(256) void passB(
    const unsigned short* __restrict__ y0g, const unsigned short* __restrict__ w1p,
    const float* __restrict__ stats, const float* __restrict__ gbf,
    unsigned short* __restrict__ y1g, float* osum, float* osq)
{
  __shared__ unsigned short st[64*136];
  __shared__ float sacc[256];
  __shared__ __align__(16) float sbn[128];
  int tid = threadIdx.x, lane = tid & 63, w = tid >> 6;
  int l15 = lane & 15, quad = lane >> 4;
  float ssum[8], ssq[8];
  #pragma unroll
  for (int c = 0; c < 8; c++){ ssum[c] = 0.f; ssq[c] = 0.f; }
  sacc[tid] = 0.f;
  if (tid < 64){
    const float invM = 1.0f/262144.0f;
    float mu = stats[tid]*invM;
    float var = fmaxf(stats[64+tid]*invM - mu*mu, 0.f);
    float inv = 1.0f/sqrtf(var + 1e-5f);
    float av = gbf[tid]*inv;
    sbn[tid] = av; sbn[64+tid] = gbf[64+tid] - mu*av;
  }
  __syncthreads();

  for (int t = 0; t < TILES; t++){
    int row0 = (blockIdx.x * TILES + t) * 64;
    int row = row0 + w*16 + l15;
    bf16x8_t a1[2];
    #pragma unroll
    for (int ks = 0; ks < 2; ks++){
      bf16x8_t v = *(const bf16x8_t*)(y0g + (size_t)row*64 + ks*32 + quad*8);
      a1[ks] = bn_frag(v, sbn, sbn + 64, ks*32 + quad*8);
    }
    #pragma unroll
    for (int ct = 0; ct < 8; ct++){
      f32x4_t a = {0.f,0.f,0.f,0.f};
      #pragma unroll
      for (int ks = 0; ks < 2; ks++)
        a = __builtin_amdgcn_mfma_f32_16x16x32_bf16(a1[ks], bfrag(w1p, ct*2+ks, lane), a, 0, 0, 0);
      #pragma unroll
      for (int r = 0; r < 4; r++){
        float v = a[r]; ssum[ct] += v; ssq[ct] += v*v;
        st[(w*16 + quad*4 + r)*136 + ct*16 + l15] = f2bf(v);
      }
    }
    __syncthreads();
    #pragma unroll
    for (int p = 0; p < 4; p++){
      int idx = p*2048 + tid*8; int r = idx >> 7; int c = idx & 127;
      *(bf16x8_t*)(y1g + (size_t)row0*128 + idx) = *(const bf16x8_t*)&st[r*136 + c];
    }
    __syncthreads();
  }
  #pragma unroll
  for (int c = 0; c < 8; c++){
    ssum[c] += __shfl_xor(ssum[c], 16); ssum[c] += __shfl_xor(ssum[c], 32);
    ssq [c] += __shfl_xor(ssq [c], 16); ssq [c] += __shfl_xor(ssq [c], 32);
  }
  if (quad == 0){
    #pragma unroll
    for (int c = 0; c < 8; c++){
      atomicAdd(&sacc[c*16 + l15], ssum[c]);
      atomicAdd(&sacc[128 + c*16 + l15], ssq[c]);
    }
  }
  __syncthreads();
  if (tid < 128){
    atomicAdd(&osum[tid], sacc[tid]);
    atomicAdd(&osq [tid], sacc[128 + tid]);
  }
}

template<int TILES>
__global__ __launch_bounds__(256) void passC(
    const unsigned short* __restrict__ y1g, const unsigned short* __restrict__ w2p,
    const float* __restrict__ stats, const float* __restrict__ gbf,
    float* osum, float* osq)
{
  __shared__ float sacc[512];
  __shared__ __align__(16) float sbn[256];
  int tid = threadIdx.x, lane = tid & 63, w = tid >> 6;
  int l15 = lane & 15, quad = lane >> 4;
  float ssum[16], ssq[16];
  #pragma unroll
  for (int c = 0; c < 16; c++){ ssum[c] = 0.f; ssq[c] = 0.f; }
  sacc[tid] = 0.f; sacc[tid + 256] = 0.f;
  if (tid < 128){
    const float invM = 1.0f/262144.0f;
    float mu = stats[128+tid]*invM;
    float var = fmaxf(stats[256+tid]*invM - mu*mu, 0.f);
    float inv = 1.0f/sqrtf(var + 1e-5f);
    float av = gbf[128+tid]*inv;
    sbn[tid] = av; sbn[128+tid] = gbf[256+tid] - mu*av;
  }
  __syncthreads();

  for (int t = 0; t < TILES; t++){
    int row0 = (blockIdx.x * TILES + t) * 64;
    int row = row0 + w*16 + l15;
    bf16x8_t a2[4];
    #pragma unroll
    for (int ks = 0; ks < 4; ks++){
      bf16x8_t v = *(const bf16x8_t*)(y1g + (size_t)row*128 + ks*32 + quad*8);
      a2[ks] = bn_frag(v, sbn, sbn + 128, ks*32 + quad*8);
    }
    #pragma unroll
    for (int ct = 0; ct < 16; ct++){
      f32x4_t a = {0.f,0.f,0.f,0.f};
      #pragma unroll
      for (int ks = 0; ks < 4; ks++)
        a = __builtin_amdgcn_mfma_f32_16x16x32_bf16(a2[ks], bfrag(w2p, ct*4+ks, lane), a, 0, 0, 0);
      #pragma unroll
      for (int r = 0; r < 4; r++){ float v = a[r]; ssum[ct] += v; ssq[ct] += v*v; }
    }
  }
  #pragma unroll
  for (int c = 0; c < 16; c++){
    ssum[c] += __shfl_xor(ssum[c], 16); ssum[c] += __shfl_xor(ssum[c], 32);
    ssq [c] += __shfl_xor(ssq [c], 16); ssq [c] += __shfl_xor(ssq [c], 32);
  }
  if (quad == 0){
    #pragma unroll
    for (int c = 0; c < 16; c++){
      atomicAdd(&sacc[c*16 + l15], ssum[c]);
      atomicAdd(&sacc[256 + c*16 + l15], ssq[c]);
    }
  }
  __syncthreads();
  if (tid < 256){
    atomicAdd(&osum[tid], sacc[tid]);
    atomicAdd(&osq [tid], sacc[256 + tid]);
  }
}

__global__ __launch_bounds__(256) void passD(
    const unsigned short* __restrict__ y1g, const unsigned short* __restrict__ w2p,
    const float* __restrict__ stats, const float* __restrict__ gbf,
    void* d_out, const int* __restrict__ flag)
{
  __shared__ float smax[1024];
  __shared__ __align__(16) float sbn[768];  // a1[128] c1[128] a2[256] c2[256]
  int tid = threadIdx.x, lane = tid & 63, w = tid >> 6;
  int l15 = lane & 15, quad = lane >> 4;
  {
    const float invM = 1.0f/262144.0f;
    if (tid < 128){
      float mu = stats[128+tid]*invM;
      float var = fmaxf(stats[256+tid]*invM - mu*mu, 0.f);
      float inv = 1.0f/sqrtf(var + 1e-5f);
      float av = gbf[128+tid]*inv;
      sbn[tid] = av; sbn[128+tid] = gbf[256+tid] - mu*av;
    }
    float mu2 = stats[384+tid]*invM;
    float var2 = fmaxf(stats[640+tid]*invM - mu2*mu2, 0.f);
    float inv2 = 1.0f/sqrtf(var2 + 1e-5f);
    float av2 = gbf[384+tid]*inv2;
    sbn[256+tid] = av2; sbn[512+tid] = gbf[640+tid] - mu2*av2;
  }
  __syncthreads();
  int row0 = blockIdx.x * 64;
  int row = row0 + w*16 + l15;
  bf16x8_t a2[4];
  #pragma unroll
  for (int ks = 0; ks < 4; ks++){
    bf16x8_t v = *(const bf16x8_t*)(y1g + (size_t)row*128 + ks*32 + quad*8);
    a2[ks] = bn_frag(v, sbn, sbn + 128, ks*32 + quad*8);
  }
  #pragma unroll
  for (int ct = 0; ct < 16; ct++){
    f32x4_t a = {0.f,0.f,0.f,0.f};
    #pragma unroll
    for (int ks = 0; ks < 4; ks++)
      a = __builtin_amdgcn_mfma_f32_16x16x32_bf16(a2[ks], bfrag(w2p, ct*4+ks, lane), a, 0, 0, 0);
    int o = ct*16 + l15;
    float ga = sbn[256 + o], gc = sbn[512 + o];
    float m = fmaxf(fmaxf(a[0]*ga + gc, a[1]*ga + gc), fmaxf(a[2]*ga + gc, a[3]*ga + gc));
    m = fmaxf(m, __shfl_xor(m, 16));
    m = fmaxf(m, __shfl_xor(m, 32));
    if (quad == 0) smax[w*256 + o] = m;
  }
  __syncthreads();
  float v0 = fmaxf(fmaxf(smax[tid], smax[256 + tid]), 0.f);
  float v1 = fmaxf(fmaxf(smax[512 + tid], smax[768 + tid]), 0.f);
  int cg = blockIdx.x * 2;
  bool isf32 = (*flag != 0);
  int b0 = cg >> 11, s0 = cg & 2047;
  int b1 = (cg+1) >> 11, s1 = (cg+1) & 2047;
  size_t o0 = (size_t)BB*SS*3 + (((size_t)(b0*256 + tid)) << 11) + s0;
  size_t o1 = (size_t)BB*SS*3 + (((size_t)(b1*256 + tid)) << 11) + s1;
  if (isf32){ ((float*)d_out)[o0] = v0; ((float*)d_out)[o1] = v1; }
  else { ((unsigned short*)d_out)[o0] = f2bf(v0); ((unsigned short*)d_out)[o1] = f2bf(v1); }
}

// ---------------- workspace layout (bytes) ----------------
#define OFF_FLAG   0u
#define OFF_FPS    256u
#define OFF_KNN    33024u
#define OFF_STATS  1081600u
#define OFF_XYZF   1088768u
#define OFF_GB     1481984u
#define OFF_W0P    1485568u
#define OFF_W1P    1497856u
#define OFF_W2P    1514240u
#define OFF_PTSB   1579776u
#define OFF_Y0     5774336u
#define OFF_Y1     39328768u
#define OFF_PSX    (OFF_Y1)
#define OFF_PSY    (OFF_Y1 + 131072u)
#define OFF_PSZ    (OFF_Y1 + 262144u)
#define OFF_IOR    (OFF_Y1 + 393216u)

extern "C" void kernel_launch(void* const* d_in, const int* in_sizes, int n_in,
                              void* d_out, int out_size, void* d_ws, size_t ws_size,
                              hipStream_t stream){
  char* ws = (char*)d_ws;
  int*   flag  = (int*)(ws + OFF_FLAG);
  int*   fpsi  = (int*)(ws + OFF_FPS);
  int*   knn   = (int*)(ws + OFF_KNN);
  float* stats = (float*)(ws + OFF_STATS);
  float* xyzf  = (float*)(ws + OFF_XYZF);
  float* gbf   = (float*)(ws + OFF_GB);
  unsigned short* w0p = (unsigned short*)(ws + OFF_W0P);
  unsigned short* w1p = (unsigned short*)(ws + OFF_W1P);
  unsigned short* w2p = (unsigned short*)(ws + OFF_W2P);
  unsigned short* ptsb = (unsigned short*)(ws + OFF_PTSB);
  unsigned short* y0g = (unsigned short*)(ws + OFF_Y0);
  unsigned short* y1g = (unsigned short*)(ws + OFF_Y1);
  float* psx = (float*)(ws + OFF_PSX);
  float* psy = (float*)(ws + OFF_PSY);
  float* psz = (float*)(ws + OFF_PSZ);
  int*   ior = (int*)(ws + OFF_IOR);

  detect_kernel<<<1, 256, 0, stream>>>(d_in[1], flag);
  prep_kernel<<<1084, 256, 0, stream>>>(d_in[0], d_in[1], d_in[2], d_in[5], d_in[8],
                                        d_in[3], d_in[4], d_in[6], d_in[7], d_in[9], d_in[10],
                                        xyzf, ptsb, w0p, w1p, w2p, gbf, stats, flag);

  morton_sort<<<BB, 1024, 0, stream>>>(xyzf, psx, psy, psz, ior);
  fps_kernel<<<BB, 1024, 0, stream>>>(xyzf, psx, psy, psz, ior, fpsi, d_out, flag);
  knn_kernel<<<BB*SS, 256, 0, stream>>>(psx, psy, psz, ior, xyzf, fpsi, knn);

  passA<4><<<1024, 256, 0, stream>>>(xyzf, ptsb, fpsi, knn, w0p, y0g, stats + 0, stats + 64);
  passB<4><<<1024, 256, 0, stream>>>(y0g, w1p, stats, gbf, y1g, stats + 128, stats + 256);
  passC<4><<<1024, 256, 0, stream>>>(y1g, w2p, stats, gbf, stats + 384, stats + 640);
  passD<<<4096, 256, 0, stream>>>(y1g, w2p, stats, gbf, d_out, flag);
  (void)in_sizes; (void)n_in; (void)out_size; (void)ws_size;
}